// Round 1
// baseline (4973.539 us; speedup 1.0000x reference)
//
#include <hip/hip_runtime.h>
#include <math.h>

#define NN 30000
#define NE 480000

// ---------------- fill kernels ----------------
__global__ void zero4_kernel(float4* __restrict__ p, int n4) {
  int g = blockIdx.x * 256 + threadIdx.x;
  if (g < n4) p[g] = make_float4(0.f, 0.f, 0.f, 0.f);
}
__global__ void zero1_kernel(float* __restrict__ p) { p[0] = 0.f; }

// ---------------- fp32 GEMM: C[M,Nc] = A[M,K] @ B[K,Nc], tiles 64x64x16 ----------------
__global__ __launch_bounds__(256) void gemm_nn(const float* __restrict__ A,
                                               const float* __restrict__ B,
                                               float* __restrict__ C,
                                               int M, int K, int Nc) {
  __shared__ float As[16][64];
  __shared__ float Bs[16][64];
  int tid = threadIdx.x;
  int tx = tid & 15, ty = tid >> 4;
  int bm = blockIdx.x * 64, bn = blockIdx.y * 64;
  float acc[4][4] = {};
  for (int k0 = 0; k0 < K; k0 += 16) {
    {
      int r = tid >> 2, cq = tid & 3;
      int gr = bm + r;
      float4 a = make_float4(0.f, 0.f, 0.f, 0.f);
      if (gr < M) a = *(const float4*)&A[(size_t)gr * K + k0 + 4 * cq];
      As[4 * cq + 0][r] = a.x;
      As[4 * cq + 1][r] = a.y;
      As[4 * cq + 2][r] = a.z;
      As[4 * cq + 3][r] = a.w;
    }
    {
      int kr = tid >> 4, nc = (tid & 15) * 4;
      *(float4*)&Bs[kr][nc] = *(const float4*)&B[(size_t)(k0 + kr) * Nc + bn + nc];
    }
    __syncthreads();
#pragma unroll
    for (int kk = 0; kk < 16; ++kk) {
      float4 a4 = *(float4*)&As[kk][4 * ty];
      float4 b4 = *(float4*)&Bs[kk][4 * tx];
      float av[4] = {a4.x, a4.y, a4.z, a4.w};
      float bv[4] = {b4.x, b4.y, b4.z, b4.w};
#pragma unroll
      for (int i = 0; i < 4; ++i)
#pragma unroll
        for (int j = 0; j < 4; ++j) acc[i][j] = fmaf(av[i], bv[j], acc[i][j]);
    }
    __syncthreads();
  }
#pragma unroll
  for (int i = 0; i < 4; ++i) {
    int gr = bm + 4 * ty + i;
    if (gr < M) {
      float4 o = make_float4(acc[i][0], acc[i][1], acc[i][2], acc[i][3]);
      *(float4*)&C[(size_t)gr * Nc + bn + 4 * tx] = o;
    }
  }
}

// ---------------- el/er: per (node,head) dot of h row-chunk with al/ar ----------------
__global__ void eler_kernel(const float* __restrict__ h, const float* __restrict__ al,
                            const float* __restrict__ ar, float* __restrict__ el,
                            float* __restrict__ er) {
  int gid = blockIdx.x * 256 + threadIdx.x;
  if (gid >= NN * 4) return;
  int n = gid >> 2, hh = gid & 3;
  const float4* hr = (const float4*)&h[(size_t)n * 256 + hh * 64];
  const float4* alr = (const float4*)&al[hh * 64];
  const float4* arr = (const float4*)&ar[hh * 64];
  float sl = 0.f, sr = 0.f;
#pragma unroll
  for (int q = 0; q < 16; ++q) {
    float4 hv = hr[q], a = alr[q], b = arr[q];
    sl += hv.x * a.x + hv.y * a.y + hv.z * a.z + hv.w * a.w;
    sr += hv.x * b.x + hv.y * b.y + hv.z * b.z + hv.w * b.w;
  }
  el[gid] = sl;
  er[gid] = sr;
}

// ---------------- softmax denominator (no max-subtraction; |e| <~ 2) ----------------
__global__ void edge_sum_kernel(const int* __restrict__ src, const int* __restrict__ dst,
                                const float* __restrict__ el, const float* __restrict__ er,
                                float* __restrict__ ssum) {
  int e = blockIdx.x * 256 + threadIdx.x;
  if (e >= NE) return;
  int s = src[e], d = dst[e];
#pragma unroll
  for (int h = 0; h < 4; ++h) {
    float v = el[s * 4 + h] + er[d * 4 + h];
    v = v > 0.f ? v : 0.2f * v;
    atomicAdd(&ssum[d * 4 + h], expf(v));
  }
}

// ---------------- weighted aggregation: z[dst] += a * h[src] (wave per edge) ----------------
__global__ __launch_bounds__(256) void edge_aggr_kernel(
    const int* __restrict__ src, const int* __restrict__ dst, const float* __restrict__ el,
    const float* __restrict__ er, const float* __restrict__ ssum, const float* __restrict__ h,
    float* __restrict__ z) {
  int lane = threadIdx.x & 63;
  int e = blockIdx.x * 4 + (threadIdx.x >> 6);
  if (e >= NE) return;
  int s = src[e], d = dst[e];
  int hh = lane >> 4;
  float v = el[s * 4 + hh] + er[d * 4 + hh];
  v = v > 0.f ? v : 0.2f * v;
  float a = expf(v) / ssum[d * 4 + hh];
  float4 hv = *(const float4*)&h[(size_t)s * 256 + lane * 4];
  float* zp = &z[(size_t)d * 256 + lane * 4];
  atomicAdd(zp + 0, a * hv.x);
  atomicAdd(zp + 1, a * hv.y);
  atomicAdd(zp + 2, a * hv.z);
  atomicAdd(zp + 3, a * hv.w);
}

// ---------------- GAT epilogue: z = clip(z + b, 0, 6) ----------------
__global__ void gat_epi_kernel(float* __restrict__ z, const float* __restrict__ b) {
  int gid = blockIdx.x * 256 + threadIdx.x;  // over N*64 float4s
  if (gid >= NN * 64) return;
  int c4 = gid & 63;
  float4 zb = ((const float4*)b)[c4];
  float4 v = ((float4*)z)[gid];
  v.x = fminf(fmaxf(v.x + zb.x, 0.f), 6.f);
  v.y = fminf(fmaxf(v.y + zb.y, 0.f), 6.f);
  v.z = fminf(fmaxf(v.z + zb.z, 0.f), 6.f);
  v.w = fminf(fmaxf(v.w + zb.w, 0.f), 6.f);
  ((float4*)z)[gid] = v;
}

// ---------------- attention pooling: wsum[m] += sum_n tanh(z@Wp1+bp1)@wp2 ----------------
__global__ __launch_bounds__(256) void attn_pool_kernel(
    const float* __restrict__ z0, const float* __restrict__ z1, const float* __restrict__ Wp1,
    const float* __restrict__ bp1, const float* __restrict__ wp2, float* __restrict__ wb) {
  __shared__ float frow[4][256];
  int lane = threadIdx.x & 63, w = threadIdx.x >> 6;
  int n = blockIdx.x * 4 + w;
  const float* z = blockIdx.y ? z1 : z0;
  *(float4*)&frow[w][lane * 4] = *(const float4*)&z[(size_t)n * 256 + lane * 4];
  __syncthreads();
  float acc = 0.f;
#pragma unroll 4
  for (int k = 0; k < 256; k += 4) {
    float4 f = *(float4*)&frow[w][k];
    acc = fmaf(f.x, Wp1[(k + 0) * 64 + lane], acc);
    acc = fmaf(f.y, Wp1[(k + 1) * 64 + lane], acc);
    acc = fmaf(f.z, Wp1[(k + 2) * 64 + lane], acc);
    acc = fmaf(f.w, Wp1[(k + 3) * 64 + lane], acc);
  }
  float t = tanhf(acc + bp1[lane]) * wp2[lane];
  for (int off = 32; off > 0; off >>= 1) t += __shfl_down(t, off);
  if (lane == 0) atomicAdd(&wb[blockIdx.y], t);
}

// ---------------- beta = softmax(wsum / N) ----------------
__global__ void beta_kernel(float* __restrict__ wb) {
  float w0 = wb[0] * (1.0f / NN);
  float w1 = wb[1] * (1.0f / NN);
  float mx = fmaxf(w0, w1);
  float e0 = expf(w0 - mx), e1 = expf(w1 - mx);
  float inv = 1.f / (e0 + e1);
  wb[2] = e0 * inv;
  wb[3] = e1 * inv;
}

// ---------------- Femb = (beta0*z0 + beta1*z1) @ Wf + bf ----------------
__global__ __launch_bounds__(256) void fused_femb_kernel(
    const float* __restrict__ z0, const float* __restrict__ z1, const float* __restrict__ wb,
    const float* __restrict__ Wf, const float* __restrict__ bf, float* __restrict__ Femb) {
  __shared__ float frow[4][256];
  int lane = threadIdx.x & 63, w = threadIdx.x >> 6;
  int n = blockIdx.x * 4 + w;
  float b0 = wb[2], b1 = wb[3];
  float4 a0 = *(const float4*)&z0[(size_t)n * 256 + lane * 4];
  float4 a1 = *(const float4*)&z1[(size_t)n * 256 + lane * 4];
  float4 f;
  f.x = b0 * a0.x + b1 * a1.x;
  f.y = b0 * a0.y + b1 * a1.y;
  f.z = b0 * a0.z + b1 * a1.z;
  f.w = b0 * a0.w + b1 * a1.w;
  *(float4*)&frow[w][lane * 4] = f;
  __syncthreads();
  float acc = 0.f;
#pragma unroll 4
  for (int k = 0; k < 256; k += 4) {
    float4 fv = *(float4*)&frow[w][k];
    acc = fmaf(fv.x, Wf[(k + 0) * 64 + lane], acc);
    acc = fmaf(fv.y, Wf[(k + 1) * 64 + lane], acc);
    acc = fmaf(fv.z, Wf[(k + 2) * 64 + lane], acc);
    acc = fmaf(fv.w, Wf[(k + 3) * 64 + lane], acc);
  }
  Femb[(size_t)n * 64 + lane] = acc + bf[lane];
}

// ---------------- degrees ----------------
__global__ void deg_kernel(const int* __restrict__ gsrc, const int* __restrict__ gdst,
                           float* __restrict__ dego, float* __restrict__ degi) {
  int e = blockIdx.x * 256 + threadIdx.x;
  if (e >= NE) return;
  atomicAdd(&dego[gsrc[e]], 1.f);
  atomicAdd(&degi[gdst[e]], 1.f);
}
__global__ void rdeg_kernel(float* __restrict__ dego, float* __restrict__ degi) {
  int n = blockIdx.x * 256 + threadIdx.x;
  if (n >= NN) return;
  dego[n] = 1.f / sqrtf(fmaxf(dego[n], 1.f));
  degi[n] = 1.f / sqrtf(fmaxf(degi[n], 1.f));
}

// ---------------- GCN gemm K=256: out[n,j] = rdo[n] * sum_k X[n,k] W[k,j] ----------------
__global__ __launch_bounds__(256) void gcn_gemm256_kernel(const float* __restrict__ X,
                                                          const float* __restrict__ W,
                                                          const float* __restrict__ rdo,
                                                          float* __restrict__ out) {
  __shared__ float frow[4][256];
  int lane = threadIdx.x & 63, w = threadIdx.x >> 6;
  int n = blockIdx.x * 4 + w;
  *(float4*)&frow[w][lane * 4] = *(const float4*)&X[(size_t)n * 256 + lane * 4];
  __syncthreads();
  float acc = 0.f;
#pragma unroll 4
  for (int k = 0; k < 256; k += 4) {
    float4 fv = *(float4*)&frow[w][k];
    acc = fmaf(fv.x, W[(k + 0) * 64 + lane], acc);
    acc = fmaf(fv.y, W[(k + 1) * 64 + lane], acc);
    acc = fmaf(fv.z, W[(k + 2) * 64 + lane], acc);
    acc = fmaf(fv.w, W[(k + 3) * 64 + lane], acc);
  }
  out[(size_t)n * 64 + lane] = acc * rdo[n];
}

// ---------------- GCN gemm K=64 via shuffle ----------------
__global__ __launch_bounds__(256) void gcn_gemm64_kernel(const float* __restrict__ X,
                                                         const float* __restrict__ W,
                                                         const float* __restrict__ rdo,
                                                         float* __restrict__ out) {
  int lane = threadIdx.x & 63, w = threadIdx.x >> 6;
  int n = blockIdx.x * 4 + w;
  float x = X[(size_t)n * 64 + lane];
  float acc = 0.f;
#pragma unroll
  for (int k = 0; k < 64; ++k) acc = fmaf(__shfl(x, k), W[k * 64 + lane], acc);
  out[(size_t)n * 64 + lane] = acc * rdo[n];
}

// ---------------- GCN aggregation: out[dst] += in[src] (64 floats, wave per edge) ----------------
__global__ __launch_bounds__(256) void gcn_aggr_kernel(const int* __restrict__ src,
                                                       const int* __restrict__ dst,
                                                       const float* __restrict__ in,
                                                       float* __restrict__ out) {
  int lane = threadIdx.x & 63;
  int e = blockIdx.x * 4 + (threadIdx.x >> 6);
  if (e >= NE) return;
  int s = src[e], d = dst[e];
  atomicAdd(&out[(size_t)d * 64 + lane], in[(size_t)s * 64 + lane]);
}

// ---------------- p1 = tanh(agg * rdi + bg1) (in place) ----------------
__global__ void gcn_post_kernel(float* __restrict__ buf, const float* __restrict__ rdi,
                                const float* __restrict__ bg1) {
  int gid = blockIdx.x * 256 + threadIdx.x;
  if (gid >= NN * 64) return;
  int n = gid >> 6, j = gid & 63;
  buf[gid] = tanhf(buf[gid] * rdi[n] + bg1[j]);
}

// ---------------- Z = 0.5*(Femb + P*rdi) -> d_out[1..] ----------------
__global__ void zfinal_kernel(const float* __restrict__ Femb, const float* __restrict__ P,
                              const float* __restrict__ rdi, float* __restrict__ dout) {
  int gid = blockIdx.x * 256 + threadIdx.x;
  if (gid >= NN * 64) return;
  int n = gid >> 6;
  dout[1 + gid] = 0.5f * (Femb[gid] + P[gid] * rdi[n]);
}

// ---------------- tr = 0.5 * sum_e ||Zk[asrc]-Zk[adst]||^2 ----------------
__global__ __launch_bounds__(256) void tr_kernel(const int* __restrict__ asrc,
                                                 const int* __restrict__ adst,
                                                 const int* __restrict__ kptr,
                                                 float* __restrict__ dout) {
  __shared__ float wsum[4];
  int e = blockIdx.x * 256 + threadIdx.x;
  int k = *kptr;
  float local = 0.f;
  if (e < NE) {
    int a = asrc[e], b = adst[e];
    const float* Za = dout + 1 + (size_t)a * 64;
    const float* Zb = dout + 1 + (size_t)b * 64;
    for (int c = 0; c < k; ++c) {
      float d2 = Za[c] - Zb[c];
      local += d2 * d2;
    }
  }
  for (int off = 32; off > 0; off >>= 1) local += __shfl_down(local, off);
  int lane = threadIdx.x & 63, w = threadIdx.x >> 6;
  if (lane == 0) wsum[w] = local;
  __syncthreads();
  if (threadIdx.x == 0) {
    float s = wsum[0] + wsum[1] + wsum[2] + wsum[3];
    atomicAdd(&dout[0], 0.5f * s);
  }
}

extern "C" void kernel_launch(void* const* d_in, const int* in_sizes, int n_in, void* d_out,
                              int out_size, void* d_ws, size_t ws_size, hipStream_t stream) {
  const float* feat0 = (const float*)d_in[0];
  const float* feat1 = (const float*)d_in[1];
  const float* sen = (const float*)d_in[2];
  const float* Wgat0 = (const float*)d_in[3];
  const float* al0 = (const float*)d_in[4];
  const float* ar0 = (const float*)d_in[5];
  const float* b0 = (const float*)d_in[6];
  const float* Wgat1 = (const float*)d_in[7];
  const float* al1 = (const float*)d_in[8];
  const float* ar1 = (const float*)d_in[9];
  const float* b1 = (const float*)d_in[10];
  const float* Wp1 = (const float*)d_in[11];
  const float* bp1 = (const float*)d_in[12];
  const float* wp2 = (const float*)d_in[13];
  const float* Wf = (const float*)d_in[14];
  const float* bf = (const float*)d_in[15];
  const float* Wg1 = (const float*)d_in[16];
  const float* bg1 = (const float*)d_in[17];
  const float* Wg2 = (const float*)d_in[18];
  const int* src0 = (const int*)d_in[19];
  const int* dst0 = (const int*)d_in[20];
  const int* src1 = (const int*)d_in[21];
  const int* dst1 = (const int*)d_in[22];
  const int* gsrc = (const int*)d_in[23];
  const int* gdst = (const int*)d_in[24];
  const int* asrc = (const int*)d_in[25];
  const int* adst = (const int*)d_in[26];
  const int* kptr = (const int*)d_in[27];
  float* out = (float*)d_out;
  float* ws = (float*)d_ws;

  // workspace layout (floats). zero-init region first.
  float* z0 = ws;                  // 7,680,000
  float* z1 = z0 + 7680000;        // 7,680,000
  float* s0 = z1 + 7680000;        // 120,000
  float* s1 = s0 + 120000;         // 120,000
  float* dego = s1 + 120000;       // 30,000
  float* degi = dego + 30000;      // 30,000
  float* gcnB = degi + 30000;      // 1,920,000
  float* gcnC = gcnB + 1920000;    // 1,920,000
  float* wb = gcnC + 1920000;      // 4: wsum0, wsum1, beta0, beta1
  size_t zero_floats = (size_t)(wb + 4 - ws);  // 19,500,004
  float* h0 = wb + 4;              // 7,680,000
  float* h1 = h0 + 7680000;        // 7,680,000
  float* el0 = h1 + 7680000;       // 120,000
  float* er0 = el0 + 120000;       // 120,000
  float* el1 = er0 + 120000;       // 120,000
  float* er1 = el1 + 120000;       // 120,000
  float* Femb = er1 + 120000;      // 1,920,000
  float* gcnA = Femb + 1920000;    // 1,920,000

  int n4 = (int)(zero_floats / 4);  // zero_floats divisible by 4
  zero4_kernel<<<(n4 + 255) / 256, 256, 0, stream>>>((float4*)ws, n4);
  zero1_kernel<<<1, 1, 0, stream>>>(out);

  // h = feat @ Wgat
  gemm_nn<<<dim3(469, 4), 256, 0, stream>>>(feat0, Wgat0, h0, NN, 256, 256);
  gemm_nn<<<dim3(469, 4), 256, 0, stream>>>(feat1, Wgat1, h1, NN, 128, 256);

  // el/er
  eler_kernel<<<469, 256, 0, stream>>>(h0, al0, ar0, el0, er0);
  eler_kernel<<<469, 256, 0, stream>>>(h1, al1, ar1, el1, er1);

  // softmax denominators
  edge_sum_kernel<<<1875, 256, 0, stream>>>(src0, dst0, el0, er0, s0);
  edge_sum_kernel<<<1875, 256, 0, stream>>>(src1, dst1, el1, er1, s1);

  // weighted aggregation
  edge_aggr_kernel<<<120000, 256, 0, stream>>>(src0, dst0, el0, er0, s0, h0, z0);
  edge_aggr_kernel<<<120000, 256, 0, stream>>>(src1, dst1, el1, er1, s1, h1, z1);

  // z = clip(z + b, 0, 6)
  gat_epi_kernel<<<7500, 256, 0, stream>>>(z0, b0);
  gat_epi_kernel<<<7500, 256, 0, stream>>>(z1, b1);

  // attention pooling -> beta
  attn_pool_kernel<<<dim3(7500, 2), 256, 0, stream>>>(z0, z1, Wp1, bp1, wp2, wb);
  beta_kernel<<<1, 1, 0, stream>>>(wb);

  // Femb
  fused_femb_kernel<<<7500, 256, 0, stream>>>(z0, z1, wb, Wf, bf, Femb);

  // GCN path
  deg_kernel<<<1875, 256, 0, stream>>>(gsrc, gdst, dego, degi);
  rdeg_kernel<<<118, 256, 0, stream>>>(dego, degi);
  gcn_gemm256_kernel<<<7500, 256, 0, stream>>>(sen, Wg1, dego, gcnA);
  gcn_aggr_kernel<<<120000, 256, 0, stream>>>(gsrc, gdst, gcnA, gcnB);
  gcn_post_kernel<<<7500, 256, 0, stream>>>(gcnB, degi, bg1);
  gcn_gemm64_kernel<<<7500, 256, 0, stream>>>(gcnB, Wg2, dego, gcnA);
  gcn_aggr_kernel<<<120000, 256, 0, stream>>>(gsrc, gdst, gcnA, gcnC);

  // Z and trace
  zfinal_kernel<<<7500, 256, 0, stream>>>(Femb, gcnC, degi, out);
  tr_kernel<<<1875, 256, 0, stream>>>(asrc, adst, kptr, out);
}

// Round 2
// 1695.174 us; speedup vs baseline: 2.9339x; 2.9339x over previous
//
#include <hip/hip_runtime.h>
#include <math.h>

#define NN 30000
#define NE 480000
#define NBLK 118  // ceil(30000/256)

// ---------------- fill kernels ----------------
__global__ void zero4_kernel(float4* __restrict__ p, int n4) {
  int g = blockIdx.x * 256 + threadIdx.x;
  if (g < n4) p[g] = make_float4(0.f, 0.f, 0.f, 0.f);
}
__global__ void zero1_kernel(float* __restrict__ p) { p[0] = 0.f; }

__device__ __forceinline__ float wred(float v) {
#pragma unroll
  for (int off = 32; off > 0; off >>= 1) v += __shfl_xor(v, off);
  return v;
}

// ---------------- fp32 GEMM: C[M,Nc] = A[M,K] @ B[K,Nc], tiles 64x64x16 ----------------
__global__ __launch_bounds__(256) void gemm_nn(const float* __restrict__ A,
                                               const float* __restrict__ B,
                                               float* __restrict__ C,
                                               int M, int K, int Nc) {
  __shared__ float As[16][64];
  __shared__ float Bs[16][64];
  int tid = threadIdx.x;
  int tx = tid & 15, ty = tid >> 4;
  int bm = blockIdx.x * 64, bn = blockIdx.y * 64;
  float acc[4][4] = {};
  for (int k0 = 0; k0 < K; k0 += 16) {
    {
      int r = tid >> 2, cq = tid & 3;
      int gr = bm + r;
      float4 a = make_float4(0.f, 0.f, 0.f, 0.f);
      if (gr < M) a = *(const float4*)&A[(size_t)gr * K + k0 + 4 * cq];
      As[4 * cq + 0][r] = a.x;
      As[4 * cq + 1][r] = a.y;
      As[4 * cq + 2][r] = a.z;
      As[4 * cq + 3][r] = a.w;
    }
    {
      int kr = tid >> 4, nc = (tid & 15) * 4;
      *(float4*)&Bs[kr][nc] = *(const float4*)&B[(size_t)(k0 + kr) * Nc + bn + nc];
    }
    __syncthreads();
#pragma unroll
    for (int kk = 0; kk < 16; ++kk) {
      float4 a4 = *(float4*)&As[kk][4 * ty];
      float4 b4 = *(float4*)&Bs[kk][4 * tx];
      float av[4] = {a4.x, a4.y, a4.z, a4.w};
      float bv[4] = {b4.x, b4.y, b4.z, b4.w};
#pragma unroll
      for (int i = 0; i < 4; ++i)
#pragma unroll
        for (int j = 0; j < 4; ++j) acc[i][j] = fmaf(av[i], bv[j], acc[i][j]);
    }
    __syncthreads();
  }
#pragma unroll
  for (int i = 0; i < 4; ++i) {
    int gr = bm + 4 * ty + i;
    if (gr < M) {
      float4 o = make_float4(acc[i][0], acc[i][1], acc[i][2], acc[i][3]);
      *(float4*)&C[(size_t)gr * Nc + bn + 4 * tx] = o;
    }
  }
}

// ---------------- el/er ----------------
__global__ void eler_kernel(const float* __restrict__ h, const float* __restrict__ al,
                            const float* __restrict__ ar, float* __restrict__ el,
                            float* __restrict__ er) {
  int gid = blockIdx.x * 256 + threadIdx.x;
  if (gid >= NN * 4) return;
  int n = gid >> 2, hh = gid & 3;
  const float4* hr = (const float4*)&h[(size_t)n * 256 + hh * 64];
  const float4* alr = (const float4*)&al[hh * 64];
  const float4* arr = (const float4*)&ar[hh * 64];
  float sl = 0.f, sr = 0.f;
#pragma unroll
  for (int q = 0; q < 16; ++q) {
    float4 hv = hr[q], a = alr[q], b = arr[q];
    sl += hv.x * a.x + hv.y * a.y + hv.z * a.z + hv.w * a.w;
    sr += hv.x * b.x + hv.y * b.y + hv.z * b.z + hv.w * b.w;
  }
  el[gid] = sl;
  er[gid] = sr;
}

// ---------------- CSR build: histogram over dst ----------------
__global__ void hist_kernel(const int* __restrict__ d0, const int* __restrict__ d1,
                            const int* __restrict__ d2, int* __restrict__ cnt) {
  int g = blockIdx.y;
  const int* d = g == 0 ? d0 : g == 1 ? d1 : d2;
  int e = blockIdx.x * 256 + threadIdx.x;
  if (e < NE) atomicAdd(&cnt[g * NN + d[e]], 1);
}

// out-degree (gsrc) float histogram
__global__ void deg_src_kernel(const int* __restrict__ gsrc, float* __restrict__ dego) {
  int e = blockIdx.x * 256 + threadIdx.x;
  if (e < NE) atomicAdd(&dego[gsrc[e]], 1.f);
}

// ---------------- hierarchical exclusive scan ----------------
__global__ __launch_bounds__(256) void scan_blocks_kernel(const int* __restrict__ cnt,
                                                          int* __restrict__ rows,
                                                          int* __restrict__ bsum) {
  __shared__ int sm[256];
  int g = blockIdx.y, t = threadIdx.x;
  int i = blockIdx.x * 256 + t;
  int v = (i < NN) ? cnt[g * NN + i] : 0;
  sm[t] = v;
  __syncthreads();
#pragma unroll
  for (int off = 1; off < 256; off <<= 1) {
    int tmp = (t >= off) ? sm[t - off] : 0;
    __syncthreads();
    sm[t] += tmp;
    __syncthreads();
  }
  if (i < NN) rows[g * (NN + 1) + i] = sm[t] - v;  // exclusive
  if (t == 255) bsum[g * NBLK + blockIdx.x] = sm[255];
}

__global__ __launch_bounds__(128) void scan_tops_kernel(int* __restrict__ bsum,
                                                        int* __restrict__ boff) {
  __shared__ int sm[128];
  int g = blockIdx.y, t = threadIdx.x;
  int v = (t < NBLK) ? bsum[g * NBLK + t] : 0;
  sm[t] = v;
  __syncthreads();
#pragma unroll
  for (int off = 1; off < 128; off <<= 1) {
    int tmp = (t >= off) ? sm[t - off] : 0;
    __syncthreads();
    sm[t] += tmp;
    __syncthreads();
  }
  if (t < NBLK) boff[g * NBLK + t] = sm[t] - v;  // exclusive
}

__global__ void add_off_kernel(int* __restrict__ rows, const int* __restrict__ boff) {
  int g = blockIdx.y, t = threadIdx.x;
  int i = blockIdx.x * 256 + t;
  if (i < NN) rows[g * (NN + 1) + i] += boff[g * NBLK + blockIdx.x];
  if (blockIdx.x == 0 && t == 0) rows[g * (NN + 1) + NN] = NE;
}

// ---------------- scatter into CSR col arrays ----------------
__global__ void scatter_kernel(const int* __restrict__ s0, const int* __restrict__ s1,
                               const int* __restrict__ s2, const int* __restrict__ d0,
                               const int* __restrict__ d1, const int* __restrict__ d2,
                               const int* __restrict__ rows, int* __restrict__ cnt2,
                               int* __restrict__ cols) {
  int g = blockIdx.y;
  const int* sp = g == 0 ? s0 : g == 1 ? s1 : s2;
  const int* dp = g == 0 ? d0 : g == 1 ? d1 : d2;
  int e = blockIdx.x * 256 + threadIdx.x;
  if (e >= NE) return;
  int d = dp[e];
  int pos = rows[g * (NN + 1) + d] + atomicAdd(&cnt2[g * NN + d], 1);
  cols[(size_t)g * NE + pos] = sp[e];
}

// ---------------- rdo/rdi ----------------
__global__ void rdeg2_kernel(float* __restrict__ rdo, float* __restrict__ rdi,
                             const int* __restrict__ rows_g) {
  int n = blockIdx.x * 256 + threadIdx.x;
  if (n >= NN) return;
  rdo[n] = rsqrtf(fmaxf(rdo[n], 1.f));
  float di = (float)(rows_g[n + 1] - rows_g[n]);
  rdi[n] = rsqrtf(fmaxf(di, 1.f));
}

// ---------------- GAT per-node gather: softmax + weighted sum + bias + relu6 ----------------
__global__ __launch_bounds__(256) void gat_node_kernel(
    const int* __restrict__ rows, const int* __restrict__ cols, const float* __restrict__ el,
    const float* __restrict__ er, const float* __restrict__ h, const float* __restrict__ bias,
    float* __restrict__ z) {
  int lane = threadIdx.x & 63, w = threadIdx.x >> 6;
  int n = blockIdx.x * 4 + w;
  if (n >= NN) return;
  int r0 = rows[n], r1 = rows[n + 1];
  float4 er4 = *(const float4*)&er[n * 4];
  // phase A: per-head softmax denominators (no max-sub: |e| bounded ~2)
  float s0 = 0.f, s1 = 0.f, s2 = 0.f, s3 = 0.f;
  for (int j = r0 + lane; j < r1; j += 64) {
    int s = cols[j];
    float4 elv = *(const float4*)&el[s * 4];
    float v0 = elv.x + er4.x; v0 = v0 > 0.f ? v0 : 0.2f * v0;
    float v1 = elv.y + er4.y; v1 = v1 > 0.f ? v1 : 0.2f * v1;
    float v2 = elv.z + er4.z; v2 = v2 > 0.f ? v2 : 0.2f * v2;
    float v3 = elv.w + er4.w; v3 = v3 > 0.f ? v3 : 0.2f * v3;
    s0 += __expf(v0); s1 += __expf(v1); s2 += __expf(v2); s3 += __expf(v3);
  }
  s0 = wred(s0); s1 = wred(s1); s2 = wred(s2); s3 = wred(s3);
  int hh = lane >> 4;
  float denom = hh == 0 ? s0 : hh == 1 ? s1 : hh == 2 ? s2 : s3;
  float myer = hh == 0 ? er4.x : hh == 1 ? er4.y : hh == 2 ? er4.z : er4.w;
  float invd = (r1 > r0) ? 1.f / denom : 0.f;
  // phase B: weighted gather
  float4 acc = make_float4(0.f, 0.f, 0.f, 0.f);
  for (int j = r0; j < r1; ++j) {
    int s = cols[j];
    float v = el[s * 4 + hh] + myer;
    v = v > 0.f ? v : 0.2f * v;
    float a = __expf(v) * invd;
    float4 hv = *(const float4*)&h[(size_t)s * 256 + lane * 4];
    acc.x = fmaf(a, hv.x, acc.x);
    acc.y = fmaf(a, hv.y, acc.y);
    acc.z = fmaf(a, hv.z, acc.z);
    acc.w = fmaf(a, hv.w, acc.w);
  }
  float4 bv = *(const float4*)&bias[lane * 4];
  acc.x = fminf(fmaxf(acc.x + bv.x, 0.f), 6.f);
  acc.y = fminf(fmaxf(acc.y + bv.y, 0.f), 6.f);
  acc.z = fminf(fmaxf(acc.z + bv.z, 0.f), 6.f);
  acc.w = fminf(fmaxf(acc.w + bv.w, 0.f), 6.f);
  *(float4*)&z[(size_t)n * 256 + lane * 4] = acc;
}

// ---------------- attention pooling ----------------
__global__ __launch_bounds__(256) void attn_pool_kernel(
    const float* __restrict__ z0, const float* __restrict__ z1, const float* __restrict__ Wp1,
    const float* __restrict__ bp1, const float* __restrict__ wp2, float* __restrict__ wb) {
  __shared__ float frow[4][256];
  int lane = threadIdx.x & 63, w = threadIdx.x >> 6;
  int n = blockIdx.x * 4 + w;
  const float* z = blockIdx.y ? z1 : z0;
  *(float4*)&frow[w][lane * 4] = *(const float4*)&z[(size_t)n * 256 + lane * 4];
  __syncthreads();
  float acc = 0.f;
#pragma unroll 4
  for (int k = 0; k < 256; k += 4) {
    float4 f = *(float4*)&frow[w][k];
    acc = fmaf(f.x, Wp1[(k + 0) * 64 + lane], acc);
    acc = fmaf(f.y, Wp1[(k + 1) * 64 + lane], acc);
    acc = fmaf(f.z, Wp1[(k + 2) * 64 + lane], acc);
    acc = fmaf(f.w, Wp1[(k + 3) * 64 + lane], acc);
  }
  float t = tanhf(acc + bp1[lane]) * wp2[lane];
  for (int off = 32; off > 0; off >>= 1) t += __shfl_down(t, off);
  if (lane == 0) atomicAdd(&wb[blockIdx.y], t);
}

__global__ void beta_kernel(float* __restrict__ wb) {
  float w0 = wb[0] * (1.0f / NN);
  float w1 = wb[1] * (1.0f / NN);
  float mx = fmaxf(w0, w1);
  float e0 = expf(w0 - mx), e1 = expf(w1 - mx);
  float inv = 1.f / (e0 + e1);
  wb[2] = e0 * inv;
  wb[3] = e1 * inv;
}

// ---------------- Femb = (beta0*z0 + beta1*z1) @ Wf + bf ----------------
__global__ __launch_bounds__(256) void fused_femb_kernel(
    const float* __restrict__ z0, const float* __restrict__ z1, const float* __restrict__ wb,
    const float* __restrict__ Wf, const float* __restrict__ bf, float* __restrict__ Femb) {
  __shared__ float frow[4][256];
  int lane = threadIdx.x & 63, w = threadIdx.x >> 6;
  int n = blockIdx.x * 4 + w;
  float b0 = wb[2], b1 = wb[3];
  float4 a0 = *(const float4*)&z0[(size_t)n * 256 + lane * 4];
  float4 a1 = *(const float4*)&z1[(size_t)n * 256 + lane * 4];
  float4 f;
  f.x = b0 * a0.x + b1 * a1.x;
  f.y = b0 * a0.y + b1 * a1.y;
  f.z = b0 * a0.z + b1 * a1.z;
  f.w = b0 * a0.w + b1 * a1.w;
  *(float4*)&frow[w][lane * 4] = f;
  __syncthreads();
  float acc = 0.f;
#pragma unroll 4
  for (int k = 0; k < 256; k += 4) {
    float4 fv = *(float4*)&frow[w][k];
    acc = fmaf(fv.x, Wf[(k + 0) * 64 + lane], acc);
    acc = fmaf(fv.y, Wf[(k + 1) * 64 + lane], acc);
    acc = fmaf(fv.z, Wf[(k + 2) * 64 + lane], acc);
    acc = fmaf(fv.w, Wf[(k + 3) * 64 + lane], acc);
  }
  Femb[(size_t)n * 64 + lane] = acc + bf[lane];
}

// ---------------- GCN gemm K=256 with src-norm ----------------
__global__ __launch_bounds__(256) void gcn_gemm256_kernel(const float* __restrict__ X,
                                                          const float* __restrict__ W,
                                                          const float* __restrict__ rdo,
                                                          float* __restrict__ out) {
  __shared__ float frow[4][256];
  int lane = threadIdx.x & 63, w = threadIdx.x >> 6;
  int n = blockIdx.x * 4 + w;
  *(float4*)&frow[w][lane * 4] = *(const float4*)&X[(size_t)n * 256 + lane * 4];
  __syncthreads();
  float acc = 0.f;
#pragma unroll 4
  for (int k = 0; k < 256; k += 4) {
    float4 fv = *(float4*)&frow[w][k];
    acc = fmaf(fv.x, W[(k + 0) * 64 + lane], acc);
    acc = fmaf(fv.y, W[(k + 1) * 64 + lane], acc);
    acc = fmaf(fv.z, W[(k + 2) * 64 + lane], acc);
    acc = fmaf(fv.w, W[(k + 3) * 64 + lane], acc);
  }
  out[(size_t)n * 64 + lane] = acc * rdo[n];
}

// ---------------- GCN gemm K=64 via shuffle ----------------
__global__ __launch_bounds__(256) void gcn_gemm64_kernel(const float* __restrict__ X,
                                                         const float* __restrict__ W,
                                                         const float* __restrict__ rdo,
                                                         float* __restrict__ out) {
  int lane = threadIdx.x & 63, w = threadIdx.x >> 6;
  int n = blockIdx.x * 4 + w;
  float x = X[(size_t)n * 64 + lane];
  float acc = 0.f;
#pragma unroll
  for (int k = 0; k < 64; ++k) acc = fmaf(__shfl(x, k), W[k * 64 + lane], acc);
  out[(size_t)n * 64 + lane] = acc * rdo[n];
}

// ---------------- GCN gather layer1: tanh(agg*rdi + bg1) ----------------
__global__ __launch_bounds__(256) void gcn_gather1_kernel(
    const int* __restrict__ rows, const int* __restrict__ cols, const float* __restrict__ X,
    const float* __restrict__ rdi, const float* __restrict__ bg1, float* __restrict__ out) {
  int lane = threadIdx.x & 63, w = threadIdx.x >> 6;
  int n = blockIdx.x * 4 + w;
  if (n >= NN) return;
  int r0 = rows[n], r1 = rows[n + 1];
  float acc = 0.f;
  for (int j = r0; j < r1; ++j) {
    int s = cols[j];
    acc += X[(size_t)s * 64 + lane];
  }
  out[(size_t)n * 64 + lane] = tanhf(acc * rdi[n] + bg1[lane]);
}

// ---------------- GCN gather layer2 fused with Z-final write ----------------
__global__ __launch_bounds__(256) void gcn_gather2_kernel(
    const int* __restrict__ rows, const int* __restrict__ cols, const float* __restrict__ X,
    const float* __restrict__ rdi, const float* __restrict__ Femb, float* __restrict__ dout) {
  int lane = threadIdx.x & 63, w = threadIdx.x >> 6;
  int n = blockIdx.x * 4 + w;
  if (n >= NN) return;
  int r0 = rows[n], r1 = rows[n + 1];
  float acc = 0.f;
  for (int j = r0; j < r1; ++j) {
    int s = cols[j];
    acc += X[(size_t)s * 64 + lane];
  }
  dout[1 + (size_t)n * 64 + lane] = 0.5f * (Femb[(size_t)n * 64 + lane] + acc * rdi[n]);
}

// ---------------- tr = 0.5 * sum_e ||Zk[asrc]-Zk[adst]||^2 ----------------
__global__ __launch_bounds__(256) void tr_kernel(const int* __restrict__ asrc,
                                                 const int* __restrict__ adst,
                                                 const int* __restrict__ kptr,
                                                 float* __restrict__ dout) {
  __shared__ float wsum[4];
  int e = blockIdx.x * 256 + threadIdx.x;
  int k = *kptr;
  float local = 0.f;
  if (e < NE) {
    int a = asrc[e], b = adst[e];
    const float* Za = dout + 1 + (size_t)a * 64;
    const float* Zb = dout + 1 + (size_t)b * 64;
    for (int c = 0; c < k; ++c) {
      float d2 = Za[c] - Zb[c];
      local += d2 * d2;
    }
  }
  for (int off = 32; off > 0; off >>= 1) local += __shfl_down(local, off);
  int lane = threadIdx.x & 63, w = threadIdx.x >> 6;
  if (lane == 0) wsum[w] = local;
  __syncthreads();
  if (threadIdx.x == 0) {
    float s = wsum[0] + wsum[1] + wsum[2] + wsum[3];
    atomicAdd(&dout[0], 0.5f * s);
  }
}

extern "C" void kernel_launch(void* const* d_in, const int* in_sizes, int n_in, void* d_out,
                              int out_size, void* d_ws, size_t ws_size, hipStream_t stream) {
  const float* feat0 = (const float*)d_in[0];
  const float* feat1 = (const float*)d_in[1];
  const float* sen = (const float*)d_in[2];
  const float* Wgat0 = (const float*)d_in[3];
  const float* al0 = (const float*)d_in[4];
  const float* ar0 = (const float*)d_in[5];
  const float* b0 = (const float*)d_in[6];
  const float* Wgat1 = (const float*)d_in[7];
  const float* al1 = (const float*)d_in[8];
  const float* ar1 = (const float*)d_in[9];
  const float* b1 = (const float*)d_in[10];
  const float* Wp1 = (const float*)d_in[11];
  const float* bp1 = (const float*)d_in[12];
  const float* wp2 = (const float*)d_in[13];
  const float* Wf = (const float*)d_in[14];
  const float* bf = (const float*)d_in[15];
  const float* Wg1 = (const float*)d_in[16];
  const float* bg1 = (const float*)d_in[17];
  const float* Wg2 = (const float*)d_in[18];
  const int* src0 = (const int*)d_in[19];
  const int* dst0 = (const int*)d_in[20];
  const int* src1 = (const int*)d_in[21];
  const int* dst1 = (const int*)d_in[22];
  const int* gsrc = (const int*)d_in[23];
  const int* gdst = (const int*)d_in[24];
  const int* asrc = (const int*)d_in[25];
  const int* adst = (const int*)d_in[26];
  const int* kptr = (const int*)d_in[27];
  float* out = (float*)d_out;
  float* ws = (float*)d_ws;

  // ---- workspace layout (element offsets, all %4==0 for float4 alignment) ----
  // ZERO region [0 .. 210004): dego(30000) wb(4) cnt(90000 int) cnt2(90000 int)
  float* dego = ws;                       // 30000
  float* wb = ws + 30000;                 // 4
  int* cnt = (int*)(ws + 30004);          // 3*30000
  int* cnt2 = (int*)(ws + 120004);        // 3*30000
  float* rdi = ws + 210004;               // 30000
  int* rows = (int*)(ws + 240004);        // 3*(NN+1) = 90003
  int* bsum = (int*)(ws + 330007);        // 3*118 = 354
  int* boff = (int*)(ws + 330361);        // 354
  int* cols = (int*)(ws + 330716);        // 3*NE = 1,440,000
  float* h0 = ws + 1770716;               // 7,680,000
  float* h1 = ws + 9450716;               // 7,680,000
  float* z0 = ws + 17130716;              // 7,680,000
  float* z1 = ws + 24810716;              // 7,680,000
  float* el0 = ws + 32490716;             // 120000
  float* er0 = ws + 32610716;             // 120000
  float* el1 = ws + 32730716;             // 120000
  float* er1 = ws + 32850716;             // 120000
  float* Femb = ws + 32970716;            // 1,920,000
  float* gcnA = ws + 34890716;            // 1,920,000
  float* gcnB = ws + 36810716;            // 1,920,000

  int* rows_g = rows + 2 * (NN + 1);
  int* cols_g = cols + 2 * NE;

  // zero: 210004 elements = 52501 float4
  zero4_kernel<<<(52501 + 255) / 256, 256, 0, stream>>>((float4*)ws, 52501);
  zero1_kernel<<<1, 1, 0, stream>>>(out);

  // ---- CSR build for 3 graphs (by dst) ----
  hist_kernel<<<dim3(1875, 3), 256, 0, stream>>>(dst0, dst1, gdst, cnt);
  deg_src_kernel<<<1875, 256, 0, stream>>>(gsrc, dego);
  scan_blocks_kernel<<<dim3(NBLK, 3), 256, 0, stream>>>(cnt, rows, bsum);
  scan_tops_kernel<<<dim3(1, 3), 128, 0, stream>>>(bsum, boff);
  add_off_kernel<<<dim3(NBLK, 3), 256, 0, stream>>>(rows, boff);
  scatter_kernel<<<dim3(1875, 3), 256, 0, stream>>>(src0, src1, gsrc, dst0, dst1, gdst, rows,
                                                    cnt2, cols);
  rdeg2_kernel<<<NBLK, 256, 0, stream>>>(dego, rdi, rows_g);

  // ---- GAT dense projections ----
  gemm_nn<<<dim3(469, 4), 256, 0, stream>>>(feat0, Wgat0, h0, NN, 256, 256);
  gemm_nn<<<dim3(469, 4), 256, 0, stream>>>(feat1, Wgat1, h1, NN, 128, 256);
  eler_kernel<<<469, 256, 0, stream>>>(h0, al0, ar0, el0, er0);
  eler_kernel<<<469, 256, 0, stream>>>(h1, al1, ar1, el1, er1);

  // ---- GAT gather (softmax + aggregate + bias + relu6) ----
  gat_node_kernel<<<7500, 256, 0, stream>>>(rows, cols, el0, er0, h0, b0, z0);
  gat_node_kernel<<<7500, 256, 0, stream>>>(rows + (NN + 1), cols + NE, el1, er1, h1, b1, z1);

  // ---- attention pooling -> beta -> Femb ----
  attn_pool_kernel<<<dim3(7500, 2), 256, 0, stream>>>(z0, z1, Wp1, bp1, wp2, wb);
  beta_kernel<<<1, 1, 0, stream>>>(wb);
  fused_femb_kernel<<<7500, 256, 0, stream>>>(z0, z1, wb, Wf, bf, Femb);

  // ---- GCN path (gather-based) ----
  gcn_gemm256_kernel<<<7500, 256, 0, stream>>>(sen, Wg1, dego, gcnA);
  gcn_gather1_kernel<<<7500, 256, 0, stream>>>(rows_g, cols_g, gcnA, rdi, bg1, gcnB);
  gcn_gemm64_kernel<<<7500, 256, 0, stream>>>(gcnB, Wg2, dego, gcnA);
  gcn_gather2_kernel<<<7500, 256, 0, stream>>>(rows_g, cols_g, gcnA, rdi, Femb, out);

  // ---- trace ----
  tr_kernel<<<1875, 256, 0, stream>>>(asrc, adst, kptr, out);
}

// Round 3
// 1030.397 us; speedup vs baseline: 4.8268x; 1.6452x over previous
//
#include <hip/hip_runtime.h>
#include <math.h>

#define NN 30000
#define NE 480000
#define NBLK 118  // ceil(30000/256)
#define NPOOL 7500   // blocks per graph in attn_pool
#define NTRB 1875    // blocks in tr pass

// ---------------- fill kernels ----------------
__global__ void zero4_kernel(float4* __restrict__ p, int n4) {
  int g = blockIdx.x * 256 + threadIdx.x;
  if (g < n4) p[g] = make_float4(0.f, 0.f, 0.f, 0.f);
}

__device__ __forceinline__ float wred(float v) {
#pragma unroll
  for (int off = 32; off > 0; off >>= 1) v += __shfl_xor(v, off);
  return v;
}

// ---------------- fp32 GEMM: C[M,Nc] = A[M,K] @ B[K,Nc], tiles 64x64x16 ----------------
__global__ __launch_bounds__(256) void gemm_nn(const float* __restrict__ A,
                                               const float* __restrict__ B,
                                               float* __restrict__ C,
                                               int M, int K, int Nc) {
  __shared__ float As[16][64];
  __shared__ float Bs[16][64];
  int tid = threadIdx.x;
  int tx = tid & 15, ty = tid >> 4;
  int bm = blockIdx.x * 64, bn = blockIdx.y * 64;
  float acc[4][4] = {};
  for (int k0 = 0; k0 < K; k0 += 16) {
    {
      int r = tid >> 2, cq = tid & 3;
      int gr = bm + r;
      float4 a = make_float4(0.f, 0.f, 0.f, 0.f);
      if (gr < M) a = *(const float4*)&A[(size_t)gr * K + k0 + 4 * cq];
      As[4 * cq + 0][r] = a.x;
      As[4 * cq + 1][r] = a.y;
      As[4 * cq + 2][r] = a.z;
      As[4 * cq + 3][r] = a.w;
    }
    {
      int kr = tid >> 4, nc = (tid & 15) * 4;
      *(float4*)&Bs[kr][nc] = *(const float4*)&B[(size_t)(k0 + kr) * Nc + bn + nc];
    }
    __syncthreads();
#pragma unroll
    for (int kk = 0; kk < 16; ++kk) {
      float4 a4 = *(float4*)&As[kk][4 * ty];
      float4 b4 = *(float4*)&Bs[kk][4 * tx];
      float av[4] = {a4.x, a4.y, a4.z, a4.w};
      float bv[4] = {b4.x, b4.y, b4.z, b4.w};
#pragma unroll
      for (int i = 0; i < 4; ++i)
#pragma unroll
        for (int j = 0; j < 4; ++j) acc[i][j] = fmaf(av[i], bv[j], acc[i][j]);
    }
    __syncthreads();
  }
#pragma unroll
  for (int i = 0; i < 4; ++i) {
    int gr = bm + 4 * ty + i;
    if (gr < M) {
      float4 o = make_float4(acc[i][0], acc[i][1], acc[i][2], acc[i][3]);
      *(float4*)&C[(size_t)gr * Nc + bn + 4 * tx] = o;
    }
  }
}

// ---------------- el/er ----------------
__global__ void eler_kernel(const float* __restrict__ h, const float* __restrict__ al,
                            const float* __restrict__ ar, float* __restrict__ el,
                            float* __restrict__ er) {
  int gid = blockIdx.x * 256 + threadIdx.x;
  if (gid >= NN * 4) return;
  int n = gid >> 2, hh = gid & 3;
  const float4* hr = (const float4*)&h[(size_t)n * 256 + hh * 64];
  const float4* alr = (const float4*)&al[hh * 64];
  const float4* arr = (const float4*)&ar[hh * 64];
  float sl = 0.f, sr = 0.f;
#pragma unroll
  for (int q = 0; q < 16; ++q) {
    float4 hv = hr[q], a = alr[q], b = arr[q];
    sl += hv.x * a.x + hv.y * a.y + hv.z * a.z + hv.w * a.w;
    sr += hv.x * b.x + hv.y * b.y + hv.z * b.z + hv.w * b.w;
  }
  el[gid] = sl;
  er[gid] = sr;
}

// ---------------- CSR build: histogram over dst ----------------
__global__ void hist_kernel(const int* __restrict__ d0, const int* __restrict__ d1,
                            const int* __restrict__ d2, int* __restrict__ cnt) {
  int g = blockIdx.y;
  const int* d = g == 0 ? d0 : g == 1 ? d1 : d2;
  int e = blockIdx.x * 256 + threadIdx.x;
  if (e < NE) atomicAdd(&cnt[g * NN + d[e]], 1);
}

__global__ void deg_src_kernel(const int* __restrict__ gsrc, float* __restrict__ dego) {
  int e = blockIdx.x * 256 + threadIdx.x;
  if (e < NE) atomicAdd(&dego[gsrc[e]], 1.f);
}

// ---------------- hierarchical exclusive scan ----------------
__global__ __launch_bounds__(256) void scan_blocks_kernel(const int* __restrict__ cnt,
                                                          int* __restrict__ rows,
                                                          int* __restrict__ bsum) {
  __shared__ int sm[256];
  int g = blockIdx.y, t = threadIdx.x;
  int i = blockIdx.x * 256 + t;
  int v = (i < NN) ? cnt[g * NN + i] : 0;
  sm[t] = v;
  __syncthreads();
#pragma unroll
  for (int off = 1; off < 256; off <<= 1) {
    int tmp = (t >= off) ? sm[t - off] : 0;
    __syncthreads();
    sm[t] += tmp;
    __syncthreads();
  }
  if (i < NN) rows[g * (NN + 1) + i] = sm[t] - v;  // exclusive
  if (t == 255) bsum[g * NBLK + blockIdx.x] = sm[255];
}

__global__ __launch_bounds__(128) void scan_tops_kernel(int* __restrict__ bsum,
                                                        int* __restrict__ boff) {
  __shared__ int sm[128];
  int g = blockIdx.y, t = threadIdx.x;
  int v = (t < NBLK) ? bsum[g * NBLK + t] : 0;
  sm[t] = v;
  __syncthreads();
#pragma unroll
  for (int off = 1; off < 128; off <<= 1) {
    int tmp = (t >= off) ? sm[t - off] : 0;
    __syncthreads();
    sm[t] += tmp;
    __syncthreads();
  }
  if (t < NBLK) boff[g * NBLK + t] = sm[t] - v;  // exclusive
}

__global__ void add_off_kernel(int* __restrict__ rows, const int* __restrict__ boff) {
  int g = blockIdx.y, t = threadIdx.x;
  int i = blockIdx.x * 256 + t;
  if (i < NN) rows[g * (NN + 1) + i] += boff[g * NBLK + blockIdx.x];
  if (blockIdx.x == 0 && t == 0) rows[g * (NN + 1) + NN] = NE;
}

// ---------------- scatter into CSR col arrays ----------------
__global__ void scatter_kernel(const int* __restrict__ s0, const int* __restrict__ s1,
                               const int* __restrict__ s2, const int* __restrict__ d0,
                               const int* __restrict__ d1, const int* __restrict__ d2,
                               const int* __restrict__ rows, int* __restrict__ cnt2,
                               int* __restrict__ cols) {
  int g = blockIdx.y;
  const int* sp = g == 0 ? s0 : g == 1 ? s1 : s2;
  const int* dp = g == 0 ? d0 : g == 1 ? d1 : d2;
  int e = blockIdx.x * 256 + threadIdx.x;
  if (e >= NE) return;
  int d = dp[e];
  int pos = rows[g * (NN + 1) + d] + atomicAdd(&cnt2[g * NN + d], 1);
  cols[(size_t)g * NE + pos] = sp[e];
}

// ---------------- rdo/rdi ----------------
__global__ void rdeg2_kernel(float* __restrict__ rdo, float* __restrict__ rdi,
                             const int* __restrict__ rows_g) {
  int n = blockIdx.x * 256 + threadIdx.x;
  if (n >= NN) return;
  rdo[n] = rsqrtf(fmaxf(rdo[n], 1.f));
  float di = (float)(rows_g[n + 1] - rows_g[n]);
  rdi[n] = rsqrtf(fmaxf(di, 1.f));
}

// ---------------- GAT per-node gather: softmax + weighted sum + bias + relu6 ----------------
__global__ __launch_bounds__(256) void gat_node_kernel(
    const int* __restrict__ rows, const int* __restrict__ cols, const float* __restrict__ el,
    const float* __restrict__ er, const float* __restrict__ h, const float* __restrict__ bias,
    float* __restrict__ z) {
  int lane = threadIdx.x & 63, w = threadIdx.x >> 6;
  int n = blockIdx.x * 4 + w;
  if (n >= NN) return;
  int r0 = rows[n], r1 = rows[n + 1];
  float4 er4 = *(const float4*)&er[n * 4];
  float s0 = 0.f, s1 = 0.f, s2 = 0.f, s3 = 0.f;
  for (int j = r0 + lane; j < r1; j += 64) {
    int s = cols[j];
    float4 elv = *(const float4*)&el[s * 4];
    float v0 = elv.x + er4.x; v0 = v0 > 0.f ? v0 : 0.2f * v0;
    float v1 = elv.y + er4.y; v1 = v1 > 0.f ? v1 : 0.2f * v1;
    float v2 = elv.z + er4.z; v2 = v2 > 0.f ? v2 : 0.2f * v2;
    float v3 = elv.w + er4.w; v3 = v3 > 0.f ? v3 : 0.2f * v3;
    s0 += __expf(v0); s1 += __expf(v1); s2 += __expf(v2); s3 += __expf(v3);
  }
  s0 = wred(s0); s1 = wred(s1); s2 = wred(s2); s3 = wred(s3);
  int hh = lane >> 4;
  float denom = hh == 0 ? s0 : hh == 1 ? s1 : hh == 2 ? s2 : s3;
  float myer = hh == 0 ? er4.x : hh == 1 ? er4.y : hh == 2 ? er4.z : er4.w;
  float invd = (r1 > r0) ? 1.f / denom : 0.f;
  float4 acc = make_float4(0.f, 0.f, 0.f, 0.f);
  for (int j = r0; j < r1; ++j) {
    int s = cols[j];
    float v = el[s * 4 + hh] + myer;
    v = v > 0.f ? v : 0.2f * v;
    float a = __expf(v) * invd;
    float4 hv = *(const float4*)&h[(size_t)s * 256 + lane * 4];
    acc.x = fmaf(a, hv.x, acc.x);
    acc.y = fmaf(a, hv.y, acc.y);
    acc.z = fmaf(a, hv.z, acc.z);
    acc.w = fmaf(a, hv.w, acc.w);
  }
  float4 bv = *(const float4*)&bias[lane * 4];
  acc.x = fminf(fmaxf(acc.x + bv.x, 0.f), 6.f);
  acc.y = fminf(fmaxf(acc.y + bv.y, 0.f), 6.f);
  acc.z = fminf(fmaxf(acc.z + bv.z, 0.f), 6.f);
  acc.w = fminf(fmaxf(acc.w + bv.w, 0.f), 6.f);
  *(float4*)&z[(size_t)n * 256 + lane * 4] = acc;
}

// ---------------- attention pooling: per-block partial (NO same-address atomics) ----------------
__global__ __launch_bounds__(256) void attn_pool_kernel(
    const float* __restrict__ z0, const float* __restrict__ z1, const float* __restrict__ Wp1,
    const float* __restrict__ bp1, const float* __restrict__ wp2, float* __restrict__ pbuf) {
  __shared__ float frow[4][256];
  __shared__ float wsum[4];
  int lane = threadIdx.x & 63, w = threadIdx.x >> 6;
  int n = blockIdx.x * 4 + w;
  const float* z = blockIdx.y ? z1 : z0;
  *(float4*)&frow[w][lane * 4] = *(const float4*)&z[(size_t)n * 256 + lane * 4];
  __syncthreads();
  float acc = 0.f;
#pragma unroll 4
  for (int k = 0; k < 256; k += 4) {
    float4 f = *(float4*)&frow[w][k];
    acc = fmaf(f.x, Wp1[(k + 0) * 64 + lane], acc);
    acc = fmaf(f.y, Wp1[(k + 1) * 64 + lane], acc);
    acc = fmaf(f.z, Wp1[(k + 2) * 64 + lane], acc);
    acc = fmaf(f.w, Wp1[(k + 3) * 64 + lane], acc);
  }
  float t = tanhf(acc + bp1[lane]) * wp2[lane];
#pragma unroll
  for (int off = 32; off > 0; off >>= 1) t += __shfl_down(t, off);
  if (lane == 0) wsum[w] = t;
  __syncthreads();
  if (threadIdx.x == 0)
    pbuf[blockIdx.y * NPOOL + blockIdx.x] = wsum[0] + wsum[1] + wsum[2] + wsum[3];
}

// ---------------- reduce partials -> beta (single block) ----------------
__global__ __launch_bounds__(256) void attn_reduce_kernel(const float* __restrict__ pbuf,
                                                          float* __restrict__ wb) {
  __shared__ float sm[8];
  int t = threadIdx.x;
  float a0 = 0.f, a1 = 0.f;
  for (int i = t; i < NPOOL; i += 256) {
    a0 += pbuf[i];
    a1 += pbuf[NPOOL + i];
  }
  a0 = wred(a0);
  a1 = wred(a1);
  int lane = t & 63, w = t >> 6;
  if (lane == 0) { sm[w] = a0; sm[4 + w] = a1; }
  __syncthreads();
  if (t == 0) {
    float w0 = (sm[0] + sm[1] + sm[2] + sm[3]) * (1.0f / NN);
    float w1 = (sm[4] + sm[5] + sm[6] + sm[7]) * (1.0f / NN);
    float mx = fmaxf(w0, w1);
    float e0 = expf(w0 - mx), e1 = expf(w1 - mx);
    float inv = 1.f / (e0 + e1);
    wb[2] = e0 * inv;
    wb[3] = e1 * inv;
  }
}

// ---------------- Femb = (beta0*z0 + beta1*z1) @ Wf + bf ----------------
__global__ __launch_bounds__(256) void fused_femb_kernel(
    const float* __restrict__ z0, const float* __restrict__ z1, const float* __restrict__ wb,
    const float* __restrict__ Wf, const float* __restrict__ bf, float* __restrict__ Femb) {
  __shared__ float frow[4][256];
  int lane = threadIdx.x & 63, w = threadIdx.x >> 6;
  int n = blockIdx.x * 4 + w;
  float b0 = wb[2], b1 = wb[3];
  float4 a0 = *(const float4*)&z0[(size_t)n * 256 + lane * 4];
  float4 a1 = *(const float4*)&z1[(size_t)n * 256 + lane * 4];
  float4 f;
  f.x = b0 * a0.x + b1 * a1.x;
  f.y = b0 * a0.y + b1 * a1.y;
  f.z = b0 * a0.z + b1 * a1.z;
  f.w = b0 * a0.w + b1 * a1.w;
  *(float4*)&frow[w][lane * 4] = f;
  __syncthreads();
  float acc = 0.f;
#pragma unroll 4
  for (int k = 0; k < 256; k += 4) {
    float4 fv = *(float4*)&frow[w][k];
    acc = fmaf(fv.x, Wf[(k + 0) * 64 + lane], acc);
    acc = fmaf(fv.y, Wf[(k + 1) * 64 + lane], acc);
    acc = fmaf(fv.z, Wf[(k + 2) * 64 + lane], acc);
    acc = fmaf(fv.w, Wf[(k + 3) * 64 + lane], acc);
  }
  Femb[(size_t)n * 64 + lane] = acc + bf[lane];
}

// ---------------- GCN gemm K=256 with src-norm ----------------
__global__ __launch_bounds__(256) void gcn_gemm256_kernel(const float* __restrict__ X,
                                                          const float* __restrict__ W,
                                                          const float* __restrict__ rdo,
                                                          float* __restrict__ out) {
  __shared__ float frow[4][256];
  int lane = threadIdx.x & 63, w = threadIdx.x >> 6;
  int n = blockIdx.x * 4 + w;
  *(float4*)&frow[w][lane * 4] = *(const float4*)&X[(size_t)n * 256 + lane * 4];
  __syncthreads();
  float acc = 0.f;
#pragma unroll 4
  for (int k = 0; k < 256; k += 4) {
    float4 fv = *(float4*)&frow[w][k];
    acc = fmaf(fv.x, W[(k + 0) * 64 + lane], acc);
    acc = fmaf(fv.y, W[(k + 1) * 64 + lane], acc);
    acc = fmaf(fv.z, W[(k + 2) * 64 + lane], acc);
    acc = fmaf(fv.w, W[(k + 3) * 64 + lane], acc);
  }
  out[(size_t)n * 64 + lane] = acc * rdo[n];
}

// ---------------- GCN gemm K=64 via shuffle ----------------
__global__ __launch_bounds__(256) void gcn_gemm64_kernel(const float* __restrict__ X,
                                                         const float* __restrict__ W,
                                                         const float* __restrict__ rdo,
                                                         float* __restrict__ out) {
  int lane = threadIdx.x & 63, w = threadIdx.x >> 6;
  int n = blockIdx.x * 4 + w;
  float x = X[(size_t)n * 64 + lane];
  float acc = 0.f;
#pragma unroll
  for (int k = 0; k < 64; ++k) acc = fmaf(__shfl(x, k), W[k * 64 + lane], acc);
  out[(size_t)n * 64 + lane] = acc * rdo[n];
}

// ---------------- GCN gather layer1: tanh(agg*rdi + bg1) ----------------
__global__ __launch_bounds__(256) void gcn_gather1_kernel(
    const int* __restrict__ rows, const int* __restrict__ cols, const float* __restrict__ X,
    const float* __restrict__ rdi, const float* __restrict__ bg1, float* __restrict__ out) {
  int lane = threadIdx.x & 63, w = threadIdx.x >> 6;
  int n = blockIdx.x * 4 + w;
  if (n >= NN) return;
  int r0 = rows[n], r1 = rows[n + 1];
  float acc = 0.f;
  for (int j = r0; j < r1; ++j) {
    int s = cols[j];
    acc += X[(size_t)s * 64 + lane];
  }
  out[(size_t)n * 64 + lane] = tanhf(acc * rdi[n] + bg1[lane]);
}

// ---------------- GCN gather layer2 fused with Z-final write ----------------
__global__ __launch_bounds__(256) void gcn_gather2_kernel(
    const int* __restrict__ rows, const int* __restrict__ cols, const float* __restrict__ X,
    const float* __restrict__ rdi, const float* __restrict__ Femb, float* __restrict__ dout) {
  int lane = threadIdx.x & 63, w = threadIdx.x >> 6;
  int n = blockIdx.x * 4 + w;
  if (n >= NN) return;
  int r0 = rows[n], r1 = rows[n + 1];
  float acc = 0.f;
  for (int j = r0; j < r1; ++j) {
    int s = cols[j];
    acc += X[(size_t)s * 64 + lane];
  }
  dout[1 + (size_t)n * 64 + lane] = 0.5f * (Femb[(size_t)n * 64 + lane] + acc * rdi[n]);
}

// ---------------- trace: per-block partials ----------------
__global__ __launch_bounds__(256) void tr_kernel(const int* __restrict__ asrc,
                                                 const int* __restrict__ adst,
                                                 const int* __restrict__ kptr,
                                                 const float* __restrict__ dout,
                                                 float* __restrict__ trbuf) {
  __shared__ float wsum[4];
  int e = blockIdx.x * 256 + threadIdx.x;
  int k = *kptr;
  float local = 0.f;
  if (e < NE) {
    int a = asrc[e], b = adst[e];
    const float* Za = dout + 1 + (size_t)a * 64;
    const float* Zb = dout + 1 + (size_t)b * 64;
    for (int c = 0; c < k; ++c) {
      float d2 = Za[c] - Zb[c];
      local += d2 * d2;
    }
  }
#pragma unroll
  for (int off = 32; off > 0; off >>= 1) local += __shfl_down(local, off);
  int lane = threadIdx.x & 63, w = threadIdx.x >> 6;
  if (lane == 0) wsum[w] = local;
  __syncthreads();
  if (threadIdx.x == 0) trbuf[blockIdx.x] = wsum[0] + wsum[1] + wsum[2] + wsum[3];
}

__global__ __launch_bounds__(256) void tr_reduce_kernel(const float* __restrict__ trbuf,
                                                        float* __restrict__ dout) {
  __shared__ float sm[4];
  int t = threadIdx.x;
  float a = 0.f;
  for (int i = t; i < NTRB; i += 256) a += trbuf[i];
  a = wred(a);
  int lane = t & 63, w = t >> 6;
  if (lane == 0) sm[w] = a;
  __syncthreads();
  if (t == 0) dout[0] = 0.5f * (sm[0] + sm[1] + sm[2] + sm[3]);
}

extern "C" void kernel_launch(void* const* d_in, const int* in_sizes, int n_in, void* d_out,
                              int out_size, void* d_ws, size_t ws_size, hipStream_t stream) {
  const float* feat0 = (const float*)d_in[0];
  const float* feat1 = (const float*)d_in[1];
  const float* sen = (const float*)d_in[2];
  const float* Wgat0 = (const float*)d_in[3];
  const float* al0 = (const float*)d_in[4];
  const float* ar0 = (const float*)d_in[5];
  const float* b0 = (const float*)d_in[6];
  const float* Wgat1 = (const float*)d_in[7];
  const float* al1 = (const float*)d_in[8];
  const float* ar1 = (const float*)d_in[9];
  const float* b1 = (const float*)d_in[10];
  const float* Wp1 = (const float*)d_in[11];
  const float* bp1 = (const float*)d_in[12];
  const float* wp2 = (const float*)d_in[13];
  const float* Wf = (const float*)d_in[14];
  const float* bf = (const float*)d_in[15];
  const float* Wg1 = (const float*)d_in[16];
  const float* bg1 = (const float*)d_in[17];
  const float* Wg2 = (const float*)d_in[18];
  const int* src0 = (const int*)d_in[19];
  const int* dst0 = (const int*)d_in[20];
  const int* src1 = (const int*)d_in[21];
  const int* dst1 = (const int*)d_in[22];
  const int* gsrc = (const int*)d_in[23];
  const int* gdst = (const int*)d_in[24];
  const int* asrc = (const int*)d_in[25];
  const int* adst = (const int*)d_in[26];
  const int* kptr = (const int*)d_in[27];
  float* out = (float*)d_out;
  float* ws = (float*)d_ws;

  // ---- workspace layout ----
  // ZERO region [0 .. 210004): dego(30000) wb(4) cnt(90000 int) cnt2(90000 int)
  float* dego = ws;                       // 30000
  float* wb = ws + 30000;                 // 4
  int* cnt = (int*)(ws + 30004);          // 3*30000
  int* cnt2 = (int*)(ws + 120004);        // 3*30000
  float* rdi = ws + 210004;               // 30000
  int* rows = (int*)(ws + 240004);        // 3*(NN+1) = 90003
  int* bsum = (int*)(ws + 330007);        // 354
  int* boff = (int*)(ws + 330361);        // 354
  int* cols = (int*)(ws + 330716);        // 3*NE
  float* h0 = ws + 1770716;               // 7,680,000
  float* h1 = ws + 9450716;
  float* z0 = ws + 17130716;
  float* z1 = ws + 24810716;
  float* el0 = ws + 32490716;
  float* er0 = ws + 32610716;
  float* el1 = ws + 32730716;
  float* er1 = ws + 32850716;
  float* Femb = ws + 32970716;            // 1,920,000
  float* gcnA = ws + 34890716;
  float* gcnB = ws + 36810716;
  float* pbuf = ws + 38730716;            // 2*NPOOL = 15000
  float* trbuf = ws + 38745716;           // NTRB = 1875

  int* rows_g = rows + 2 * (NN + 1);
  int* cols_g = cols + 2 * NE;

  zero4_kernel<<<(52501 + 255) / 256, 256, 0, stream>>>((float4*)ws, 52501);

  // ---- CSR build for 3 graphs (by dst) ----
  hist_kernel<<<dim3(1875, 3), 256, 0, stream>>>(dst0, dst1, gdst, cnt);
  deg_src_kernel<<<1875, 256, 0, stream>>>(gsrc, dego);
  scan_blocks_kernel<<<dim3(NBLK, 3), 256, 0, stream>>>(cnt, rows, bsum);
  scan_tops_kernel<<<dim3(1, 3), 128, 0, stream>>>(bsum, boff);
  add_off_kernel<<<dim3(NBLK, 3), 256, 0, stream>>>(rows, boff);
  scatter_kernel<<<dim3(1875, 3), 256, 0, stream>>>(src0, src1, gsrc, dst0, dst1, gdst, rows,
                                                    cnt2, cols);
  rdeg2_kernel<<<NBLK, 256, 0, stream>>>(dego, rdi, rows_g);

  // ---- GAT dense projections ----
  gemm_nn<<<dim3(469, 4), 256, 0, stream>>>(feat0, Wgat0, h0, NN, 256, 256);
  gemm_nn<<<dim3(469, 4), 256, 0, stream>>>(feat1, Wgat1, h1, NN, 128, 256);
  eler_kernel<<<469, 256, 0, stream>>>(h0, al0, ar0, el0, er0);
  eler_kernel<<<469, 256, 0, stream>>>(h1, al1, ar1, el1, er1);

  // ---- GAT gather ----
  gat_node_kernel<<<7500, 256, 0, stream>>>(rows, cols, el0, er0, h0, b0, z0);
  gat_node_kernel<<<7500, 256, 0, stream>>>(rows + (NN + 1), cols + NE, el1, er1, h1, b1, z1);

  // ---- attention pooling -> beta -> Femb ----
  attn_pool_kernel<<<dim3(NPOOL, 2), 256, 0, stream>>>(z0, z1, Wp1, bp1, wp2, pbuf);
  attn_reduce_kernel<<<1, 256, 0, stream>>>(pbuf, wb);
  fused_femb_kernel<<<7500, 256, 0, stream>>>(z0, z1, wb, Wf, bf, Femb);

  // ---- GCN path ----
  gcn_gemm256_kernel<<<7500, 256, 0, stream>>>(sen, Wg1, dego, gcnA);
  gcn_gather1_kernel<<<7500, 256, 0, stream>>>(rows_g, cols_g, gcnA, rdi, bg1, gcnB);
  gcn_gemm64_kernel<<<7500, 256, 0, stream>>>(gcnB, Wg2, dego, gcnA);
  gcn_gather2_kernel<<<7500, 256, 0, stream>>>(rows_g, cols_g, gcnA, rdi, Femb, out);

  // ---- trace ----
  tr_kernel<<<NTRB, 256, 0, stream>>>(asrc, adst, kptr, out, trbuf);
  tr_reduce_kernel<<<1, 256, 0, stream>>>(trbuf, out);
}

// Round 4
// 860.897 us; speedup vs baseline: 5.7772x; 1.1969x over previous
//
#include <hip/hip_runtime.h>
#include <math.h>

#define NN 30000
#define NE 480000
#define NBLK 118   // ceil(30000/256)
#define NTB 469    // ceil(30000/64) tiles of 64 rows
#define NTRB 1875  // blocks in tr pass

// ---------------- fill kernels ----------------
__global__ void zero4_kernel(float4* __restrict__ p, int n4) {
  int g = blockIdx.x * 256 + threadIdx.x;
  if (g < n4) p[g] = make_float4(0.f, 0.f, 0.f, 0.f);
}

__device__ __forceinline__ float wred(float v) {
#pragma unroll
  for (int off = 32; off > 0; off >>= 1) v += __shfl_xor(v, off);
  return v;
}

// ---------------- fp32 GEMM: C[M,Nc] = A[M,K] @ B[K,Nc], tiles 64x64x16 ----------------
__global__ __launch_bounds__(256) void gemm_nn(const float* __restrict__ A,
                                               const float* __restrict__ B,
                                               float* __restrict__ C,
                                               int M, int K, int Nc) {
  __shared__ float As[16][64];
  __shared__ float Bs[16][64];
  int tid = threadIdx.x;
  int tx = tid & 15, ty = tid >> 4;
  int bm = blockIdx.x * 64, bn = blockIdx.y * 64;
  float acc[4][4] = {};
  for (int k0 = 0; k0 < K; k0 += 16) {
    {
      int r = tid >> 2, cq = tid & 3;
      int gr = bm + r;
      float4 a = make_float4(0.f, 0.f, 0.f, 0.f);
      if (gr < M) a = *(const float4*)&A[(size_t)gr * K + k0 + 4 * cq];
      As[4 * cq + 0][r] = a.x;
      As[4 * cq + 1][r] = a.y;
      As[4 * cq + 2][r] = a.z;
      As[4 * cq + 3][r] = a.w;
    }
    {
      int kr = tid >> 4, nc = (tid & 15) * 4;
      *(float4*)&Bs[kr][nc] = *(const float4*)&B[(size_t)(k0 + kr) * Nc + bn + nc];
    }
    __syncthreads();
#pragma unroll
    for (int kk = 0; kk < 16; ++kk) {
      float4 a4 = *(float4*)&As[kk][4 * ty];
      float4 b4 = *(float4*)&Bs[kk][4 * tx];
      float av[4] = {a4.x, a4.y, a4.z, a4.w};
      float bv[4] = {b4.x, b4.y, b4.z, b4.w};
#pragma unroll
      for (int i = 0; i < 4; ++i)
#pragma unroll
        for (int j = 0; j < 4; ++j) acc[i][j] = fmaf(av[i], bv[j], acc[i][j]);
    }
    __syncthreads();
  }
#pragma unroll
  for (int i = 0; i < 4; ++i) {
    int gr = bm + 4 * ty + i;
    if (gr < M) {
      float4 o = make_float4(acc[i][0], acc[i][1], acc[i][2], acc[i][3]);
      *(float4*)&C[(size_t)gr * Nc + bn + 4 * tx] = o;
    }
  }
}

// ---------------- el/er ----------------
__global__ void eler_kernel(const float* __restrict__ h, const float* __restrict__ al,
                            const float* __restrict__ ar, float* __restrict__ el,
                            float* __restrict__ er) {
  int gid = blockIdx.x * 256 + threadIdx.x;
  if (gid >= NN * 4) return;
  int n = gid >> 2, hh = gid & 3;
  const float4* hr = (const float4*)&h[(size_t)n * 256 + hh * 64];
  const float4* alr = (const float4*)&al[hh * 64];
  const float4* arr = (const float4*)&ar[hh * 64];
  float sl = 0.f, sr = 0.f;
#pragma unroll
  for (int q = 0; q < 16; ++q) {
    float4 hv = hr[q], a = alr[q], b = arr[q];
    sl += hv.x * a.x + hv.y * a.y + hv.z * a.z + hv.w * a.w;
    sr += hv.x * b.x + hv.y * b.y + hv.z * b.z + hv.w * b.w;
  }
  el[gid] = sl;
  er[gid] = sr;
}

// ---------------- CSR build: histogram over dst ----------------
__global__ void hist_kernel(const int* __restrict__ d0, const int* __restrict__ d1,
                            const int* __restrict__ d2, int* __restrict__ cnt) {
  int g = blockIdx.y;
  const int* d = g == 0 ? d0 : g == 1 ? d1 : d2;
  int e = blockIdx.x * 256 + threadIdx.x;
  if (e < NE) atomicAdd(&cnt[g * NN + d[e]], 1);
}

__global__ void deg_src_kernel(const int* __restrict__ gsrc, float* __restrict__ dego) {
  int e = blockIdx.x * 256 + threadIdx.x;
  if (e < NE) atomicAdd(&dego[gsrc[e]], 1.f);
}

// ---------------- hierarchical exclusive scan ----------------
__global__ __launch_bounds__(256) void scan_blocks_kernel(const int* __restrict__ cnt,
                                                          int* __restrict__ rows,
                                                          int* __restrict__ bsum) {
  __shared__ int sm[256];
  int g = blockIdx.y, t = threadIdx.x;
  int i = blockIdx.x * 256 + t;
  int v = (i < NN) ? cnt[g * NN + i] : 0;
  sm[t] = v;
  __syncthreads();
#pragma unroll
  for (int off = 1; off < 256; off <<= 1) {
    int tmp = (t >= off) ? sm[t - off] : 0;
    __syncthreads();
    sm[t] += tmp;
    __syncthreads();
  }
  if (i < NN) rows[g * (NN + 1) + i] = sm[t] - v;  // exclusive
  if (t == 255) bsum[g * NBLK + blockIdx.x] = sm[255];
}

__global__ __launch_bounds__(128) void scan_tops_kernel(int* __restrict__ bsum,
                                                        int* __restrict__ boff) {
  __shared__ int sm[128];
  int g = blockIdx.y, t = threadIdx.x;
  int v = (t < NBLK) ? bsum[g * NBLK + t] : 0;
  sm[t] = v;
  __syncthreads();
#pragma unroll
  for (int off = 1; off < 128; off <<= 1) {
    int tmp = (t >= off) ? sm[t - off] : 0;
    __syncthreads();
    sm[t] += tmp;
    __syncthreads();
  }
  if (t < NBLK) boff[g * NBLK + t] = sm[t] - v;  // exclusive
}

__global__ void add_off_kernel(int* __restrict__ rows, const int* __restrict__ boff) {
  int g = blockIdx.y, t = threadIdx.x;
  int i = blockIdx.x * 256 + t;
  if (i < NN) rows[g * (NN + 1) + i] += boff[g * NBLK + blockIdx.x];
  if (blockIdx.x == 0 && t == 0) rows[g * (NN + 1) + NN] = NE;
}

// ---------------- scatter into CSR col arrays ----------------
__global__ void scatter_kernel(const int* __restrict__ s0, const int* __restrict__ s1,
                               const int* __restrict__ s2, const int* __restrict__ d0,
                               const int* __restrict__ d1, const int* __restrict__ d2,
                               const int* __restrict__ rows, int* __restrict__ cnt2,
                               int* __restrict__ cols) {
  int g = blockIdx.y;
  const int* sp = g == 0 ? s0 : g == 1 ? s1 : s2;
  const int* dp = g == 0 ? d0 : g == 1 ? d1 : d2;
  int e = blockIdx.x * 256 + threadIdx.x;
  if (e >= NE) return;
  int d = dp[e];
  int pos = rows[g * (NN + 1) + d] + atomicAdd(&cnt2[g * NN + d], 1);
  cols[(size_t)g * NE + pos] = sp[e];
}

// ---------------- rdo/rdi ----------------
__global__ void rdeg2_kernel(float* __restrict__ rdo, float* __restrict__ rdi,
                             const int* __restrict__ rows_g) {
  int n = blockIdx.x * 256 + threadIdx.x;
  if (n >= NN) return;
  rdo[n] = rsqrtf(fmaxf(rdo[n], 1.f));
  float di = (float)(rows_g[n + 1] - rows_g[n]);
  rdi[n] = rsqrtf(fmaxf(di, 1.f));
}

// ---------------- GAT per-node gather: softmax + weighted sum + bias + relu6 ----------------
__global__ __launch_bounds__(256) void gat_node_kernel(
    const int* __restrict__ rows, const int* __restrict__ cols, const float* __restrict__ el,
    const float* __restrict__ er, const float* __restrict__ h, const float* __restrict__ bias,
    float* __restrict__ z) {
  int lane = threadIdx.x & 63, w = threadIdx.x >> 6;
  int n = blockIdx.x * 4 + w;
  if (n >= NN) return;
  int r0 = rows[n], r1 = rows[n + 1];
  float4 er4 = *(const float4*)&er[n * 4];
  float s0 = 0.f, s1 = 0.f, s2 = 0.f, s3 = 0.f;
  for (int j = r0 + lane; j < r1; j += 64) {
    int s = cols[j];
    float4 elv = *(const float4*)&el[s * 4];
    float v0 = elv.x + er4.x; v0 = v0 > 0.f ? v0 : 0.2f * v0;
    float v1 = elv.y + er4.y; v1 = v1 > 0.f ? v1 : 0.2f * v1;
    float v2 = elv.z + er4.z; v2 = v2 > 0.f ? v2 : 0.2f * v2;
    float v3 = elv.w + er4.w; v3 = v3 > 0.f ? v3 : 0.2f * v3;
    s0 += __expf(v0); s1 += __expf(v1); s2 += __expf(v2); s3 += __expf(v3);
  }
  s0 = wred(s0); s1 = wred(s1); s2 = wred(s2); s3 = wred(s3);
  int hh = lane >> 4;
  float denom = hh == 0 ? s0 : hh == 1 ? s1 : hh == 2 ? s2 : s3;
  float myer = hh == 0 ? er4.x : hh == 1 ? er4.y : hh == 2 ? er4.z : er4.w;
  float invd = (r1 > r0) ? 1.f / denom : 0.f;
  float4 acc = make_float4(0.f, 0.f, 0.f, 0.f);
  for (int j = r0; j < r1; ++j) {
    int s = cols[j];
    float v = el[s * 4 + hh] + myer;
    v = v > 0.f ? v : 0.2f * v;
    float a = __expf(v) * invd;
    float4 hv = *(const float4*)&h[(size_t)s * 256 + lane * 4];
    acc.x = fmaf(a, hv.x, acc.x);
    acc.y = fmaf(a, hv.y, acc.y);
    acc.z = fmaf(a, hv.z, acc.z);
    acc.w = fmaf(a, hv.w, acc.w);
  }
  float4 bv = *(const float4*)&bias[lane * 4];
  acc.x = fminf(fmaxf(acc.x + bv.x, 0.f), 6.f);
  acc.y = fminf(fmaxf(acc.y + bv.y, 0.f), 6.f);
  acc.z = fminf(fmaxf(acc.z + bv.z, 0.f), 6.f);
  acc.w = fminf(fmaxf(acc.w + bv.w, 0.f), 6.f);
  *(float4*)&z[(size_t)n * 256 + lane * 4] = acc;
}

// ================= tiled 30000x256 @ 256x64 GEMM family =================
// Shared tile structure: block=256, tile M=64, full K=256, N=64.
// As staged per 16-k slab; Bs (W) staged likewise -> W amortized over 64 rows.

// ---- attn: partial[block] = sum_rows tanh(row@Wp1+bp1).wp2 ----
__global__ __launch_bounds__(256) void attn_gemm_kernel(
    const float* __restrict__ z0, const float* __restrict__ z1, const float* __restrict__ Wp1,
    const float* __restrict__ bp1, const float* __restrict__ wp2, float* __restrict__ pbuf) {
  __shared__ float As[16][64];
  __shared__ float Bs[16][64];
  __shared__ float wsum[4];
  const float* A = blockIdx.y ? z1 : z0;
  int tid = threadIdx.x;
  int tx = tid & 15, ty = tid >> 4;
  int bm = blockIdx.x * 64;
  float acc[4][4] = {};
  for (int k0 = 0; k0 < 256; k0 += 16) {
    {
      int r = tid >> 2, cq = tid & 3;
      int gr = bm + r;
      float4 a = make_float4(0.f, 0.f, 0.f, 0.f);
      if (gr < NN) a = *(const float4*)&A[(size_t)gr * 256 + k0 + 4 * cq];
      As[4 * cq + 0][r] = a.x;
      As[4 * cq + 1][r] = a.y;
      As[4 * cq + 2][r] = a.z;
      As[4 * cq + 3][r] = a.w;
    }
    {
      int kr = tid >> 4, nc = (tid & 15) * 4;
      *(float4*)&Bs[kr][nc] = *(const float4*)&Wp1[(size_t)(k0 + kr) * 64 + nc];
    }
    __syncthreads();
#pragma unroll
    for (int kk = 0; kk < 16; ++kk) {
      float4 a4 = *(float4*)&As[kk][4 * ty];
      float4 b4 = *(float4*)&Bs[kk][4 * tx];
      float av[4] = {a4.x, a4.y, a4.z, a4.w};
      float bv[4] = {b4.x, b4.y, b4.z, b4.w};
#pragma unroll
      for (int i = 0; i < 4; ++i)
#pragma unroll
        for (int j = 0; j < 4; ++j) acc[i][j] = fmaf(av[i], bv[j], acc[i][j]);
    }
    __syncthreads();
  }
  float4 bp = *(const float4*)&bp1[4 * tx];
  float4 wp = *(const float4*)&wp2[4 * tx];
  float local = 0.f;
#pragma unroll
  for (int i = 0; i < 4; ++i) {
    if (bm + 4 * ty + i < NN) {
      local += tanhf(acc[i][0] + bp.x) * wp.x;
      local += tanhf(acc[i][1] + bp.y) * wp.y;
      local += tanhf(acc[i][2] + bp.z) * wp.z;
      local += tanhf(acc[i][3] + bp.w) * wp.w;
    }
  }
  local = wred(local);
  int lane = tid & 63, w = tid >> 6;
  if (lane == 0) wsum[w] = local;
  __syncthreads();
  if (tid == 0) pbuf[blockIdx.y * NTB + blockIdx.x] = wsum[0] + wsum[1] + wsum[2] + wsum[3];
}

// ---- reduce partials -> beta ----
__global__ __launch_bounds__(256) void attn_reduce_kernel(const float* __restrict__ pbuf,
                                                          float* __restrict__ wb) {
  __shared__ float sm[8];
  int t = threadIdx.x;
  float a0 = 0.f, a1 = 0.f;
  for (int i = t; i < NTB; i += 256) {
    a0 += pbuf[i];
    a1 += pbuf[NTB + i];
  }
  a0 = wred(a0);
  a1 = wred(a1);
  int lane = t & 63, w = t >> 6;
  if (lane == 0) { sm[w] = a0; sm[4 + w] = a1; }
  __syncthreads();
  if (t == 0) {
    float w0 = (sm[0] + sm[1] + sm[2] + sm[3]) * (1.0f / NN);
    float w1 = (sm[4] + sm[5] + sm[6] + sm[7]) * (1.0f / NN);
    float mx = fmaxf(w0, w1);
    float e0 = expf(w0 - mx), e1 = expf(w1 - mx);
    float inv = 1.f / (e0 + e1);
    wb[2] = e0 * inv;
    wb[3] = e1 * inv;
  }
}

// ---- femb: Femb = (b0*z0 + b1*z1) @ Wf + bf ----
__global__ __launch_bounds__(256) void femb_gemm_kernel(
    const float* __restrict__ z0, const float* __restrict__ z1, const float* __restrict__ wb,
    const float* __restrict__ Wf, const float* __restrict__ bf, float* __restrict__ Femb) {
  __shared__ float As[16][64];
  __shared__ float Bs[16][64];
  int tid = threadIdx.x;
  int tx = tid & 15, ty = tid >> 4;
  int bm = blockIdx.x * 64;
  float beta0 = wb[2], beta1 = wb[3];
  float acc[4][4] = {};
  for (int k0 = 0; k0 < 256; k0 += 16) {
    {
      int r = tid >> 2, cq = tid & 3;
      int gr = bm + r;
      float4 a = make_float4(0.f, 0.f, 0.f, 0.f);
      if (gr < NN) {
        float4 u = *(const float4*)&z0[(size_t)gr * 256 + k0 + 4 * cq];
        float4 v = *(const float4*)&z1[(size_t)gr * 256 + k0 + 4 * cq];
        a.x = beta0 * u.x + beta1 * v.x;
        a.y = beta0 * u.y + beta1 * v.y;
        a.z = beta0 * u.z + beta1 * v.z;
        a.w = beta0 * u.w + beta1 * v.w;
      }
      As[4 * cq + 0][r] = a.x;
      As[4 * cq + 1][r] = a.y;
      As[4 * cq + 2][r] = a.z;
      As[4 * cq + 3][r] = a.w;
    }
    {
      int kr = tid >> 4, nc = (tid & 15) * 4;
      *(float4*)&Bs[kr][nc] = *(const float4*)&Wf[(size_t)(k0 + kr) * 64 + nc];
    }
    __syncthreads();
#pragma unroll
    for (int kk = 0; kk < 16; ++kk) {
      float4 a4 = *(float4*)&As[kk][4 * ty];
      float4 b4 = *(float4*)&Bs[kk][4 * tx];
      float av[4] = {a4.x, a4.y, a4.z, a4.w};
      float bv[4] = {b4.x, b4.y, b4.z, b4.w};
#pragma unroll
      for (int i = 0; i < 4; ++i)
#pragma unroll
        for (int j = 0; j < 4; ++j) acc[i][j] = fmaf(av[i], bv[j], acc[i][j]);
    }
    __syncthreads();
  }
  float4 bfv = *(const float4*)&bf[4 * tx];
#pragma unroll
  for (int i = 0; i < 4; ++i) {
    int gr = bm + 4 * ty + i;
    if (gr < NN) {
      float4 o = make_float4(acc[i][0] + bfv.x, acc[i][1] + bfv.y, acc[i][2] + bfv.z,
                             acc[i][3] + bfv.w);
      *(float4*)&Femb[(size_t)gr * 64 + 4 * tx] = o;
    }
  }
}

// ---- gcn1: out = (sen @ Wg1) * rdo[n] ----
__global__ __launch_bounds__(256) void gcn1_gemm_kernel(const float* __restrict__ X,
                                                        const float* __restrict__ W,
                                                        const float* __restrict__ rdo,
                                                        float* __restrict__ out) {
  __shared__ float As[16][64];
  __shared__ float Bs[16][64];
  int tid = threadIdx.x;
  int tx = tid & 15, ty = tid >> 4;
  int bm = blockIdx.x * 64;
  float acc[4][4] = {};
  for (int k0 = 0; k0 < 256; k0 += 16) {
    {
      int r = tid >> 2, cq = tid & 3;
      int gr = bm + r;
      float4 a = make_float4(0.f, 0.f, 0.f, 0.f);
      if (gr < NN) a = *(const float4*)&X[(size_t)gr * 256 + k0 + 4 * cq];
      As[4 * cq + 0][r] = a.x;
      As[4 * cq + 1][r] = a.y;
      As[4 * cq + 2][r] = a.z;
      As[4 * cq + 3][r] = a.w;
    }
    {
      int kr = tid >> 4, nc = (tid & 15) * 4;
      *(float4*)&Bs[kr][nc] = *(const float4*)&W[(size_t)(k0 + kr) * 64 + nc];
    }
    __syncthreads();
#pragma unroll
    for (int kk = 0; kk < 16; ++kk) {
      float4 a4 = *(float4*)&As[kk][4 * ty];
      float4 b4 = *(float4*)&Bs[kk][4 * tx];
      float av[4] = {a4.x, a4.y, a4.z, a4.w};
      float bv[4] = {b4.x, b4.y, b4.z, b4.w};
#pragma unroll
      for (int i = 0; i < 4; ++i)
#pragma unroll
        for (int j = 0; j < 4; ++j) acc[i][j] = fmaf(av[i], bv[j], acc[i][j]);
    }
    __syncthreads();
  }
#pragma unroll
  for (int i = 0; i < 4; ++i) {
    int gr = bm + 4 * ty + i;
    if (gr < NN) {
      float r = rdo[gr];
      float4 o = make_float4(acc[i][0] * r, acc[i][1] * r, acc[i][2] * r, acc[i][3] * r);
      *(float4*)&out[(size_t)gr * 64 + 4 * tx] = o;
    }
  }
}

// ---------------- GCN gemm K=64 via shuffle ----------------
__global__ __launch_bounds__(256) void gcn_gemm64_kernel(const float* __restrict__ X,
                                                         const float* __restrict__ W,
                                                         const float* __restrict__ rdo,
                                                         float* __restrict__ out) {
  int lane = threadIdx.x & 63, w = threadIdx.x >> 6;
  int n = blockIdx.x * 4 + w;
  float x = X[(size_t)n * 64 + lane];
  float acc = 0.f;
#pragma unroll
  for (int k = 0; k < 64; ++k) acc = fmaf(__shfl(x, k), W[k * 64 + lane], acc);
  out[(size_t)n * 64 + lane] = acc * rdo[n];
}

// ---------------- GCN gather layer1: tanh(agg*rdi + bg1) ----------------
__global__ __launch_bounds__(256) void gcn_gather1_kernel(
    const int* __restrict__ rows, const int* __restrict__ cols, const float* __restrict__ X,
    const float* __restrict__ rdi, const float* __restrict__ bg1, float* __restrict__ out) {
  int lane = threadIdx.x & 63, w = threadIdx.x >> 6;
  int n = blockIdx.x * 4 + w;
  if (n >= NN) return;
  int r0 = rows[n], r1 = rows[n + 1];
  float acc = 0.f;
  for (int j = r0; j < r1; ++j) {
    int s = cols[j];
    acc += X[(size_t)s * 64 + lane];
  }
  out[(size_t)n * 64 + lane] = tanhf(acc * rdi[n] + bg1[lane]);
}

// ---------------- GCN gather layer2 fused with Z-final write ----------------
__global__ __launch_bounds__(256) void gcn_gather2_kernel(
    const int* __restrict__ rows, const int* __restrict__ cols, const float* __restrict__ X,
    const float* __restrict__ rdi, const float* __restrict__ Femb, float* __restrict__ dout) {
  int lane = threadIdx.x & 63, w = threadIdx.x >> 6;
  int n = blockIdx.x * 4 + w;
  if (n >= NN) return;
  int r0 = rows[n], r1 = rows[n + 1];
  float acc = 0.f;
  for (int j = r0; j < r1; ++j) {
    int s = cols[j];
    acc += X[(size_t)s * 64 + lane];
  }
  dout[1 + (size_t)n * 64 + lane] = 0.5f * (Femb[(size_t)n * 64 + lane] + acc * rdi[n]);
}

// ---------------- trace: per-block partials ----------------
__global__ __launch_bounds__(256) void tr_kernel(const int* __restrict__ asrc,
                                                 const int* __restrict__ adst,
                                                 const int* __restrict__ kptr,
                                                 const float* __restrict__ dout,
                                                 float* __restrict__ trbuf) {
  __shared__ float wsum[4];
  int e = blockIdx.x * 256 + threadIdx.x;
  int k = *kptr;
  float local = 0.f;
  if (e < NE) {
    int a = asrc[e], b = adst[e];
    const float* Za = dout + 1 + (size_t)a * 64;
    const float* Zb = dout + 1 + (size_t)b * 64;
    for (int c = 0; c < k; ++c) {
      float d2 = Za[c] - Zb[c];
      local += d2 * d2;
    }
  }
#pragma unroll
  for (int off = 32; off > 0; off >>= 1) local += __shfl_down(local, off);
  int lane = threadIdx.x & 63, w = threadIdx.x >> 6;
  if (lane == 0) wsum[w] = local;
  __syncthreads();
  if (threadIdx.x == 0) trbuf[blockIdx.x] = wsum[0] + wsum[1] + wsum[2] + wsum[3];
}

__global__ __launch_bounds__(256) void tr_reduce_kernel(const float* __restrict__ trbuf,
                                                        float* __restrict__ dout) {
  __shared__ float sm[4];
  int t = threadIdx.x;
  float a = 0.f;
  for (int i = t; i < NTRB; i += 256) a += trbuf[i];
  a = wred(a);
  int lane = t & 63, w = t >> 6;
  if (lane == 0) sm[w] = a;
  __syncthreads();
  if (t == 0) dout[0] = 0.5f * (sm[0] + sm[1] + sm[2] + sm[3]);
}

extern "C" void kernel_launch(void* const* d_in, const int* in_sizes, int n_in, void* d_out,
                              int out_size, void* d_ws, size_t ws_size, hipStream_t stream) {
  const float* feat0 = (const float*)d_in[0];
  const float* feat1 = (const float*)d_in[1];
  const float* sen = (const float*)d_in[2];
  const float* Wgat0 = (const float*)d_in[3];
  const float* al0 = (const float*)d_in[4];
  const float* ar0 = (const float*)d_in[5];
  const float* b0 = (const float*)d_in[6];
  const float* Wgat1 = (const float*)d_in[7];
  const float* al1 = (const float*)d_in[8];
  const float* ar1 = (const float*)d_in[9];
  const float* b1 = (const float*)d_in[10];
  const float* Wp1 = (const float*)d_in[11];
  const float* bp1 = (const float*)d_in[12];
  const float* wp2 = (const float*)d_in[13];
  const float* Wf = (const float*)d_in[14];
  const float* bf = (const float*)d_in[15];
  const float* Wg1 = (const float*)d_in[16];
  const float* bg1 = (const float*)d_in[17];
  const float* Wg2 = (const float*)d_in[18];
  const int* src0 = (const int*)d_in[19];
  const int* dst0 = (const int*)d_in[20];
  const int* src1 = (const int*)d_in[21];
  const int* dst1 = (const int*)d_in[22];
  const int* gsrc = (const int*)d_in[23];
  const int* gdst = (const int*)d_in[24];
  const int* asrc = (const int*)d_in[25];
  const int* adst = (const int*)d_in[26];
  const int* kptr = (const int*)d_in[27];
  float* out = (float*)d_out;
  float* ws = (float*)d_ws;

  // ---- workspace layout ----
  // ZERO region [0 .. 210004): dego(30000) wb(4) cnt(90000 int) cnt2(90000 int)
  float* dego = ws;                       // 30000
  float* wb = ws + 30000;                 // 4
  int* cnt = (int*)(ws + 30004);          // 3*30000
  int* cnt2 = (int*)(ws + 120004);        // 3*30000
  float* rdi = ws + 210004;               // 30000
  int* rows = (int*)(ws + 240004);        // 3*(NN+1) = 90003
  int* bsum = (int*)(ws + 330007);        // 354
  int* boff = (int*)(ws + 330361);        // 354
  int* cols = (int*)(ws + 330716);        // 3*NE
  float* h0 = ws + 1770716;               // 7,680,000
  float* h1 = ws + 9450716;
  float* z0 = ws + 17130716;
  float* z1 = ws + 24810716;
  float* el0 = ws + 32490716;
  float* er0 = ws + 32610716;
  float* el1 = ws + 32730716;
  float* er1 = ws + 32850716;
  float* Femb = ws + 32970716;            // 1,920,000
  float* gcnA = ws + 34890716;
  float* gcnB = ws + 36810716;
  float* pbuf = ws + 38730716;            // 2*NTB = 938
  float* trbuf = ws + 38731656;           // NTRB = 1875

  int* rows_g = rows + 2 * (NN + 1);
  int* cols_g = cols + 2 * NE;

  zero4_kernel<<<(52501 + 255) / 256, 256, 0, stream>>>((float4*)ws, 52501);

  // ---- CSR build for 3 graphs (by dst) ----
  hist_kernel<<<dim3(1875, 3), 256, 0, stream>>>(dst0, dst1, gdst, cnt);
  deg_src_kernel<<<1875, 256, 0, stream>>>(gsrc, dego);
  scan_blocks_kernel<<<dim3(NBLK, 3), 256, 0, stream>>>(cnt, rows, bsum);
  scan_tops_kernel<<<dim3(1, 3), 128, 0, stream>>>(bsum, boff);
  add_off_kernel<<<dim3(NBLK, 3), 256, 0, stream>>>(rows, boff);
  scatter_kernel<<<dim3(1875, 3), 256, 0, stream>>>(src0, src1, gsrc, dst0, dst1, gdst, rows,
                                                    cnt2, cols);
  rdeg2_kernel<<<NBLK, 256, 0, stream>>>(dego, rdi, rows_g);

  // ---- GAT dense projections ----
  gemm_nn<<<dim3(469, 4), 256, 0, stream>>>(feat0, Wgat0, h0, NN, 256, 256);
  gemm_nn<<<dim3(469, 4), 256, 0, stream>>>(feat1, Wgat1, h1, NN, 128, 256);
  eler_kernel<<<469, 256, 0, stream>>>(h0, al0, ar0, el0, er0);
  eler_kernel<<<469, 256, 0, stream>>>(h1, al1, ar1, el1, er1);

  // ---- GAT gather ----
  gat_node_kernel<<<7500, 256, 0, stream>>>(rows, cols, el0, er0, h0, b0, z0);
  gat_node_kernel<<<7500, 256, 0, stream>>>(rows + (NN + 1), cols + NE, el1, er1, h1, b1, z1);

  // ---- attention pooling (tiled GEMM) -> beta -> Femb (tiled GEMM) ----
  attn_gemm_kernel<<<dim3(NTB, 2), 256, 0, stream>>>(z0, z1, Wp1, bp1, wp2, pbuf);
  attn_reduce_kernel<<<1, 256, 0, stream>>>(pbuf, wb);
  femb_gemm_kernel<<<NTB, 256, 0, stream>>>(z0, z1, wb, Wf, bf, Femb);

  // ---- GCN path ----
  gcn1_gemm_kernel<<<NTB, 256, 0, stream>>>(sen, Wg1, dego, gcnA);
  gcn_gather1_kernel<<<7500, 256, 0, stream>>>(rows_g, cols_g, gcnA, rdi, bg1, gcnB);
  gcn_gemm64_kernel<<<7500, 256, 0, stream>>>(gcnB, Wg2, dego, gcnA);
  gcn_gather2_kernel<<<7500, 256, 0, stream>>>(rows_g, cols_g, gcnA, rdi, Femb, out);

  // ---- trace ----
  tr_kernel<<<NTRB, 256, 0, stream>>>(asrc, adst, kptr, out, trbuf);
  tr_reduce_kernel<<<1, 256, 0, stream>>>(trbuf, out);
}

// Round 5
// 788.424 us; speedup vs baseline: 6.3082x; 1.0919x over previous
//
#include <hip/hip_runtime.h>
#include <math.h>

#define NN 30000
#define NE 480000
#define NBLK 118   // ceil(30000/256)
#define NTB 469    // ceil(30000/64) tiles of 64 rows
#define NTRB 1875  // blocks in tr pass

typedef unsigned short ushort_t;
typedef unsigned int uint_t;

__device__ __forceinline__ ushort_t f2bf(float x) {
  uint_t u = __float_as_uint(x);
  u = (u + 0x7FFF + ((u >> 16) & 1)) >> 16;
  return (ushort_t)u;
}
__device__ __forceinline__ float bf2f(ushort_t v) {
  return __uint_as_float(((uint_t)v) << 16);
}

// ---------------- fill kernels ----------------
__global__ void zero4_kernel(float4* __restrict__ p, int n4) {
  int g = blockIdx.x * 256 + threadIdx.x;
  if (g < n4) p[g] = make_float4(0.f, 0.f, 0.f, 0.f);
}

__device__ __forceinline__ float wred(float v) {
#pragma unroll
  for (int off = 32; off > 0; off >>= 1) v += __shfl_xor(v, off);
  return v;
}

// ---------------- fp32 GEMM -> bf16 out: C[M,Nc] = A[M,K] @ B[K,Nc] ----------------
__global__ __launch_bounds__(256) void gemm_nn_bf16(const float* __restrict__ A,
                                                    const float* __restrict__ B,
                                                    ushort_t* __restrict__ C,
                                                    int M, int K, int Nc) {
  __shared__ float As[16][64];
  __shared__ float Bs[16][64];
  int tid = threadIdx.x;
  int tx = tid & 15, ty = tid >> 4;
  int bm = blockIdx.x * 64, bn = blockIdx.y * 64;
  float acc[4][4] = {};
  for (int k0 = 0; k0 < K; k0 += 16) {
    {
      int r = tid >> 2, cq = tid & 3;
      int gr = bm + r;
      float4 a = make_float4(0.f, 0.f, 0.f, 0.f);
      if (gr < M) a = *(const float4*)&A[(size_t)gr * K + k0 + 4 * cq];
      As[4 * cq + 0][r] = a.x;
      As[4 * cq + 1][r] = a.y;
      As[4 * cq + 2][r] = a.z;
      As[4 * cq + 3][r] = a.w;
    }
    {
      int kr = tid >> 4, nc = (tid & 15) * 4;
      *(float4*)&Bs[kr][nc] = *(const float4*)&B[(size_t)(k0 + kr) * Nc + bn + nc];
    }
    __syncthreads();
#pragma unroll
    for (int kk = 0; kk < 16; ++kk) {
      float4 a4 = *(float4*)&As[kk][4 * ty];
      float4 b4 = *(float4*)&Bs[kk][4 * tx];
      float av[4] = {a4.x, a4.y, a4.z, a4.w};
      float bv[4] = {b4.x, b4.y, b4.z, b4.w};
#pragma unroll
      for (int i = 0; i < 4; ++i)
#pragma unroll
        for (int j = 0; j < 4; ++j) acc[i][j] = fmaf(av[i], bv[j], acc[i][j]);
    }
    __syncthreads();
  }
#pragma unroll
  for (int i = 0; i < 4; ++i) {
    int gr = bm + 4 * ty + i;
    if (gr < M) {
      ushort4 o;
      o.x = f2bf(acc[i][0]);
      o.y = f2bf(acc[i][1]);
      o.z = f2bf(acc[i][2]);
      o.w = f2bf(acc[i][3]);
      *(ushort4*)&C[(size_t)gr * Nc + bn + 4 * tx] = o;
    }
  }
}

// ---------------- el/er from bf16 h ----------------
__global__ void eler_kernel(const ushort_t* __restrict__ h, const float* __restrict__ al,
                            const float* __restrict__ ar, float* __restrict__ el,
                            float* __restrict__ er) {
  int gid = blockIdx.x * 256 + threadIdx.x;
  if (gid >= NN * 4) return;
  int n = gid >> 2, hh = gid & 3;
  const ushort_t* hr = &h[(size_t)n * 256 + hh * 64];
  const float4* alr = (const float4*)&al[hh * 64];
  const float4* arr = (const float4*)&ar[hh * 64];
  float sl = 0.f, sr = 0.f;
#pragma unroll
  for (int q = 0; q < 16; ++q) {
    ushort4 hu = *(const ushort4*)&hr[q * 4];
    float4 hv = make_float4(bf2f(hu.x), bf2f(hu.y), bf2f(hu.z), bf2f(hu.w));
    float4 a = alr[q], b = arr[q];
    sl += hv.x * a.x + hv.y * a.y + hv.z * a.z + hv.w * a.w;
    sr += hv.x * b.x + hv.y * b.y + hv.z * b.z + hv.w * b.w;
  }
  el[gid] = sl;
  er[gid] = sr;
}

// ---------------- CSR build: histogram over dst ----------------
__global__ void hist_kernel(const int* __restrict__ d0, const int* __restrict__ d1,
                            const int* __restrict__ d2, int* __restrict__ cnt) {
  int g = blockIdx.y;
  const int* d = g == 0 ? d0 : g == 1 ? d1 : d2;
  int e = blockIdx.x * 256 + threadIdx.x;
  if (e < NE) atomicAdd(&cnt[g * NN + d[e]], 1);
}

__global__ void deg_src_kernel(const int* __restrict__ gsrc, float* __restrict__ dego) {
  int e = blockIdx.x * 256 + threadIdx.x;
  if (e < NE) atomicAdd(&dego[gsrc[e]], 1.f);
}

// ---------------- hierarchical exclusive scan ----------------
__global__ __launch_bounds__(256) void scan_blocks_kernel(const int* __restrict__ cnt,
                                                          int* __restrict__ rows,
                                                          int* __restrict__ bsum) {
  __shared__ int sm[256];
  int g = blockIdx.y, t = threadIdx.x;
  int i = blockIdx.x * 256 + t;
  int v = (i < NN) ? cnt[g * NN + i] : 0;
  sm[t] = v;
  __syncthreads();
#pragma unroll
  for (int off = 1; off < 256; off <<= 1) {
    int tmp = (t >= off) ? sm[t - off] : 0;
    __syncthreads();
    sm[t] += tmp;
    __syncthreads();
  }
  if (i < NN) rows[g * (NN + 1) + i] = sm[t] - v;  // exclusive
  if (t == 255) bsum[g * NBLK + blockIdx.x] = sm[255];
}

__global__ __launch_bounds__(128) void scan_tops_kernel(int* __restrict__ bsum,
                                                        int* __restrict__ boff) {
  __shared__ int sm[128];
  int g = blockIdx.y, t = threadIdx.x;
  int v = (t < NBLK) ? bsum[g * NBLK + t] : 0;
  sm[t] = v;
  __syncthreads();
#pragma unroll
  for (int off = 1; off < 128; off <<= 1) {
    int tmp = (t >= off) ? sm[t - off] : 0;
    __syncthreads();
    sm[t] += tmp;
    __syncthreads();
  }
  if (t < NBLK) boff[g * NBLK + t] = sm[t] - v;  // exclusive
}

__global__ void add_off_kernel(int* __restrict__ rows, const int* __restrict__ boff) {
  int g = blockIdx.y, t = threadIdx.x;
  int i = blockIdx.x * 256 + t;
  if (i < NN) rows[g * (NN + 1) + i] += boff[g * NBLK + blockIdx.x];
  if (blockIdx.x == 0 && t == 0) rows[g * (NN + 1) + NN] = NE;
}

// ---------------- scatter into CSR col arrays ----------------
__global__ void scatter_kernel(const int* __restrict__ s0, const int* __restrict__ s1,
                               const int* __restrict__ s2, const int* __restrict__ d0,
                               const int* __restrict__ d1, const int* __restrict__ d2,
                               const int* __restrict__ rows, int* __restrict__ cnt2,
                               int* __restrict__ cols) {
  int g = blockIdx.y;
  const int* sp = g == 0 ? s0 : g == 1 ? s1 : s2;
  const int* dp = g == 0 ? d0 : g == 1 ? d1 : d2;
  int e = blockIdx.x * 256 + threadIdx.x;
  if (e >= NE) return;
  int d = dp[e];
  int pos = rows[g * (NN + 1) + d] + atomicAdd(&cnt2[g * NN + d], 1);
  cols[(size_t)g * NE + pos] = sp[e];
}

// ---------------- rdo/rdi ----------------
__global__ void rdeg2_kernel(float* __restrict__ rdo, float* __restrict__ rdi,
                             const int* __restrict__ rows_g) {
  int n = blockIdx.x * 256 + threadIdx.x;
  if (n >= NN) return;
  rdo[n] = rsqrtf(fmaxf(rdo[n], 1.f));
  float di = (float)(rows_g[n + 1] - rows_g[n]);
  rdi[n] = rsqrtf(fmaxf(di, 1.f));
}

// ---------------- GAT per-node gather (both graphs via blockIdx.y), bf16 h ----------------
__global__ __launch_bounds__(256) void gat_node_kernel(
    const int* __restrict__ rows0, const int* __restrict__ cols0, const float* __restrict__ el0,
    const float* __restrict__ er0, const ushort_t* __restrict__ h0,
    const float* __restrict__ bias0, float* __restrict__ zz0, const int* __restrict__ rows1,
    const int* __restrict__ cols1, const float* __restrict__ el1, const float* __restrict__ er1,
    const ushort_t* __restrict__ h1, const float* __restrict__ bias1, float* __restrict__ zz1) {
  int g = blockIdx.y;
  const int* rows = g ? rows1 : rows0;
  const int* cols = g ? cols1 : cols0;
  const float* el = g ? el1 : el0;
  const float* er = g ? er1 : er0;
  const ushort_t* h = g ? h1 : h0;
  const float* bias = g ? bias1 : bias0;
  float* z = g ? zz1 : zz0;

  int lane = threadIdx.x & 63, w = threadIdx.x >> 6;
  int n = blockIdx.x * 4 + w;
  if (n >= NN) return;
  int r0 = rows[n], r1 = rows[n + 1];
  float4 er4 = *(const float4*)&er[n * 4];
  float s0 = 0.f, s1 = 0.f, s2 = 0.f, s3 = 0.f;
  for (int j = r0 + lane; j < r1; j += 64) {
    int s = cols[j];
    float4 elv = *(const float4*)&el[s * 4];
    float v0 = elv.x + er4.x; v0 = v0 > 0.f ? v0 : 0.2f * v0;
    float v1 = elv.y + er4.y; v1 = v1 > 0.f ? v1 : 0.2f * v1;
    float v2 = elv.z + er4.z; v2 = v2 > 0.f ? v2 : 0.2f * v2;
    float v3 = elv.w + er4.w; v3 = v3 > 0.f ? v3 : 0.2f * v3;
    s0 += __expf(v0); s1 += __expf(v1); s2 += __expf(v2); s3 += __expf(v3);
  }
  s0 = wred(s0); s1 = wred(s1); s2 = wred(s2); s3 = wred(s3);
  int hh = lane >> 4;
  float denom = hh == 0 ? s0 : hh == 1 ? s1 : hh == 2 ? s2 : s3;
  float myer = hh == 0 ? er4.x : hh == 1 ? er4.y : hh == 2 ? er4.z : er4.w;
  float invd = (r1 > r0) ? 1.f / denom : 0.f;
  float4 acc = make_float4(0.f, 0.f, 0.f, 0.f);
  for (int j = r0; j < r1; ++j) {
    int s = cols[j];
    float v = el[s * 4 + hh] + myer;
    v = v > 0.f ? v : 0.2f * v;
    float a = __expf(v) * invd;
    ushort4 hu = *(const ushort4*)&h[(size_t)s * 256 + lane * 4];
    acc.x = fmaf(a, bf2f(hu.x), acc.x);
    acc.y = fmaf(a, bf2f(hu.y), acc.y);
    acc.z = fmaf(a, bf2f(hu.z), acc.z);
    acc.w = fmaf(a, bf2f(hu.w), acc.w);
  }
  float4 bv = *(const float4*)&bias[lane * 4];
  acc.x = fminf(fmaxf(acc.x + bv.x, 0.f), 6.f);
  acc.y = fminf(fmaxf(acc.y + bv.y, 0.f), 6.f);
  acc.z = fminf(fmaxf(acc.z + bv.z, 0.f), 6.f);
  acc.w = fminf(fmaxf(acc.w + bv.w, 0.f), 6.f);
  *(float4*)&z[(size_t)n * 256 + lane * 4] = acc;
}

// ================= tiled 30000x256 @ 256x64 GEMM family =================

// ---- attn: partial[block] = sum_rows tanh(row@Wp1+bp1).wp2 ----
__global__ __launch_bounds__(256) void attn_gemm_kernel(
    const float* __restrict__ z0, const float* __restrict__ z1, const float* __restrict__ Wp1,
    const float* __restrict__ bp1, const float* __restrict__ wp2, float* __restrict__ pbuf) {
  __shared__ float As[16][64];
  __shared__ float Bs[16][64];
  __shared__ float wsum[4];
  const float* A = blockIdx.y ? z1 : z0;
  int tid = threadIdx.x;
  int tx = tid & 15, ty = tid >> 4;
  int bm = blockIdx.x * 64;
  float acc[4][4] = {};
  for (int k0 = 0; k0 < 256; k0 += 16) {
    {
      int r = tid >> 2, cq = tid & 3;
      int gr = bm + r;
      float4 a = make_float4(0.f, 0.f, 0.f, 0.f);
      if (gr < NN) a = *(const float4*)&A[(size_t)gr * 256 + k0 + 4 * cq];
      As[4 * cq + 0][r] = a.x;
      As[4 * cq + 1][r] = a.y;
      As[4 * cq + 2][r] = a.z;
      As[4 * cq + 3][r] = a.w;
    }
    {
      int kr = tid >> 4, nc = (tid & 15) * 4;
      *(float4*)&Bs[kr][nc] = *(const float4*)&Wp1[(size_t)(k0 + kr) * 64 + nc];
    }
    __syncthreads();
#pragma unroll
    for (int kk = 0; kk < 16; ++kk) {
      float4 a4 = *(float4*)&As[kk][4 * ty];
      float4 b4 = *(float4*)&Bs[kk][4 * tx];
      float av[4] = {a4.x, a4.y, a4.z, a4.w};
      float bv[4] = {b4.x, b4.y, b4.z, b4.w};
#pragma unroll
      for (int i = 0; i < 4; ++i)
#pragma unroll
        for (int j = 0; j < 4; ++j) acc[i][j] = fmaf(av[i], bv[j], acc[i][j]);
    }
    __syncthreads();
  }
  float4 bp = *(const float4*)&bp1[4 * tx];
  float4 wp = *(const float4*)&wp2[4 * tx];
  float local = 0.f;
#pragma unroll
  for (int i = 0; i < 4; ++i) {
    if (bm + 4 * ty + i < NN) {
      local += tanhf(acc[i][0] + bp.x) * wp.x;
      local += tanhf(acc[i][1] + bp.y) * wp.y;
      local += tanhf(acc[i][2] + bp.z) * wp.z;
      local += tanhf(acc[i][3] + bp.w) * wp.w;
    }
  }
  local = wred(local);
  int lane = tid & 63, w = tid >> 6;
  if (lane == 0) wsum[w] = local;
  __syncthreads();
  if (tid == 0) pbuf[blockIdx.y * NTB + blockIdx.x] = wsum[0] + wsum[1] + wsum[2] + wsum[3];
}

// ---- reduce partials -> beta ----
__global__ __launch_bounds__(256) void attn_reduce_kernel(const float* __restrict__ pbuf,
                                                          float* __restrict__ wb) {
  __shared__ float sm[8];
  int t = threadIdx.x;
  float a0 = 0.f, a1 = 0.f;
  for (int i = t; i < NTB; i += 256) {
    a0 += pbuf[i];
    a1 += pbuf[NTB + i];
  }
  a0 = wred(a0);
  a1 = wred(a1);
  int lane = t & 63, w = t >> 6;
  if (lane == 0) { sm[w] = a0; sm[4 + w] = a1; }
  __syncthreads();
  if (t == 0) {
    float w0 = (sm[0] + sm[1] + sm[2] + sm[3]) * (1.0f / NN);
    float w1 = (sm[4] + sm[5] + sm[6] + sm[7]) * (1.0f / NN);
    float mx = fmaxf(w0, w1);
    float e0 = expf(w0 - mx), e1 = expf(w1 - mx);
    float inv = 1.f / (e0 + e1);
    wb[2] = e0 * inv;
    wb[3] = e1 * inv;
  }
}

// ---- femb: Femb = (b0*z0 + b1*z1) @ Wf + bf ----
__global__ __launch_bounds__(256) void femb_gemm_kernel(
    const float* __restrict__ z0, const float* __restrict__ z1, const float* __restrict__ wb,
    const float* __restrict__ Wf, const float* __restrict__ bf, float* __restrict__ Femb) {
  __shared__ float As[16][64];
  __shared__ float Bs[16][64];
  int tid = threadIdx.x;
  int tx = tid & 15, ty = tid >> 4;
  int bm = blockIdx.x * 64;
  float beta0 = wb[2], beta1 = wb[3];
  float acc[4][4] = {};
  for (int k0 = 0; k0 < 256; k0 += 16) {
    {
      int r = tid >> 2, cq = tid & 3;
      int gr = bm + r;
      float4 a = make_float4(0.f, 0.f, 0.f, 0.f);
      if (gr < NN) {
        float4 u = *(const float4*)&z0[(size_t)gr * 256 + k0 + 4 * cq];
        float4 v = *(const float4*)&z1[(size_t)gr * 256 + k0 + 4 * cq];
        a.x = beta0 * u.x + beta1 * v.x;
        a.y = beta0 * u.y + beta1 * v.y;
        a.z = beta0 * u.z + beta1 * v.z;
        a.w = beta0 * u.w + beta1 * v.w;
      }
      As[4 * cq + 0][r] = a.x;
      As[4 * cq + 1][r] = a.y;
      As[4 * cq + 2][r] = a.z;
      As[4 * cq + 3][r] = a.w;
    }
    {
      int kr = tid >> 4, nc = (tid & 15) * 4;
      *(float4*)&Bs[kr][nc] = *(const float4*)&Wf[(size_t)(k0 + kr) * 64 + nc];
    }
    __syncthreads();
#pragma unroll
    for (int kk = 0; kk < 16; ++kk) {
      float4 a4 = *(float4*)&As[kk][4 * ty];
      float4 b4 = *(float4*)&Bs[kk][4 * tx];
      float av[4] = {a4.x, a4.y, a4.z, a4.w};
      float bv[4] = {b4.x, b4.y, b4.z, b4.w};
#pragma unroll
      for (int i = 0; i < 4; ++i)
#pragma unroll
        for (int j = 0; j < 4; ++j) acc[i][j] = fmaf(av[i], bv[j], acc[i][j]);
    }
    __syncthreads();
  }
  float4 bfv = *(const float4*)&bf[4 * tx];
#pragma unroll
  for (int i = 0; i < 4; ++i) {
    int gr = bm + 4 * ty + i;
    if (gr < NN) {
      float4 o = make_float4(acc[i][0] + bfv.x, acc[i][1] + bfv.y, acc[i][2] + bfv.z,
                             acc[i][3] + bfv.w);
      *(float4*)&Femb[(size_t)gr * 64 + 4 * tx] = o;
    }
  }
}

// ---- gcn1: out = bf16((sen @ Wg1) * rdo[n]) ----
__global__ __launch_bounds__(256) void gcn1_gemm_kernel(const float* __restrict__ X,
                                                        const float* __restrict__ W,
                                                        const float* __restrict__ rdo,
                                                        ushort_t* __restrict__ out) {
  __shared__ float As[16][64];
  __shared__ float Bs[16][64];
  int tid = threadIdx.x;
  int tx = tid & 15, ty = tid >> 4;
  int bm = blockIdx.x * 64;
  float acc[4][4] = {};
  for (int k0 = 0; k0 < 256; k0 += 16) {
    {
      int r = tid >> 2, cq = tid & 3;
      int gr = bm + r;
      float4 a = make_float4(0.f, 0.f, 0.f, 0.f);
      if (gr < NN) a = *(const float4*)&X[(size_t)gr * 256 + k0 + 4 * cq];
      As[4 * cq + 0][r] = a.x;
      As[4 * cq + 1][r] = a.y;
      As[4 * cq + 2][r] = a.z;
      As[4 * cq + 3][r] = a.w;
    }
    {
      int kr = tid >> 4, nc = (tid & 15) * 4;
      *(float4*)&Bs[kr][nc] = *(const float4*)&W[(size_t)(k0 + kr) * 64 + nc];
    }
    __syncthreads();
#pragma unroll
    for (int kk = 0; kk < 16; ++kk) {
      float4 a4 = *(float4*)&As[kk][4 * ty];
      float4 b4 = *(float4*)&Bs[kk][4 * tx];
      float av[4] = {a4.x, a4.y, a4.z, a4.w};
      float bv[4] = {b4.x, b4.y, b4.z, b4.w};
#pragma unroll
      for (int i = 0; i < 4; ++i)
#pragma unroll
        for (int j = 0; j < 4; ++j) acc[i][j] = fmaf(av[i], bv[j], acc[i][j]);
    }
    __syncthreads();
  }
#pragma unroll
  for (int i = 0; i < 4; ++i) {
    int gr = bm + 4 * ty + i;
    if (gr < NN) {
      float r = rdo[gr];
      ushort4 o;
      o.x = f2bf(acc[i][0] * r);
      o.y = f2bf(acc[i][1] * r);
      o.z = f2bf(acc[i][2] * r);
      o.w = f2bf(acc[i][3] * r);
      *(ushort4*)&out[(size_t)gr * 64 + 4 * tx] = o;
    }
  }
}

// ---------------- GCN gather layer1 (bf16 table): tanh(agg*rdi + bg1) -> fp32 ----------------
__global__ __launch_bounds__(256) void gcn_gather1_kernel(
    const int* __restrict__ rows, const int* __restrict__ cols, const ushort_t* __restrict__ X,
    const float* __restrict__ rdi, const float* __restrict__ bg1, float* __restrict__ out) {
  int lane = threadIdx.x & 63, w = threadIdx.x >> 6;
  int n = blockIdx.x * 4 + w;
  if (n >= NN) return;
  int r0 = rows[n], r1 = rows[n + 1];
  float acc = 0.f;
  for (int j = r0; j < r1; ++j) {
    int s = cols[j];
    acc += bf2f(X[(size_t)s * 64 + lane]);
  }
  out[(size_t)n * 64 + lane] = tanhf(acc * rdi[n] + bg1[lane]);
}

// ---------------- GCN gemm K=64 via shuffle -> bf16 out ----------------
__global__ __launch_bounds__(256) void gcn_gemm64_kernel(const float* __restrict__ X,
                                                         const float* __restrict__ W,
                                                         const float* __restrict__ rdo,
                                                         ushort_t* __restrict__ out) {
  int lane = threadIdx.x & 63, w = threadIdx.x >> 6;
  int n = blockIdx.x * 4 + w;
  float x = X[(size_t)n * 64 + lane];
  float acc = 0.f;
#pragma unroll
  for (int k = 0; k < 64; ++k) acc = fmaf(__shfl(x, k), W[k * 64 + lane], acc);
  out[(size_t)n * 64 + lane] = f2bf(acc * rdo[n]);
}

// ---------------- GCN gather layer2 (bf16 table) fused with Z-final write ----------------
__global__ __launch_bounds__(256) void gcn_gather2_kernel(
    const int* __restrict__ rows, const int* __restrict__ cols, const ushort_t* __restrict__ X,
    const float* __restrict__ rdi, const float* __restrict__ Femb, float* __restrict__ dout) {
  int lane = threadIdx.x & 63, w = threadIdx.x >> 6;
  int n = blockIdx.x * 4 + w;
  if (n >= NN) return;
  int r0 = rows[n], r1 = rows[n + 1];
  float acc = 0.f;
  for (int j = r0; j < r1; ++j) {
    int s = cols[j];
    acc += bf2f(X[(size_t)s * 64 + lane]);
  }
  dout[1 + (size_t)n * 64 + lane] = 0.5f * (Femb[(size_t)n * 64 + lane] + acc * rdi[n]);
}

// ---------------- trace: per-block partials ----------------
__global__ __launch_bounds__(256) void tr_kernel(const int* __restrict__ asrc,
                                                 const int* __restrict__ adst,
                                                 const int* __restrict__ kptr,
                                                 const float* __restrict__ dout,
                                                 float* __restrict__ trbuf) {
  __shared__ float wsum[4];
  int e = blockIdx.x * 256 + threadIdx.x;
  int k = *kptr;
  float local = 0.f;
  if (e < NE) {
    int a = asrc[e], b = adst[e];
    const float* Za = dout + 1 + (size_t)a * 64;
    const float* Zb = dout + 1 + (size_t)b * 64;
    for (int c = 0; c < k; ++c) {
      float d2 = Za[c] - Zb[c];
      local += d2 * d2;
    }
  }
#pragma unroll
  for (int off = 32; off > 0; off >>= 1) local += __shfl_down(local, off);
  int lane = threadIdx.x & 63, w = threadIdx.x >> 6;
  if (lane == 0) wsum[w] = local;
  __syncthreads();
  if (threadIdx.x == 0) trbuf[blockIdx.x] = wsum[0] + wsum[1] + wsum[2] + wsum[3];
}

__global__ __launch_bounds__(256) void tr_reduce_kernel(const float* __restrict__ trbuf,
                                                        float* __restrict__ dout) {
  __shared__ float sm[4];
  int t = threadIdx.x;
  float a = 0.f;
  for (int i = t; i < NTRB; i += 256) a += trbuf[i];
  a = wred(a);
  int lane = t & 63, w = t >> 6;
  if (lane == 0) sm[w] = a;
  __syncthreads();
  if (t == 0) dout[0] = 0.5f * (sm[0] + sm[1] + sm[2] + sm[3]);
}

extern "C" void kernel_launch(void* const* d_in, const int* in_sizes, int n_in, void* d_out,
                              int out_size, void* d_ws, size_t ws_size, hipStream_t stream) {
  const float* feat0 = (const float*)d_in[0];
  const float* feat1 = (const float*)d_in[1];
  const float* sen = (const float*)d_in[2];
  const float* Wgat0 = (const float*)d_in[3];
  const float* al0 = (const float*)d_in[4];
  const float* ar0 = (const float*)d_in[5];
  const float* b0 = (const float*)d_in[6];
  const float* Wgat1 = (const float*)d_in[7];
  const float* al1 = (const float*)d_in[8];
  const float* ar1 = (const float*)d_in[9];
  const float* b1 = (const float*)d_in[10];
  const float* Wp1 = (const float*)d_in[11];
  const float* bp1 = (const float*)d_in[12];
  const float* wp2 = (const float*)d_in[13];
  const float* Wf = (const float*)d_in[14];
  const float* bf = (const float*)d_in[15];
  const float* Wg1 = (const float*)d_in[16];
  const float* bg1 = (const float*)d_in[17];
  const float* Wg2 = (const float*)d_in[18];
  const int* src0 = (const int*)d_in[19];
  const int* dst0 = (const int*)d_in[20];
  const int* src1 = (const int*)d_in[21];
  const int* dst1 = (const int*)d_in[22];
  const int* gsrc = (const int*)d_in[23];
  const int* gdst = (const int*)d_in[24];
  const int* asrc = (const int*)d_in[25];
  const int* adst = (const int*)d_in[26];
  const int* kptr = (const int*)d_in[27];
  float* out = (float*)d_out;
  float* ws = (float*)d_ws;

  // ---- workspace layout (float-element offsets) ----
  float* dego = ws;                        // 30000
  float* wb = ws + 30000;                  // 4
  int* cnt = (int*)(ws + 30004);           // 90000
  int* cnt2 = (int*)(ws + 120004);         // 90000
  float* rdi = ws + 210004;                // 30000
  int* rows = (int*)(ws + 240004);         // 90003
  int* bsum = (int*)(ws + 330007);         // 354
  int* boff = (int*)(ws + 330361);         // 354
  int* cols = (int*)(ws + 330716);         // 1,440,000
  float* z0 = ws + 1770716;                // 7,680,000
  float* z1 = ws + 9450716;                // 7,680,000
  float* el0 = ws + 17130716;              // 120000
  float* er0 = ws + 17250716;              // 120000
  float* el1 = ws + 17370716;              // 120000
  float* er1 = ws + 17490716;              // 120000
  float* Femb = ws + 17610716;             // 1,920,000
  float* gcnB = ws + 19530716;             // 1,920,000
  float* pbuf = ws + 21450716;             // 2*NTB
  float* trbuf = ws + 21451656;            // NTRB
  ushort_t* h0 = (ushort_t*)(ws + 21453532);   // 7,680,000 bf16 = 3,840,000 floats
  ushort_t* h1 = (ushort_t*)(ws + 25293532);   // 7,680,000 bf16
  ushort_t* gcnA = (ushort_t*)(ws + 29133532); // 1,920,000 bf16 = 960,000 floats
  ushort_t* gcnA2 = (ushort_t*)(ws + 30093532);// 1,920,000 bf16

  int* rows_g = rows + 2 * (NN + 1);
  int* cols_g = cols + 2 * NE;

  zero4_kernel<<<(52501 + 255) / 256, 256, 0, stream>>>((float4*)ws, 52501);

  // ---- CSR build for 3 graphs (by dst) ----
  hist_kernel<<<dim3(1875, 3), 256, 0, stream>>>(dst0, dst1, gdst, cnt);
  deg_src_kernel<<<1875, 256, 0, stream>>>(gsrc, dego);
  scan_blocks_kernel<<<dim3(NBLK, 3), 256, 0, stream>>>(cnt, rows, bsum);
  scan_tops_kernel<<<dim3(1, 3), 128, 0, stream>>>(bsum, boff);
  add_off_kernel<<<dim3(NBLK, 3), 256, 0, stream>>>(rows, boff);
  scatter_kernel<<<dim3(1875, 3), 256, 0, stream>>>(src0, src1, gsrc, dst0, dst1, gdst, rows,
                                                    cnt2, cols);
  rdeg2_kernel<<<NBLK, 256, 0, stream>>>(dego, rdi, rows_g);

  // ---- GAT dense projections (bf16 h out) ----
  gemm_nn_bf16<<<dim3(469, 4), 256, 0, stream>>>(feat0, Wgat0, h0, NN, 256, 256);
  gemm_nn_bf16<<<dim3(469, 4), 256, 0, stream>>>(feat1, Wgat1, h1, NN, 128, 256);
  eler_kernel<<<469, 256, 0, stream>>>(h0, al0, ar0, el0, er0);
  eler_kernel<<<469, 256, 0, stream>>>(h1, al1, ar1, el1, er1);

  // ---- GAT gather (both graphs in one launch) ----
  gat_node_kernel<<<dim3(7500, 2), 256, 0, stream>>>(rows, cols, el0, er0, h0, b0, z0,
                                                     rows + (NN + 1), cols + NE, el1, er1, h1,
                                                     b1, z1);

  // ---- attention pooling -> beta -> Femb ----
  attn_gemm_kernel<<<dim3(NTB, 2), 256, 0, stream>>>(z0, z1, Wp1, bp1, wp2, pbuf);
  attn_reduce_kernel<<<1, 256, 0, stream>>>(pbuf, wb);
  femb_gemm_kernel<<<NTB, 256, 0, stream>>>(z0, z1, wb, Wf, bf, Femb);

  // ---- GCN path ----
  gcn1_gemm_kernel<<<NTB, 256, 0, stream>>>(sen, Wg1, dego, gcnA);
  gcn_gather1_kernel<<<7500, 256, 0, stream>>>(rows_g, cols_g, gcnA, rdi, bg1, gcnB);
  gcn_gemm64_kernel<<<7500, 256, 0, stream>>>(gcnB, Wg2, dego, gcnA2);
  gcn_gather2_kernel<<<7500, 256, 0, stream>>>(rows_g, cols_g, gcnA2, rdi, Femb, out);

  // ---- trace ----
  tr_kernel<<<NTRB, 256, 0, stream>>>(asrc, adst, kptr, out, trbuf);
  tr_reduce_kernel<<<1, 256, 0, stream>>>(trbuf, out);
}

// Round 6
// 722.086 us; speedup vs baseline: 6.8877x; 1.0919x over previous
//
#include <hip/hip_runtime.h>
#include <math.h>

#define NN 30000
#define NE 480000
#define NBLK 118   // ceil(30000/256)
#define NMT 235    // ceil(30000/128) MFMA row-tiles
#define NTRB 1875  // blocks in tr pass

typedef unsigned short ushort_t;
typedef unsigned int uint_t;
typedef __attribute__((ext_vector_type(8))) short short8;
typedef __attribute__((ext_vector_type(4))) float f32x4;

__device__ __forceinline__ ushort_t f2bf(float x) {
  uint_t u = __float_as_uint(x);
  u = (u + 0x7FFF + ((u >> 16) & 1)) >> 16;
  return (ushort_t)u;
}
__device__ __forceinline__ float bf2f(ushort_t v) {
  return __uint_as_float(((uint_t)v) << 16);
}

// ---------------- fill kernels ----------------
__global__ void zero4_kernel(float4* __restrict__ p, int n4) {
  int g = blockIdx.x * 256 + threadIdx.x;
  if (g < n4) p[g] = make_float4(0.f, 0.f, 0.f, 0.f);
}

__device__ __forceinline__ float wred(float v) {
#pragma unroll
  for (int off = 32; off > 0; off >>= 1) v += __shfl_xor(v, off);
  return v;
}

// ---------------- weight prep: W[K][N] fp32 -> WT[N][K] bf16 ----------------
__global__ void wt_kernel(const float* __restrict__ W, ushort_t* __restrict__ WT, int K, int N) {
  int id = blockIdx.x * 256 + threadIdx.x;
  if (id >= K * N) return;
  int k = id / N, n = id - k * N;
  WT[(size_t)n * K + k] = f2bf(W[id]);
}

// ================= MFMA bf16 GEMM core =================
// BM=128, BN=64, BK=32; 256 threads = 4 waves; wave w owns rows [w*32, w*32+32).
// A fp32 (M x K) converted to bf16 during staging; BT bf16 [N][K] (pre-transposed).
// LDS rows padded to 40 shorts (80 B) -> 2-way-max bank aliasing (free).
template <bool BLEND>
__device__ __forceinline__ void mfma_core(const float* __restrict__ A0,
                                          const float* __restrict__ A1, float w0, float w1,
                                          const ushort_t* __restrict__ BT, int K, int bm,
                                          short* __restrict__ As, short* __restrict__ Bs,
                                          f32x4 acc[2][4]) {
  int tid = threadIdx.x;
  int lane = tid & 63, w = tid >> 6;
  int q = lane >> 4, mr = lane & 15;
#pragma unroll 1
  for (int k0 = 0; k0 < K; k0 += 32) {
    // ---- stage A tile (128 x 32 fp32 -> bf16) ----
    {
      int r = tid >> 1, hf = tid & 1;
      int gr = bm + r;
      float4 f0 = make_float4(0.f, 0.f, 0.f, 0.f), f1 = f0, f2 = f0, f3 = f0;
      if (gr < NN) {
        const float4* pa = (const float4*)(A0 + (size_t)gr * K + k0 + hf * 16);
        f0 = pa[0]; f1 = pa[1]; f2 = pa[2]; f3 = pa[3];
        if (BLEND) {
          const float4* pb = (const float4*)(A1 + (size_t)gr * K + k0 + hf * 16);
          float4 g0 = pb[0], g1 = pb[1], g2 = pb[2], g3 = pb[3];
          f0.x = w0 * f0.x + w1 * g0.x; f0.y = w0 * f0.y + w1 * g0.y;
          f0.z = w0 * f0.z + w1 * g0.z; f0.w = w0 * f0.w + w1 * g0.w;
          f1.x = w0 * f1.x + w1 * g1.x; f1.y = w0 * f1.y + w1 * g1.y;
          f1.z = w0 * f1.z + w1 * g1.z; f1.w = w0 * f1.w + w1 * g1.w;
          f2.x = w0 * f2.x + w1 * g2.x; f2.y = w0 * f2.y + w1 * g2.y;
          f2.z = w0 * f2.z + w1 * g2.z; f2.w = w0 * f2.w + w1 * g2.w;
          f3.x = w0 * f3.x + w1 * g3.x; f3.y = w0 * f3.y + w1 * g3.y;
          f3.z = w0 * f3.z + w1 * g3.z; f3.w = w0 * f3.w + w1 * g3.w;
        }
      }
      short8 lo, hi;
      lo[0] = (short)f2bf(f0.x); lo[1] = (short)f2bf(f0.y);
      lo[2] = (short)f2bf(f0.z); lo[3] = (short)f2bf(f0.w);
      lo[4] = (short)f2bf(f1.x); lo[5] = (short)f2bf(f1.y);
      lo[6] = (short)f2bf(f1.z); lo[7] = (short)f2bf(f1.w);
      hi[0] = (short)f2bf(f2.x); hi[1] = (short)f2bf(f2.y);
      hi[2] = (short)f2bf(f2.z); hi[3] = (short)f2bf(f2.w);
      hi[4] = (short)f2bf(f3.x); hi[5] = (short)f2bf(f3.y);
      hi[6] = (short)f2bf(f3.z); hi[7] = (short)f2bf(f3.w);
      short* dst = As + r * 40 + hf * 16;
      *(short8*)(dst) = lo;
      *(short8*)(dst + 8) = hi;
    }
    // ---- stage B tile (64 x 32 bf16, from BT[N][K]) ----
    {
      int n = tid >> 2, qk = tid & 3;
      short8 bv = *(const short8*)((const short*)BT + (size_t)n * K + k0 + qk * 8);
      *(short8*)(Bs + n * 40 + qk * 8) = bv;
    }
    __syncthreads();
    short8 a0 = *(short8*)(As + (w * 32 + mr) * 40 + q * 8);
    short8 a1 = *(short8*)(As + (w * 32 + 16 + mr) * 40 + q * 8);
#pragma unroll
    for (int j = 0; j < 4; ++j) {
      short8 b = *(short8*)(Bs + (j * 16 + mr) * 40 + q * 8);
      acc[0][j] = __builtin_amdgcn_mfma_f32_16x16x32_bf16(a0, b, acc[0][j], 0, 0, 0);
      acc[1][j] = __builtin_amdgcn_mfma_f32_16x16x32_bf16(a1, b, acc[1][j], 0, 0, 0);
    }
    __syncthreads();
  }
}

// ---- h = feat @ Wgat -> bf16 [NN][256], grid (NMT, 4) ----
__global__ __launch_bounds__(256) void mfma_h_kernel(const float* __restrict__ A,
                                                     const ushort_t* __restrict__ WT, int K,
                                                     ushort_t* __restrict__ H) {
  __shared__ short As[128 * 40];
  __shared__ short Bs[64 * 40];
  int bm = blockIdx.x * 128, bn = blockIdx.y * 64;
  f32x4 acc[2][4];
#pragma unroll
  for (int i = 0; i < 2; ++i)
#pragma unroll
    for (int j = 0; j < 4; ++j) acc[i][j] = (f32x4){0.f, 0.f, 0.f, 0.f};
  mfma_core<false>(A, nullptr, 0.f, 0.f, WT + (size_t)bn * K, K, bm, As, Bs, acc);
  int lane = threadIdx.x & 63, w = threadIdx.x >> 6;
  int q = lane >> 4, mr = lane & 15;
#pragma unroll
  for (int i = 0; i < 2; ++i)
#pragma unroll
    for (int j = 0; j < 4; ++j)
#pragma unroll
      for (int r = 0; r < 4; ++r) {
        int gr = bm + w * 32 + i * 16 + q * 4 + r;
        if (gr < NN) H[(size_t)gr * 256 + bn + j * 16 + mr] = f2bf(acc[i][j][r]);
      }
}

// ---- attn partials: sum tanh(z@Wp1+bp1)*wp2, grid (NMT, 2) ----
__global__ __launch_bounds__(256) void mfma_attn_kernel(
    const float* __restrict__ z0, const float* __restrict__ z1, const ushort_t* __restrict__ WT,
    const float* __restrict__ bp1, const float* __restrict__ wp2, float* __restrict__ pbuf) {
  __shared__ short As[128 * 40];
  __shared__ short Bs[64 * 40];
  __shared__ float wsum[4];
  const float* A = blockIdx.y ? z1 : z0;
  int bm = blockIdx.x * 128;
  f32x4 acc[2][4];
#pragma unroll
  for (int i = 0; i < 2; ++i)
#pragma unroll
    for (int j = 0; j < 4; ++j) acc[i][j] = (f32x4){0.f, 0.f, 0.f, 0.f};
  mfma_core<false>(A, nullptr, 0.f, 0.f, WT, 256, bm, As, Bs, acc);
  int lane = threadIdx.x & 63, w = threadIdx.x >> 6;
  int q = lane >> 4, mr = lane & 15;
  float local = 0.f;
#pragma unroll
  for (int j = 0; j < 4; ++j) {
    int col = j * 16 + mr;
    float bp = bp1[col], wp = wp2[col];
#pragma unroll
    for (int i = 0; i < 2; ++i)
#pragma unroll
      for (int r = 0; r < 4; ++r) {
        int gr = bm + w * 32 + i * 16 + q * 4 + r;
        if (gr < NN) local += tanhf(acc[i][j][r] + bp) * wp;
      }
  }
  local = wred(local);
  if (lane == 0) wsum[w] = local;
  __syncthreads();
  if (threadIdx.x == 0)
    pbuf[blockIdx.y * NMT + blockIdx.x] = wsum[0] + wsum[1] + wsum[2] + wsum[3];
}

// ---- femb: Femb = (b0*z0 + b1*z1) @ Wf + bf, grid (NMT) ----
__global__ __launch_bounds__(256) void mfma_femb_kernel(
    const float* __restrict__ z0, const float* __restrict__ z1, const float* __restrict__ wb,
    const ushort_t* __restrict__ WT, const float* __restrict__ bf, float* __restrict__ Femb) {
  __shared__ short As[128 * 40];
  __shared__ short Bs[64 * 40];
  int bm = blockIdx.x * 128;
  float beta0 = wb[2], beta1 = wb[3];
  f32x4 acc[2][4];
#pragma unroll
  for (int i = 0; i < 2; ++i)
#pragma unroll
    for (int j = 0; j < 4; ++j) acc[i][j] = (f32x4){0.f, 0.f, 0.f, 0.f};
  mfma_core<true>(z0, z1, beta0, beta1, WT, 256, bm, As, Bs, acc);
  int lane = threadIdx.x & 63, w = threadIdx.x >> 6;
  int q = lane >> 4, mr = lane & 15;
#pragma unroll
  for (int j = 0; j < 4; ++j) {
    int col = j * 16 + mr;
    float bv = bf[col];
#pragma unroll
    for (int i = 0; i < 2; ++i)
#pragma unroll
      for (int r = 0; r < 4; ++r) {
        int gr = bm + w * 32 + i * 16 + q * 4 + r;
        if (gr < NN) Femb[(size_t)gr * 64 + col] = acc[i][j][r] + bv;
      }
  }
}

// ---- gcn1: out = bf16((sen @ Wg1) * rdo), grid (NMT) ----
__global__ __launch_bounds__(256) void mfma_gcn1_kernel(const float* __restrict__ X,
                                                        const ushort_t* __restrict__ WT,
                                                        const float* __restrict__ rdo,
                                                        ushort_t* __restrict__ out) {
  __shared__ short As[128 * 40];
  __shared__ short Bs[64 * 40];
  int bm = blockIdx.x * 128;
  f32x4 acc[2][4];
#pragma unroll
  for (int i = 0; i < 2; ++i)
#pragma unroll
    for (int j = 0; j < 4; ++j) acc[i][j] = (f32x4){0.f, 0.f, 0.f, 0.f};
  mfma_core<false>(X, nullptr, 0.f, 0.f, WT, 256, bm, As, Bs, acc);
  int lane = threadIdx.x & 63, w = threadIdx.x >> 6;
  int q = lane >> 4, mr = lane & 15;
#pragma unroll
  for (int i = 0; i < 2; ++i)
#pragma unroll
    for (int r = 0; r < 4; ++r) {
      int gr = bm + w * 32 + i * 16 + q * 4 + r;
      if (gr < NN) {
        float sc = rdo[gr];
#pragma unroll
        for (int j = 0; j < 4; ++j) out[(size_t)gr * 64 + j * 16 + mr] = f2bf(acc[i][j][r] * sc);
      }
    }
}

// ---------------- el/er from bf16 h ----------------
__global__ void eler_kernel(const ushort_t* __restrict__ h, const float* __restrict__ al,
                            const float* __restrict__ ar, float* __restrict__ el,
                            float* __restrict__ er) {
  int gid = blockIdx.x * 256 + threadIdx.x;
  if (gid >= NN * 4) return;
  int n = gid >> 2, hh = gid & 3;
  const ushort_t* hr = &h[(size_t)n * 256 + hh * 64];
  const float4* alr = (const float4*)&al[hh * 64];
  const float4* arr = (const float4*)&ar[hh * 64];
  float sl = 0.f, sr = 0.f;
#pragma unroll
  for (int q = 0; q < 16; ++q) {
    ushort4 hu = *(const ushort4*)&hr[q * 4];
    float4 hv = make_float4(bf2f(hu.x), bf2f(hu.y), bf2f(hu.z), bf2f(hu.w));
    float4 a = alr[q], b = arr[q];
    sl += hv.x * a.x + hv.y * a.y + hv.z * a.z + hv.w * a.w;
    sr += hv.x * b.x + hv.y * b.y + hv.z * b.z + hv.w * b.w;
  }
  el[gid] = sl;
  er[gid] = sr;
}

// ---------------- CSR build ----------------
__global__ void hist_kernel(const int* __restrict__ d0, const int* __restrict__ d1,
                            const int* __restrict__ d2, int* __restrict__ cnt) {
  int g = blockIdx.y;
  const int* d = g == 0 ? d0 : g == 1 ? d1 : d2;
  int e = blockIdx.x * 256 + threadIdx.x;
  if (e < NE) atomicAdd(&cnt[g * NN + d[e]], 1);
}

__global__ void deg_src_kernel(const int* __restrict__ gsrc, float* __restrict__ dego) {
  int e = blockIdx.x * 256 + threadIdx.x;
  if (e < NE) atomicAdd(&dego[gsrc[e]], 1.f);
}

__global__ __launch_bounds__(256) void scan_blocks_kernel(const int* __restrict__ cnt,
                                                          int* __restrict__ rows,
                                                          int* __restrict__ bsum) {
  __shared__ int sm[256];
  int g = blockIdx.y, t = threadIdx.x;
  int i = blockIdx.x * 256 + t;
  int v = (i < NN) ? cnt[g * NN + i] : 0;
  sm[t] = v;
  __syncthreads();
#pragma unroll
  for (int off = 1; off < 256; off <<= 1) {
    int tmp = (t >= off) ? sm[t - off] : 0;
    __syncthreads();
    sm[t] += tmp;
    __syncthreads();
  }
  if (i < NN) rows[g * (NN + 1) + i] = sm[t] - v;  // exclusive
  if (t == 255) bsum[g * NBLK + blockIdx.x] = sm[255];
}

__global__ __launch_bounds__(128) void scan_tops_kernel(int* __restrict__ bsum,
                                                        int* __restrict__ boff) {
  __shared__ int sm[128];
  int g = blockIdx.y, t = threadIdx.x;
  int v = (t < NBLK) ? bsum[g * NBLK + t] : 0;
  sm[t] = v;
  __syncthreads();
#pragma unroll
  for (int off = 1; off < 128; off <<= 1) {
    int tmp = (t >= off) ? sm[t - off] : 0;
    __syncthreads();
    sm[t] += tmp;
    __syncthreads();
  }
  if (t < NBLK) boff[g * NBLK + t] = sm[t] - v;  // exclusive
}

__global__ void add_off_kernel(int* __restrict__ rows, const int* __restrict__ boff) {
  int g = blockIdx.y, t = threadIdx.x;
  int i = blockIdx.x * 256 + t;
  if (i < NN) rows[g * (NN + 1) + i] += boff[g * NBLK + blockIdx.x];
  if (blockIdx.x == 0 && t == 0) rows[g * (NN + 1) + NN] = NE;
}

__global__ void scatter_kernel(const int* __restrict__ s0, const int* __restrict__ s1,
                               const int* __restrict__ s2, const int* __restrict__ d0,
                               const int* __restrict__ d1, const int* __restrict__ d2,
                               const int* __restrict__ rows, int* __restrict__ cnt2,
                               int* __restrict__ cols) {
  int g = blockIdx.y;
  const int* sp = g == 0 ? s0 : g == 1 ? s1 : s2;
  const int* dp = g == 0 ? d0 : g == 1 ? d1 : d2;
  int e = blockIdx.x * 256 + threadIdx.x;
  if (e >= NE) return;
  int d = dp[e];
  int pos = rows[g * (NN + 1) + d] + atomicAdd(&cnt2[g * NN + d], 1);
  cols[(size_t)g * NE + pos] = sp[e];
}

__global__ void rdeg2_kernel(float* __restrict__ rdo, float* __restrict__ rdi,
                             const int* __restrict__ rows_g) {
  int n = blockIdx.x * 256 + threadIdx.x;
  if (n >= NN) return;
  rdo[n] = rsqrtf(fmaxf(rdo[n], 1.f));
  float di = (float)(rows_g[n + 1] - rows_g[n]);
  rdi[n] = rsqrtf(fmaxf(di, 1.f));
}

// ---------------- GAT per-node gather (both graphs), bf16 h ----------------
__global__ __launch_bounds__(256) void gat_node_kernel(
    const int* __restrict__ rows0, const int* __restrict__ cols0, const float* __restrict__ el0,
    const float* __restrict__ er0, const ushort_t* __restrict__ h0,
    const float* __restrict__ bias0, float* __restrict__ zz0, const int* __restrict__ rows1,
    const int* __restrict__ cols1, const float* __restrict__ el1, const float* __restrict__ er1,
    const ushort_t* __restrict__ h1, const float* __restrict__ bias1, float* __restrict__ zz1) {
  int g = blockIdx.y;
  const int* rows = g ? rows1 : rows0;
  const int* cols = g ? cols1 : cols0;
  const float* el = g ? el1 : el0;
  const float* er = g ? er1 : er0;
  const ushort_t* h = g ? h1 : h0;
  const float* bias = g ? bias1 : bias0;
  float* z = g ? zz1 : zz0;

  int lane = threadIdx.x & 63, w = threadIdx.x >> 6;
  int n = blockIdx.x * 4 + w;
  if (n >= NN) return;
  int r0 = rows[n], r1 = rows[n + 1];
  float4 er4 = *(const float4*)&er[n * 4];
  float s0 = 0.f, s1 = 0.f, s2 = 0.f, s3 = 0.f;
  for (int j = r0 + lane; j < r1; j += 64) {
    int s = cols[j];
    float4 elv = *(const float4*)&el[s * 4];
    float v0 = elv.x + er4.x; v0 = v0 > 0.f ? v0 : 0.2f * v0;
    float v1 = elv.y + er4.y; v1 = v1 > 0.f ? v1 : 0.2f * v1;
    float v2 = elv.z + er4.z; v2 = v2 > 0.f ? v2 : 0.2f * v2;
    float v3 = elv.w + er4.w; v3 = v3 > 0.f ? v3 : 0.2f * v3;
    s0 += __expf(v0); s1 += __expf(v1); s2 += __expf(v2); s3 += __expf(v3);
  }
  s0 = wred(s0); s1 = wred(s1); s2 = wred(s2); s3 = wred(s3);
  int hh = lane >> 4;
  float denom = hh == 0 ? s0 : hh == 1 ? s1 : hh == 2 ? s2 : s3;
  float myer = hh == 0 ? er4.x : hh == 1 ? er4.y : hh == 2 ? er4.z : er4.w;
  float invd = (r1 > r0) ? 1.f / denom : 0.f;
  float4 acc = make_float4(0.f, 0.f, 0.f, 0.f);
  for (int j = r0; j < r1; ++j) {
    int s = cols[j];
    float v = el[s * 4 + hh] + myer;
    v = v > 0.f ? v : 0.2f * v;
    float a = __expf(v) * invd;
    ushort4 hu = *(const ushort4*)&h[(size_t)s * 256 + lane * 4];
    acc.x = fmaf(a, bf2f(hu.x), acc.x);
    acc.y = fmaf(a, bf2f(hu.y), acc.y);
    acc.z = fmaf(a, bf2f(hu.z), acc.z);
    acc.w = fmaf(a, bf2f(hu.w), acc.w);
  }
  float4 bv = *(const float4*)&bias[lane * 4];
  acc.x = fminf(fmaxf(acc.x + bv.x, 0.f), 6.f);
  acc.y = fminf(fmaxf(acc.y + bv.y, 0.f), 6.f);
  acc.z = fminf(fmaxf(acc.z + bv.z, 0.f), 6.f);
  acc.w = fminf(fmaxf(acc.w + bv.w, 0.f), 6.f);
  *(float4*)&z[(size_t)n * 256 + lane * 4] = acc;
}

// ---- reduce partials -> beta ----
__global__ __launch_bounds__(256) void attn_reduce_kernel(const float* __restrict__ pbuf,
                                                          float* __restrict__ wb) {
  __shared__ float sm[8];
  int t = threadIdx.x;
  float a0 = 0.f, a1 = 0.f;
  for (int i = t; i < NMT; i += 256) {
    a0 += pbuf[i];
    a1 += pbuf[NMT + i];
  }
  a0 = wred(a0);
  a1 = wred(a1);
  int lane = t & 63, w = t >> 6;
  if (lane == 0) { sm[w] = a0; sm[4 + w] = a1; }
  __syncthreads();
  if (t == 0) {
    float w0 = (sm[0] + sm[1] + sm[2] + sm[3]) * (1.0f / NN);
    float w1 = (sm[4] + sm[5] + sm[6] + sm[7]) * (1.0f / NN);
    float mx = fmaxf(w0, w1);
    float e0 = expf(w0 - mx), e1 = expf(w1 - mx);
    float inv = 1.f / (e0 + e1);
    wb[2] = e0 * inv;
    wb[3] = e1 * inv;
  }
}

// ---------------- GCN gather layer1 (bf16 table): tanh(agg*rdi + bg1) ----------------
__global__ __launch_bounds__(256) void gcn_gather1_kernel(
    const int* __restrict__ rows, const int* __restrict__ cols, const ushort_t* __restrict__ X,
    const float* __restrict__ rdi, const float* __restrict__ bg1, float* __restrict__ out) {
  int lane = threadIdx.x & 63, w = threadIdx.x >> 6;
  int n = blockIdx.x * 4 + w;
  if (n >= NN) return;
  int r0 = rows[n], r1 = rows[n + 1];
  float acc = 0.f;
  for (int j = r0; j < r1; ++j) {
    int s = cols[j];
    acc += bf2f(X[(size_t)s * 64 + lane]);
  }
  out[(size_t)n * 64 + lane] = tanhf(acc * rdi[n] + bg1[lane]);
}

// ---------------- GCN gemm K=64 via shuffle -> bf16 out ----------------
__global__ __launch_bounds__(256) void gcn_gemm64_kernel(const float* __restrict__ X,
                                                         const float* __restrict__ W,
                                                         const float* __restrict__ rdo,
                                                         ushort_t* __restrict__ out) {
  int lane = threadIdx.x & 63, w = threadIdx.x >> 6;
  int n = blockIdx.x * 4 + w;
  float x = X[(size_t)n * 64 + lane];
  float acc = 0.f;
#pragma unroll
  for (int k = 0; k < 64; ++k) acc = fmaf(__shfl(x, k), W[k * 64 + lane], acc);
  out[(size_t)n * 64 + lane] = f2bf(acc * rdo[n]);
}

// ---------------- GCN gather layer2 (bf16) fused with Z write ----------------
__global__ __launch_bounds__(256) void gcn_gather2_kernel(
    const int* __restrict__ rows, const int* __restrict__ cols, const ushort_t* __restrict__ X,
    const float* __restrict__ rdi, const float* __restrict__ Femb, float* __restrict__ dout) {
  int lane = threadIdx.x & 63, w = threadIdx.x >> 6;
  int n = blockIdx.x * 4 + w;
  if (n >= NN) return;
  int r0 = rows[n], r1 = rows[n + 1];
  float acc = 0.f;
  for (int j = r0; j < r1; ++j) {
    int s = cols[j];
    acc += bf2f(X[(size_t)s * 64 + lane]);
  }
  dout[1 + (size_t)n * 64 + lane] = 0.5f * (Femb[(size_t)n * 64 + lane] + acc * rdi[n]);
}

// ---------------- trace ----------------
__global__ __launch_bounds__(256) void tr_kernel(const int* __restrict__ asrc,
                                                 const int* __restrict__ adst,
                                                 const int* __restrict__ kptr,
                                                 const float* __restrict__ dout,
                                                 float* __restrict__ trbuf) {
  __shared__ float wsum[4];
  int e = blockIdx.x * 256 + threadIdx.x;
  int k = *kptr;
  float local = 0.f;
  if (e < NE) {
    int a = asrc[e], b = adst[e];
    const float* Za = dout + 1 + (size_t)a * 64;
    const float* Zb = dout + 1 + (size_t)b * 64;
    for (int c = 0; c < k; ++c) {
      float d2 = Za[c] - Zb[c];
      local += d2 * d2;
    }
  }
#pragma unroll
  for (int off = 32; off > 0; off >>= 1) local += __shfl_down(local, off);
  int lane = threadIdx.x & 63, w = threadIdx.x >> 6;
  if (lane == 0) wsum[w] = local;
  __syncthreads();
  if (threadIdx.x == 0) trbuf[blockIdx.x] = wsum[0] + wsum[1] + wsum[2] + wsum[3];
}

__global__ __launch_bounds__(256) void tr_reduce_kernel(const float* __restrict__ trbuf,
                                                        float* __restrict__ dout) {
  __shared__ float sm[4];
  int t = threadIdx.x;
  float a = 0.f;
  for (int i = t; i < NTRB; i += 256) a += trbuf[i];
  a = wred(a);
  int lane = t & 63, w = t >> 6;
  if (lane == 0) sm[w] = a;
  __syncthreads();
  if (t == 0) dout[0] = 0.5f * (sm[0] + sm[1] + sm[2] + sm[3]);
}

extern "C" void kernel_launch(void* const* d_in, const int* in_sizes, int n_in, void* d_out,
                              int out_size, void* d_ws, size_t ws_size, hipStream_t stream) {
  const float* feat0 = (const float*)d_in[0];
  const float* feat1 = (const float*)d_in[1];
  const float* sen = (const float*)d_in[2];
  const float* Wgat0 = (const float*)d_in[3];
  const float* al0 = (const float*)d_in[4];
  const float* ar0 = (const float*)d_in[5];
  const float* b0 = (const float*)d_in[6];
  const float* Wgat1 = (const float*)d_in[7];
  const float* al1 = (const float*)d_in[8];
  const float* ar1 = (const float*)d_in[9];
  const float* b1 = (const float*)d_in[10];
  const float* Wp1 = (const float*)d_in[11];
  const float* bp1 = (const float*)d_in[12];
  const float* wp2 = (const float*)d_in[13];
  const float* Wf = (const float*)d_in[14];
  const float* bf = (const float*)d_in[15];
  const float* Wg1 = (const float*)d_in[16];
  const float* bg1 = (const float*)d_in[17];
  const float* Wg2 = (const float*)d_in[18];
  const int* src0 = (const int*)d_in[19];
  const int* dst0 = (const int*)d_in[20];
  const int* src1 = (const int*)d_in[21];
  const int* dst1 = (const int*)d_in[22];
  const int* gsrc = (const int*)d_in[23];
  const int* gdst = (const int*)d_in[24];
  const int* asrc = (const int*)d_in[25];
  const int* adst = (const int*)d_in[26];
  const int* kptr = (const int*)d_in[27];
  float* out = (float*)d_out;
  float* ws = (float*)d_ws;

  // ---- workspace layout (float-element offsets) ----
  float* dego = ws;                        // 30000
  float* wb = ws + 30000;                  // 4
  int* cnt = (int*)(ws + 30004);           // 90000
  int* cnt2 = (int*)(ws + 120004);         // 90000
  float* rdi = ws + 210004;                // 30000
  int* rows = (int*)(ws + 240004);         // 90003
  int* bsum = (int*)(ws + 330007);         // 354
  int* boff = (int*)(ws + 330361);         // 354
  int* cols = (int*)(ws + 330716);         // 1,440,000
  float* z0 = ws + 1770716;                // 7,680,000
  float* z1 = ws + 9450716;                // 7,680,000
  float* el0 = ws + 17130716;              // 120000
  float* er0 = ws + 17250716;              // 120000
  float* el1 = ws + 17370716;              // 120000
  float* er1 = ws + 17490716;              // 120000
  float* Femb = ws + 17610716;             // 1,920,000
  float* gcnB = ws + 19530716;             // 1,920,000
  float* pbuf = ws + 21450716;             // 2*NMT = 470
  float* trbuf = ws + 21451656;            // NTRB
  ushort_t* h0 = (ushort_t*)(ws + 21453532);    // 7,680,000 bf16
  ushort_t* h1 = (ushort_t*)(ws + 25293532);    // 7,680,000 bf16
  ushort_t* gcnA = (ushort_t*)(ws + 29133532);  // 1,920,000 bf16
  ushort_t* gcnA2 = (ushort_t*)(ws + 30093532); // 1,920,000 bf16
  ushort_t* WT0 = (ushort_t*)(ws + 31053532);   // 65536 bf16 (Wgat0^T [256][256])
  ushort_t* WT1 = (ushort_t*)(ws + 31086300);   // 32768 bf16 (Wgat1^T [256][128])
  ushort_t* Wp1T = (ushort_t*)(ws + 31102684);  // 16384 bf16 ([64][256])
  ushort_t* WfT = (ushort_t*)(ws + 31110876);   // 16384 bf16
  ushort_t* Wg1T = (ushort_t*)(ws + 31119068);  // 16384 bf16

  int* rows_g = rows + 2 * (NN + 1);
  int* cols_g = cols + 2 * NE;

  zero4_kernel<<<(52501 + 255) / 256, 256, 0, stream>>>((float4*)ws, 52501);

  // ---- weight prep (transpose + bf16) ----
  wt_kernel<<<256, 256, 0, stream>>>(Wgat0, WT0, 256, 256);
  wt_kernel<<<128, 256, 0, stream>>>(Wgat1, WT1, 128, 256);
  wt_kernel<<<64, 256, 0, stream>>>(Wp1, Wp1T, 256, 64);
  wt_kernel<<<64, 256, 0, stream>>>(Wf, WfT, 256, 64);
  wt_kernel<<<64, 256, 0, stream>>>(Wg1, Wg1T, 256, 64);

  // ---- CSR build for 3 graphs (by dst) ----
  hist_kernel<<<dim3(1875, 3), 256, 0, stream>>>(dst0, dst1, gdst, cnt);
  deg_src_kernel<<<1875, 256, 0, stream>>>(gsrc, dego);
  scan_blocks_kernel<<<dim3(NBLK, 3), 256, 0, stream>>>(cnt, rows, bsum);
  scan_tops_kernel<<<dim3(1, 3), 128, 0, stream>>>(bsum, boff);
  add_off_kernel<<<dim3(NBLK, 3), 256, 0, stream>>>(rows, boff);
  scatter_kernel<<<dim3(1875, 3), 256, 0, stream>>>(src0, src1, gsrc, dst0, dst1, gdst, rows,
                                                    cnt2, cols);
  rdeg2_kernel<<<NBLK, 256, 0, stream>>>(dego, rdi, rows_g);

  // ---- GAT dense projections (MFMA, bf16 h out) ----
  mfma_h_kernel<<<dim3(NMT, 4), 256, 0, stream>>>(feat0, WT0, 256, h0);
  mfma_h_kernel<<<dim3(NMT, 4), 256, 0, stream>>>(feat1, WT1, 128, h1);
  eler_kernel<<<469, 256, 0, stream>>>(h0, al0, ar0, el0, er0);
  eler_kernel<<<469, 256, 0, stream>>>(h1, al1, ar1, el1, er1);

  // ---- GAT gather (both graphs in one launch) ----
  gat_node_kernel<<<dim3(7500, 2), 256, 0, stream>>>(rows, cols, el0, er0, h0, b0, z0,
                                                     rows + (NN + 1), cols + NE, el1, er1, h1,
                                                     b1, z1);

  // ---- attention pooling -> beta -> Femb ----
  mfma_attn_kernel<<<dim3(NMT, 2), 256, 0, stream>>>(z0, z1, Wp1T, bp1, wp2, pbuf);
  attn_reduce_kernel<<<1, 256, 0, stream>>>(pbuf, wb);
  mfma_femb_kernel<<<NMT, 256, 0, stream>>>(z0, z1, wb, WfT, bf, Femb);

  // ---- GCN path ----
  mfma_gcn1_kernel<<<NMT, 256, 0, stream>>>(sen, Wg1T, dego, gcnA);
  gcn_gather1_kernel<<<7500, 256, 0, stream>>>(rows_g, cols_g, gcnA, rdi, bg1, gcnB);
  gcn_gemm64_kernel<<<7500, 256, 0, stream>>>(gcnB, Wg2, dego, gcnA2);
  gcn_gather2_kernel<<<7500, 256, 0, stream>>>(rows_g, cols_g, gcnA2, rdi, Femb, out);

  // ---- trace ----
  tr_kernel<<<NTRB, 256, 0, stream>>>(asrc, adst, kptr, out, trbuf);
  tr_reduce_kernel<<<1, 256, 0, stream>>>(trbuf, out);
}

// Round 7
// 578.658 us; speedup vs baseline: 8.5950x; 1.2479x over previous
//
#include <hip/hip_runtime.h>
#include <math.h>

#define NN 30000
#define NE 480000
#define NBLK 118   // ceil(30000/256)
#define NMT 235    // ceil(30000/128) MFMA row-tiles
#define NTRB 1875  // blocks in tr pass

typedef unsigned short ushort_t;
typedef unsigned int uint_t;
typedef __attribute__((ext_vector_type(8))) short short8;
typedef __attribute__((ext_vector_type(4))) float f32x4;

__device__ __forceinline__ ushort_t f2bf(float x) {
  uint_t u = __float_as_uint(x);
  u = (u + 0x7FFF + ((u >> 16) & 1)) >> 16;
  return (ushort_t)u;
}
__device__ __forceinline__ float bf2f(ushort_t v) {
  return __uint_as_float(((uint_t)v) << 16);
}

// ---------------- fill ----------------
__global__ void zero4_kernel(float4* __restrict__ p, int n4) {
  int g = blockIdx.x * 256 + threadIdx.x;
  if (g < n4) p[g] = make_float4(0.f, 0.f, 0.f, 0.f);
}

__device__ __forceinline__ float wred(float v) {
#pragma unroll
  for (int off = 32; off > 0; off >>= 1) v += __shfl_xor(v, off);
  return v;
}

// ---------------- merged weight prep: 5 transposes fp32->bf16 ----------------
__global__ void wt_all_kernel(const float* __restrict__ W0, const float* __restrict__ W1,
                              const float* __restrict__ W2, const float* __restrict__ W3,
                              const float* __restrict__ W4, ushort_t* __restrict__ T0,
                              ushort_t* __restrict__ T1, ushort_t* __restrict__ T2,
                              ushort_t* __restrict__ T3, ushort_t* __restrict__ T4) {
  int id = blockIdx.x * 256 + threadIdx.x;
  const float* W;
  ushort_t* T;
  int K, N, base;
  if (id < 65536) { W = W0; T = T0; K = 256; N = 256; base = 0; }
  else if (id < 98304) { W = W1; T = T1; K = 128; N = 256; base = 65536; }
  else if (id < 114688) { W = W2; T = T2; K = 256; N = 64; base = 98304; }
  else if (id < 131072) { W = W3; T = T3; K = 256; N = 64; base = 114688; }
  else if (id < 147456) { W = W4; T = T4; K = 256; N = 64; base = 131072; }
  else return;
  int l = id - base;
  int k = l / N, n = l - k * N;
  T[(size_t)n * K + k] = f2bf(W[l]);
}

// ================= MFMA cores =================
// BM=128, BN=64, BK=32; 256 threads = 4 waves; wave w owns rows [w*32, w*32+32).
// LDS rows padded to 40 shorts (80 B).

// fp32 A input (converted to bf16 during staging)
__device__ __forceinline__ void mfma_core_f32(const float* __restrict__ A0,
                                              const ushort_t* __restrict__ BT, int K, int bm,
                                              short* __restrict__ As, short* __restrict__ Bs,
                                              f32x4 acc[2][4]) {
  int tid = threadIdx.x;
  int lane = tid & 63, w = tid >> 6;
  int q = lane >> 4, mr = lane & 15;
#pragma unroll 1
  for (int k0 = 0; k0 < K; k0 += 32) {
    {
      int r = tid >> 1, hf = tid & 1;
      int gr = bm + r;
      float4 f0 = make_float4(0.f, 0.f, 0.f, 0.f), f1 = f0, f2 = f0, f3 = f0;
      if (gr < NN) {
        const float4* pa = (const float4*)(A0 + (size_t)gr * K + k0 + hf * 16);
        f0 = pa[0]; f1 = pa[1]; f2 = pa[2]; f3 = pa[3];
      }
      short8 lo, hi;
      lo[0] = (short)f2bf(f0.x); lo[1] = (short)f2bf(f0.y);
      lo[2] = (short)f2bf(f0.z); lo[3] = (short)f2bf(f0.w);
      lo[4] = (short)f2bf(f1.x); lo[5] = (short)f2bf(f1.y);
      lo[6] = (short)f2bf(f1.z); lo[7] = (short)f2bf(f1.w);
      hi[0] = (short)f2bf(f2.x); hi[1] = (short)f2bf(f2.y);
      hi[2] = (short)f2bf(f2.z); hi[3] = (short)f2bf(f2.w);
      hi[4] = (short)f2bf(f3.x); hi[5] = (short)f2bf(f3.y);
      hi[6] = (short)f2bf(f3.z); hi[7] = (short)f2bf(f3.w);
      short* dst = As + r * 40 + hf * 16;
      *(short8*)(dst) = lo;
      *(short8*)(dst + 8) = hi;
    }
    {
      int n = tid >> 2, qk = tid & 3;
      short8 bv = *(const short8*)((const short*)BT + (size_t)n * K + k0 + qk * 8);
      *(short8*)(Bs + n * 40 + qk * 8) = bv;
    }
    __syncthreads();
    short8 a0 = *(short8*)(As + (w * 32 + mr) * 40 + q * 8);
    short8 a1 = *(short8*)(As + (w * 32 + 16 + mr) * 40 + q * 8);
#pragma unroll
    for (int j = 0; j < 4; ++j) {
      short8 b = *(short8*)(Bs + (j * 16 + mr) * 40 + q * 8);
      acc[0][j] = __builtin_amdgcn_mfma_f32_16x16x32_bf16(a0, b, acc[0][j], 0, 0, 0);
      acc[1][j] = __builtin_amdgcn_mfma_f32_16x16x32_bf16(a1, b, acc[1][j], 0, 0, 0);
    }
    __syncthreads();
  }
}

// bf16 A input (K fixed = 256); optional blend of two bf16 sources
template <bool BLEND>
__device__ __forceinline__ void mfma_core_bf(const ushort_t* __restrict__ A0,
                                             const ushort_t* __restrict__ A1, float w0, float w1,
                                             const ushort_t* __restrict__ BT, int bm,
                                             short* __restrict__ As, short* __restrict__ Bs,
                                             f32x4 acc[2][4]) {
  int tid = threadIdx.x;
  int lane = tid & 63, w = tid >> 6;
  int q = lane >> 4, mr = lane & 15;
#pragma unroll 1
  for (int k0 = 0; k0 < 256; k0 += 32) {
    {
      int r = tid >> 1, hf = tid & 1;
      int gr = bm + r;
      short8 v0 = {0, 0, 0, 0, 0, 0, 0, 0}, v1 = {0, 0, 0, 0, 0, 0, 0, 0};
      if (gr < NN) {
        const short* p0 = (const short*)A0 + (size_t)gr * 256 + k0 + hf * 16;
        v0 = *(const short8*)p0;
        v1 = *(const short8*)(p0 + 8);
        if (BLEND) {
          const short* p1 = (const short*)A1 + (size_t)gr * 256 + k0 + hf * 16;
          short8 y0 = *(const short8*)p1, y1 = *(const short8*)(p1 + 8);
#pragma unroll
          for (int t = 0; t < 8; ++t) {
            v0[t] = (short)f2bf(w0 * bf2f((ushort_t)v0[t]) + w1 * bf2f((ushort_t)y0[t]));
            v1[t] = (short)f2bf(w0 * bf2f((ushort_t)v1[t]) + w1 * bf2f((ushort_t)y1[t]));
          }
        }
      }
      short* dst = As + r * 40 + hf * 16;
      *(short8*)(dst) = v0;
      *(short8*)(dst + 8) = v1;
    }
    {
      int n = tid >> 2, qk = tid & 3;
      short8 bv = *(const short8*)((const short*)BT + (size_t)n * 256 + k0 + qk * 8);
      *(short8*)(Bs + n * 40 + qk * 8) = bv;
    }
    __syncthreads();
    short8 a0 = *(short8*)(As + (w * 32 + mr) * 40 + q * 8);
    short8 a1 = *(short8*)(As + (w * 32 + 16 + mr) * 40 + q * 8);
#pragma unroll
    for (int j = 0; j < 4; ++j) {
      short8 b = *(short8*)(Bs + (j * 16 + mr) * 40 + q * 8);
      acc[0][j] = __builtin_amdgcn_mfma_f32_16x16x32_bf16(a0, b, acc[0][j], 0, 0, 0);
      acc[1][j] = __builtin_amdgcn_mfma_f32_16x16x32_bf16(a1, b, acc[1][j], 0, 0, 0);
    }
    __syncthreads();
  }
}

// ---- h = feat @ Wgat -> bf16 [NN][256] + fused el/er; grid (NMT, 4), blockIdx.y = head ----
__global__ __launch_bounds__(256) void mfma_h_kernel(const float* __restrict__ A,
                                                     const ushort_t* __restrict__ WT, int K,
                                                     ushort_t* __restrict__ H,
                                                     const float* __restrict__ al,
                                                     const float* __restrict__ ar,
                                                     float* __restrict__ el,
                                                     float* __restrict__ er) {
  __shared__ short As[128 * 40];
  __shared__ short Bs[64 * 40];
  int head = blockIdx.y;
  int bm = blockIdx.x * 128, bn = head * 64;
  f32x4 acc[2][4];
#pragma unroll
  for (int i = 0; i < 2; ++i)
#pragma unroll
    for (int j = 0; j < 4; ++j) acc[i][j] = (f32x4){0.f, 0.f, 0.f, 0.f};
  mfma_core_f32(A, WT + (size_t)bn * K, K, bm, As, Bs, acc);
  int lane = threadIdx.x & 63, w = threadIdx.x >> 6;
  int q = lane >> 4, mr = lane & 15;
  float alv[4], arv[4];
#pragma unroll
  for (int j = 0; j < 4; ++j) {
    alv[j] = al[head * 64 + j * 16 + mr];
    arv[j] = ar[head * 64 + j * 16 + mr];
  }
#pragma unroll
  for (int i = 0; i < 2; ++i)
#pragma unroll
    for (int r = 0; r < 4; ++r) {
      int gr = bm + w * 32 + i * 16 + q * 4 + r;
      float pl = 0.f, pr = 0.f;
#pragma unroll
      for (int j = 0; j < 4; ++j) {
        pl = fmaf(acc[i][j][r], alv[j], pl);
        pr = fmaf(acc[i][j][r], arv[j], pr);
      }
#pragma unroll
      for (int m = 1; m < 16; m <<= 1) {
        pl += __shfl_xor(pl, m);
        pr += __shfl_xor(pr, m);
      }
      if (gr < NN) {
        if (mr == 0) {
          el[gr * 4 + head] = pl;
          er[gr * 4 + head] = pr;
        }
#pragma unroll
        for (int j = 0; j < 4; ++j) H[(size_t)gr * 256 + bn + j * 16 + mr] = f2bf(acc[i][j][r]);
      }
    }
}

// ---- attn partials from bf16 z: sum tanh(z@Wp1+bp1)*wp2, grid (NMT, 2) ----
__global__ __launch_bounds__(256) void mfma_attn_kernel(
    const ushort_t* __restrict__ z0, const ushort_t* __restrict__ z1,
    const ushort_t* __restrict__ WT, const float* __restrict__ bp1,
    const float* __restrict__ wp2, float* __restrict__ pbuf) {
  __shared__ short As[128 * 40];
  __shared__ short Bs[64 * 40];
  __shared__ float wsum[4];
  const ushort_t* A = blockIdx.y ? z1 : z0;
  int bm = blockIdx.x * 128;
  f32x4 acc[2][4];
#pragma unroll
  for (int i = 0; i < 2; ++i)
#pragma unroll
    for (int j = 0; j < 4; ++j) acc[i][j] = (f32x4){0.f, 0.f, 0.f, 0.f};
  mfma_core_bf<false>(A, nullptr, 0.f, 0.f, WT, bm, As, Bs, acc);
  int lane = threadIdx.x & 63, w = threadIdx.x >> 6;
  int q = lane >> 4, mr = lane & 15;
  float local = 0.f;
#pragma unroll
  for (int j = 0; j < 4; ++j) {
    int col = j * 16 + mr;
    float bp = bp1[col], wp = wp2[col];
#pragma unroll
    for (int i = 0; i < 2; ++i)
#pragma unroll
      for (int r = 0; r < 4; ++r) {
        int gr = bm + w * 32 + i * 16 + q * 4 + r;
        if (gr < NN) local += tanhf(acc[i][j][r] + bp) * wp;
      }
  }
  local = wred(local);
  if (lane == 0) wsum[w] = local;
  __syncthreads();
  if (threadIdx.x == 0)
    pbuf[blockIdx.y * NMT + blockIdx.x] = wsum[0] + wsum[1] + wsum[2] + wsum[3];
}

// ---- femb: Femb = (b0*z0 + b1*z1) @ Wf + bf (bf16 z), grid (NMT) ----
__global__ __launch_bounds__(256) void mfma_femb_kernel(
    const ushort_t* __restrict__ z0, const ushort_t* __restrict__ z1,
    const float* __restrict__ wb, const ushort_t* __restrict__ WT, const float* __restrict__ bf,
    float* __restrict__ Femb) {
  __shared__ short As[128 * 40];
  __shared__ short Bs[64 * 40];
  int bm = blockIdx.x * 128;
  float beta0 = wb[2], beta1 = wb[3];
  f32x4 acc[2][4];
#pragma unroll
  for (int i = 0; i < 2; ++i)
#pragma unroll
    for (int j = 0; j < 4; ++j) acc[i][j] = (f32x4){0.f, 0.f, 0.f, 0.f};
  mfma_core_bf<true>(z0, z1, beta0, beta1, WT, bm, As, Bs, acc);
  int lane = threadIdx.x & 63, w = threadIdx.x >> 6;
  int q = lane >> 4, mr = lane & 15;
#pragma unroll
  for (int j = 0; j < 4; ++j) {
    int col = j * 16 + mr;
    float bv = bf[col];
#pragma unroll
    for (int i = 0; i < 2; ++i)
#pragma unroll
      for (int r = 0; r < 4; ++r) {
        int gr = bm + w * 32 + i * 16 + q * 4 + r;
        if (gr < NN) Femb[(size_t)gr * 64 + col] = acc[i][j][r] + bv;
      }
  }
}

// ---- gcn1: out = bf16((sen @ Wg1) * rdo), grid (NMT) ----
__global__ __launch_bounds__(256) void mfma_gcn1_kernel(const float* __restrict__ X,
                                                        const ushort_t* __restrict__ WT,
                                                        const float* __restrict__ rdo,
                                                        ushort_t* __restrict__ out) {
  __shared__ short As[128 * 40];
  __shared__ short Bs[64 * 40];
  int bm = blockIdx.x * 128;
  f32x4 acc[2][4];
#pragma unroll
  for (int i = 0; i < 2; ++i)
#pragma unroll
    for (int j = 0; j < 4; ++j) acc[i][j] = (f32x4){0.f, 0.f, 0.f, 0.f};
  mfma_core_f32(X, WT, 256, bm, As, Bs, acc);
  int lane = threadIdx.x & 63, w = threadIdx.x >> 6;
  int q = lane >> 4, mr = lane & 15;
#pragma unroll
  for (int i = 0; i < 2; ++i)
#pragma unroll
    for (int r = 0; r < 4; ++r) {
      int gr = bm + w * 32 + i * 16 + q * 4 + r;
      if (gr < NN) {
        float sc = rdo[gr];
#pragma unroll
        for (int j = 0; j < 4; ++j) out[(size_t)gr * 64 + j * 16 + mr] = f2bf(acc[i][j][r] * sc);
      }
    }
}

// ---------------- CSR build: histogram over dst (g=0..2) + gsrc degree (g=3) ----------------
__global__ void hist_kernel(const int* __restrict__ d0, const int* __restrict__ d1,
                            const int* __restrict__ d2, const int* __restrict__ d3,
                            int* __restrict__ cnt) {
  int g = blockIdx.y;
  const int* d = g == 0 ? d0 : g == 1 ? d1 : g == 2 ? d2 : d3;
  int e = blockIdx.x * 256 + threadIdx.x;
  if (e < NE) atomicAdd(&cnt[g * NN + d[e]], 1);
}

__global__ __launch_bounds__(256) void scan_blocks_kernel(const int* __restrict__ cnt,
                                                          int* __restrict__ rows,
                                                          int* __restrict__ bsum) {
  __shared__ int sm[256];
  int g = blockIdx.y, t = threadIdx.x;
  int i = blockIdx.x * 256 + t;
  int v = (i < NN) ? cnt[g * NN + i] : 0;
  sm[t] = v;
  __syncthreads();
#pragma unroll
  for (int off = 1; off < 256; off <<= 1) {
    int tmp = (t >= off) ? sm[t - off] : 0;
    __syncthreads();
    sm[t] += tmp;
    __syncthreads();
  }
  if (i < NN) rows[g * (NN + 1) + i] = sm[t] - v;  // exclusive
  if (t == 255) bsum[g * NBLK + blockIdx.x] = sm[255];
}

__global__ __launch_bounds__(128) void scan_tops_kernel(int* __restrict__ bsum,
                                                        int* __restrict__ boff) {
  __shared__ int sm[128];
  int g = blockIdx.y, t = threadIdx.x;
  int v = (t < NBLK) ? bsum[g * NBLK + t] : 0;
  sm[t] = v;
  __syncthreads();
#pragma unroll
  for (int off = 1; off < 128; off <<= 1) {
    int tmp = (t >= off) ? sm[t - off] : 0;
    __syncthreads();
    sm[t] += tmp;
    __syncthreads();
  }
  if (t < NBLK) boff[g * NBLK + t] = sm[t] - v;  // exclusive
}

__global__ void add_off_kernel(int* __restrict__ rows, const int* __restrict__ boff) {
  int g = blockIdx.y, t = threadIdx.x;
  int i = blockIdx.x * 256 + t;
  if (i < NN) rows[g * (NN + 1) + i] += boff[g * NBLK + blockIdx.x];
  if (blockIdx.x == 0 && t == 0) rows[g * (NN + 1) + NN] = NE;
}

__global__ void scatter_kernel(const int* __restrict__ s0, const int* __restrict__ s1,
                               const int* __restrict__ s2, const int* __restrict__ d0,
                               const int* __restrict__ d1, const int* __restrict__ d2,
                               const int* __restrict__ rows, int* __restrict__ cnt2,
                               int* __restrict__ cols) {
  int g = blockIdx.y;
  const int* sp = g == 0 ? s0 : g == 1 ? s1 : s2;
  const int* dp = g == 0 ? d0 : g == 1 ? d1 : d2;
  int e = blockIdx.x * 256 + threadIdx.x;
  if (e >= NE) return;
  int d = dp[e];
  int pos = rows[g * (NN + 1) + d] + atomicAdd(&cnt2[g * NN + d], 1);
  cols[(size_t)g * NE + pos] = sp[e];
}

__global__ void rdeg2_kernel(const int* __restrict__ cnt_deg, float* __restrict__ rdo,
                             float* __restrict__ rdi, const int* __restrict__ rows_g) {
  int n = blockIdx.x * 256 + threadIdx.x;
  if (n >= NN) return;
  rdo[n] = rsqrtf(fmaxf((float)cnt_deg[n], 1.f));
  float di = (float)(rows_g[n + 1] - rows_g[n]);
  rdi[n] = rsqrtf(fmaxf(di, 1.f));
}

// ---------------- GAT per-node gather (both graphs), bf16 h, bf16 z out ----------------
__global__ __launch_bounds__(256) void gat_node_kernel(
    const int* __restrict__ rows0, const int* __restrict__ cols0, const float* __restrict__ el0,
    const float* __restrict__ er0, const ushort_t* __restrict__ h0,
    const float* __restrict__ bias0, ushort_t* __restrict__ zz0, const int* __restrict__ rows1,
    const int* __restrict__ cols1, const float* __restrict__ el1, const float* __restrict__ er1,
    const ushort_t* __restrict__ h1, const float* __restrict__ bias1,
    ushort_t* __restrict__ zz1) {
  int g = blockIdx.y;
  const int* rows = g ? rows1 : rows0;
  const int* cols = g ? cols1 : cols0;
  const float* el = g ? el1 : el0;
  const float* er = g ? er1 : er0;
  const ushort_t* h = g ? h1 : h0;
  const float* bias = g ? bias1 : bias0;
  ushort_t* z = g ? zz1 : zz0;

  int lane = threadIdx.x & 63, w = threadIdx.x >> 6;
  int n = blockIdx.x * 4 + w;
  if (n >= NN) return;
  int r0 = rows[n], r1 = rows[n + 1];
  float4 er4 = *(const float4*)&er[n * 4];
  float s0 = 0.f, s1 = 0.f, s2 = 0.f, s3 = 0.f;
  for (int j = r0 + lane; j < r1; j += 64) {
    int s = cols[j];
    float4 elv = *(const float4*)&el[s * 4];
    float v0 = elv.x + er4.x; v0 = v0 > 0.f ? v0 : 0.2f * v0;
    float v1 = elv.y + er4.y; v1 = v1 > 0.f ? v1 : 0.2f * v1;
    float v2 = elv.z + er4.z; v2 = v2 > 0.f ? v2 : 0.2f * v2;
    float v3 = elv.w + er4.w; v3 = v3 > 0.f ? v3 : 0.2f * v3;
    s0 += __expf(v0); s1 += __expf(v1); s2 += __expf(v2); s3 += __expf(v3);
  }
  s0 = wred(s0); s1 = wred(s1); s2 = wred(s2); s3 = wred(s3);
  int hh = lane >> 4;
  float denom = hh == 0 ? s0 : hh == 1 ? s1 : hh == 2 ? s2 : s3;
  float myer = hh == 0 ? er4.x : hh == 1 ? er4.y : hh == 2 ? er4.z : er4.w;
  float invd = (r1 > r0) ? 1.f / denom : 0.f;
  float4 acc = make_float4(0.f, 0.f, 0.f, 0.f);
  int j = r0;
  for (; j + 4 <= r1; j += 4) {
    int sa = cols[j], sb = cols[j + 1], sc = cols[j + 2], sd = cols[j + 3];
    float ea = el[sa * 4 + hh], eb = el[sb * 4 + hh], ec = el[sc * 4 + hh],
          ed = el[sd * 4 + hh];
    ushort4 ua = *(const ushort4*)&h[(size_t)sa * 256 + lane * 4];
    ushort4 ub = *(const ushort4*)&h[(size_t)sb * 256 + lane * 4];
    ushort4 uc = *(const ushort4*)&h[(size_t)sc * 256 + lane * 4];
    ushort4 ud = *(const ushort4*)&h[(size_t)sd * 256 + lane * 4];
    float va = ea + myer; va = va > 0.f ? va : 0.2f * va;
    float vb = eb + myer; vb = vb > 0.f ? vb : 0.2f * vb;
    float vc = ec + myer; vc = vc > 0.f ? vc : 0.2f * vc;
    float vd = ed + myer; vd = vd > 0.f ? vd : 0.2f * vd;
    float aa = __expf(va) * invd, ab = __expf(vb) * invd, ac = __expf(vc) * invd,
          ad = __expf(vd) * invd;
    acc.x = fmaf(aa, bf2f(ua.x), acc.x); acc.y = fmaf(aa, bf2f(ua.y), acc.y);
    acc.z = fmaf(aa, bf2f(ua.z), acc.z); acc.w = fmaf(aa, bf2f(ua.w), acc.w);
    acc.x = fmaf(ab, bf2f(ub.x), acc.x); acc.y = fmaf(ab, bf2f(ub.y), acc.y);
    acc.z = fmaf(ab, bf2f(ub.z), acc.z); acc.w = fmaf(ab, bf2f(ub.w), acc.w);
    acc.x = fmaf(ac, bf2f(uc.x), acc.x); acc.y = fmaf(ac, bf2f(uc.y), acc.y);
    acc.z = fmaf(ac, bf2f(uc.z), acc.z); acc.w = fmaf(ac, bf2f(uc.w), acc.w);
    acc.x = fmaf(ad, bf2f(ud.x), acc.x); acc.y = fmaf(ad, bf2f(ud.y), acc.y);
    acc.z = fmaf(ad, bf2f(ud.z), acc.z); acc.w = fmaf(ad, bf2f(ud.w), acc.w);
  }
  for (; j < r1; ++j) {
    int s = cols[j];
    float v = el[s * 4 + hh] + myer;
    v = v > 0.f ? v : 0.2f * v;
    float a = __expf(v) * invd;
    ushort4 hu = *(const ushort4*)&h[(size_t)s * 256 + lane * 4];
    acc.x = fmaf(a, bf2f(hu.x), acc.x);
    acc.y = fmaf(a, bf2f(hu.y), acc.y);
    acc.z = fmaf(a, bf2f(hu.z), acc.z);
    acc.w = fmaf(a, bf2f(hu.w), acc.w);
  }
  float4 bv = *(const float4*)&bias[lane * 4];
  ushort4 o;
  o.x = f2bf(fminf(fmaxf(acc.x + bv.x, 0.f), 6.f));
  o.y = f2bf(fminf(fmaxf(acc.y + bv.y, 0.f), 6.f));
  o.z = f2bf(fminf(fmaxf(acc.z + bv.z, 0.f), 6.f));
  o.w = f2bf(fminf(fmaxf(acc.w + bv.w, 0.f), 6.f));
  *(ushort4*)&z[(size_t)n * 256 + lane * 4] = o;
}

// ---- reduce partials -> beta ----
__global__ __launch_bounds__(256) void attn_reduce_kernel(const float* __restrict__ pbuf,
                                                          float* __restrict__ wb) {
  __shared__ float sm[8];
  int t = threadIdx.x;
  float a0 = 0.f, a1 = 0.f;
  for (int i = t; i < NMT; i += 256) {
    a0 += pbuf[i];
    a1 += pbuf[NMT + i];
  }
  a0 = wred(a0);
  a1 = wred(a1);
  int lane = t & 63, w = t >> 6;
  if (lane == 0) { sm[w] = a0; sm[4 + w] = a1; }
  __syncthreads();
  if (t == 0) {
    float w0 = (sm[0] + sm[1] + sm[2] + sm[3]) * (1.0f / NN);
    float w1 = (sm[4] + sm[5] + sm[6] + sm[7]) * (1.0f / NN);
    float mx = fmaxf(w0, w1);
    float e0 = expf(w0 - mx), e1 = expf(w1 - mx);
    float inv = 1.f / (e0 + e1);
    wb[2] = e0 * inv;
    wb[3] = e1 * inv;
  }
}

// ---------------- GCN gather1 + gemm64 fused: p1=tanh(agg*rdi+bg1); out2=bf16((p1@Wg2)*rdo) ----
__global__ __launch_bounds__(256) void gcn_gather12_kernel(
    const int* __restrict__ rows, const int* __restrict__ cols, const ushort_t* __restrict__ X,
    const float* __restrict__ rdi, const float* __restrict__ bg1, const float* __restrict__ Wg2,
    const float* __restrict__ rdo, ushort_t* __restrict__ out2) {
  int lane = threadIdx.x & 63, w = threadIdx.x >> 6;
  int n = blockIdx.x * 4 + w;
  if (n >= NN) return;
  int r0 = rows[n], r1 = rows[n + 1];
  float acc = 0.f;
  int j = r0;
  for (; j + 4 <= r1; j += 4) {
    int sa = cols[j], sb = cols[j + 1], sc = cols[j + 2], sd = cols[j + 3];
    acc += bf2f(X[(size_t)sa * 64 + lane]) + bf2f(X[(size_t)sb * 64 + lane]) +
           bf2f(X[(size_t)sc * 64 + lane]) + bf2f(X[(size_t)sd * 64 + lane]);
  }
  for (; j < r1; ++j) acc += bf2f(X[(size_t)cols[j] * 64 + lane]);
  float p = tanhf(acc * rdi[n] + bg1[lane]);
  float o = 0.f;
#pragma unroll
  for (int k = 0; k < 64; ++k) o = fmaf(__shfl(p, k), Wg2[k * 64 + lane], o);
  out2[(size_t)n * 64 + lane] = f2bf(o * rdo[n]);
}

// ---------------- GCN gather layer2 (bf16) fused with Z write ----------------
__global__ __launch_bounds__(256) void gcn_gather2_kernel(
    const int* __restrict__ rows, const int* __restrict__ cols, const ushort_t* __restrict__ X,
    const float* __restrict__ rdi, const float* __restrict__ Femb, float* __restrict__ dout) {
  int lane = threadIdx.x & 63, w = threadIdx.x >> 6;
  int n = blockIdx.x * 4 + w;
  if (n >= NN) return;
  int r0 = rows[n], r1 = rows[n + 1];
  float acc = 0.f;
  int j = r0;
  for (; j + 4 <= r1; j += 4) {
    int sa = cols[j], sb = cols[j + 1], sc = cols[j + 2], sd = cols[j + 3];
    acc += bf2f(X[(size_t)sa * 64 + lane]) + bf2f(X[(size_t)sb * 64 + lane]) +
           bf2f(X[(size_t)sc * 64 + lane]) + bf2f(X[(size_t)sd * 64 + lane]);
  }
  for (; j < r1; ++j) acc += bf2f(X[(size_t)cols[j] * 64 + lane]);
  dout[1 + (size_t)n * 64 + lane] = 0.5f * (Femb[(size_t)n * 64 + lane] + acc * rdi[n]);
}

// ---------------- trace ----------------
__global__ __launch_bounds__(256) void tr_kernel(const int* __restrict__ asrc,
                                                 const int* __restrict__ adst,
                                                 const int* __restrict__ kptr,
                                                 const float* __restrict__ dout,
                                                 float* __restrict__ trbuf) {
  __shared__ float wsum[4];
  int e = blockIdx.x * 256 + threadIdx.x;
  int k = *kptr;
  float local = 0.f;
  if (e < NE) {
    int a = asrc[e], b = adst[e];
    const float* Za = dout + 1 + (size_t)a * 64;
    const float* Zb = dout + 1 + (size_t)b * 64;
    for (int c = 0; c < k; ++c) {
      float d2 = Za[c] - Zb[c];
      local += d2 * d2;
    }
  }
#pragma unroll
  for (int off = 32; off > 0; off >>= 1) local += __shfl_down(local, off);
  int lane = threadIdx.x & 63, w = threadIdx.x >> 6;
  if (lane == 0) wsum[w] = local;
  __syncthreads();
  if (threadIdx.x == 0) trbuf[blockIdx.x] = wsum[0] + wsum[1] + wsum[2] + wsum[3];
}

__global__ __launch_bounds__(256) void tr_reduce_kernel(const float* __restrict__ trbuf,
                                                        float* __restrict__ dout) {
  __shared__ float sm[4];
  int t = threadIdx.x;
  float a = 0.f;
  for (int i = t; i < NTRB; i += 256) a += trbuf[i];
  a = wred(a);
  int lane = t & 63, w = t >> 6;
  if (lane == 0) sm[w] = a;
  __syncthreads();
  if (t == 0) dout[0] = 0.5f * (sm[0] + sm[1] + sm[2] + sm[3]);
}

extern "C" void kernel_launch(void* const* d_in, const int* in_sizes, int n_in, void* d_out,
                              int out_size, void* d_ws, size_t ws_size, hipStream_t stream) {
  const float* feat0 = (const float*)d_in[0];
  const float* feat1 = (const float*)d_in[1];
  const float* sen = (const float*)d_in[2];
  const float* Wgat0 = (const float*)d_in[3];
  const float* al0 = (const float*)d_in[4];
  const float* ar0 = (const float*)d_in[5];
  const float* b0 = (const float*)d_in[6];
  const float* Wgat1 = (const float*)d_in[7];
  const float* al1 = (const float*)d_in[8];
  const float* ar1 = (const float*)d_in[9];
  const float* b1 = (const float*)d_in[10];
  const float* Wp1 = (const float*)d_in[11];
  const float* bp1 = (const float*)d_in[12];
  const float* wp2 = (const float*)d_in[13];
  const float* Wf = (const float*)d_in[14];
  const float* bf = (const float*)d_in[15];
  const float* Wg1 = (const float*)d_in[16];
  const float* bg1 = (const float*)d_in[17];
  const float* Wg2 = (const float*)d_in[18];
  const int* src0 = (const int*)d_in[19];
  const int* dst0 = (const int*)d_in[20];
  const int* src1 = (const int*)d_in[21];
  const int* dst1 = (const int*)d_in[22];
  const int* gsrc = (const int*)d_in[23];
  const int* gdst = (const int*)d_in[24];
  const int* asrc = (const int*)d_in[25];
  const int* adst = (const int*)d_in[26];
  const int* kptr = (const int*)d_in[27];
  float* out = (float*)d_out;
  float* ws = (float*)d_ws;

  // ---- workspace layout (float-element offsets) ----
  // ZERO region [0 .. 210004): wb(4) cnt(120000 int: dst0,dst1,gdst,gsrc-deg) cnt2(90000 int)
  float* wb = ws;                               // 4
  int* cnt = (int*)(ws + 4);                    // 4*30000
  int* cnt2 = (int*)(ws + 120004);              // 3*30000
  float* rdo = ws + 210004;                     // 30000
  float* rdi = ws + 240004;                     // 30000
  int* rows = (int*)(ws + 270004);              // 3*(NN+1)=90003
  int* bsum = (int*)(ws + 360008);              // 354
  int* boff = (int*)(ws + 360364);              // 354
  int* cols = (int*)(ws + 360720);              // 3*NE = 1,440,000
  float* el0 = ws + 1800720;                    // 120000
  float* er0 = ws + 1920720;                    // 120000
  float* el1 = ws + 2040720;                    // 120000
  float* er1 = ws + 2160720;                    // 120000
  float* Femb = ws + 2280720;                   // 1,920,000
  float* pbuf = ws + 4200720;                   // 2*NMT = 470
  float* trbuf = ws + 4201192;                  // 1875
  ushort_t* h0 = (ushort_t*)(ws + 4203068);     // 7,680,000 bf16 (3,840,000 fl)
  ushort_t* h1 = (ushort_t*)(ws + 8043068);     // 7,680,000 bf16
  ushort_t* z0 = (ushort_t*)(ws + 11883068);    // 7,680,000 bf16
  ushort_t* z1 = (ushort_t*)(ws + 15723068);    // 7,680,000 bf16
  ushort_t* gcnA = (ushort_t*)(ws + 19563068);  // 1,920,000 bf16
  ushort_t* gcnA2 = (ushort_t*)(ws + 20523068); // 1,920,000 bf16
  ushort_t* WT0 = (ushort_t*)(ws + 21483068);   // 65536 bf16
  ushort_t* WT1 = (ushort_t*)(ws + 21515836);   // 32768 bf16
  ushort_t* Wp1T = (ushort_t*)(ws + 21532220);  // 16384 bf16
  ushort_t* WfT = (ushort_t*)(ws + 21540412);   // 16384 bf16
  ushort_t* Wg1T = (ushort_t*)(ws + 21548604);  // 16384 bf16

  int* rows_g = rows + 2 * (NN + 1);
  int* cols_g = cols + 2 * NE;
  int* cnt_deg = cnt + 3 * NN;

  zero4_kernel<<<206, 256, 0, stream>>>((float4*)ws, 52501);

  // ---- weight prep (single launch) ----
  wt_all_kernel<<<576, 256, 0, stream>>>(Wgat0, Wgat1, Wp1, Wf, Wg1, WT0, WT1, Wp1T, WfT, Wg1T);

  // ---- CSR build for 3 graphs (by dst) + gsrc out-degree ----
  hist_kernel<<<dim3(1875, 4), 256, 0, stream>>>(dst0, dst1, gdst, gsrc, cnt);
  scan_blocks_kernel<<<dim3(NBLK, 3), 256, 0, stream>>>(cnt, rows, bsum);
  scan_tops_kernel<<<dim3(1, 3), 128, 0, stream>>>(bsum, boff);
  add_off_kernel<<<dim3(NBLK, 3), 256, 0, stream>>>(rows, boff);
  scatter_kernel<<<dim3(1875, 3), 256, 0, stream>>>(src0, src1, gsrc, dst0, dst1, gdst, rows,
                                                    cnt2, cols);
  rdeg2_kernel<<<NBLK, 256, 0, stream>>>(cnt_deg, rdo, rdi, rows_g);

  // ---- GAT dense projections (MFMA, bf16 h out, fused el/er) ----
  mfma_h_kernel<<<dim3(NMT, 4), 256, 0, stream>>>(feat0, WT0, 256, h0, al0, ar0, el0, er0);
  mfma_h_kernel<<<dim3(NMT, 4), 256, 0, stream>>>(feat1, WT1, 128, h1, al1, ar1, el1, er1);

  // ---- GAT gather (both graphs) -> bf16 z ----
  gat_node_kernel<<<dim3(7500, 2), 256, 0, stream>>>(rows, cols, el0, er0, h0, b0, z0,
                                                     rows + (NN + 1), cols + NE, el1, er1, h1,
                                                     b1, z1);

  // ---- attention pooling -> beta -> Femb ----
  mfma_attn_kernel<<<dim3(NMT, 2), 256, 0, stream>>>(z0, z1, Wp1T, bp1, wp2, pbuf);
  attn_reduce_kernel<<<1, 256, 0, stream>>>(pbuf, wb);
  mfma_femb_kernel<<<NMT, 256, 0, stream>>>(z0, z1, wb, WfT, bf, Femb);

  // ---- GCN path ----
  mfma_gcn1_kernel<<<NMT, 256, 0, stream>>>(sen, Wg1T, rdo, gcnA);
  gcn_gather12_kernel<<<7500, 256, 0, stream>>>(rows_g, cols_g, gcnA, rdi, bg1, Wg2, rdo, gcnA2);
  gcn_gather2_kernel<<<7500, 256, 0, stream>>>(rows_g, cols_g, gcnA2, rdi, Femb, out);

  // ---- trace ----
  tr_kernel<<<NTRB, 256, 0, stream>>>(asrc, adst, kptr, out, trbuf);
  tr_reduce_kernel<<<1, 256, 0, stream>>>(trbuf, out);
}

// Round 8
// 575.959 us; speedup vs baseline: 8.6352x; 1.0047x over previous
//
#include <hip/hip_runtime.h>
#include <math.h>

#define NN 30000
#define NE 480000
#define NBLK 118   // ceil(30000/256)
#define NMT 235    // ceil(30000/128) MFMA row-tiles
#define NTRB 1875  // blocks in tr pass
#define CAPD 128   // LDS-cached attention weights per node (deg mean 16; P(>128)~0, fallback exists)

typedef unsigned short ushort_t;
typedef unsigned int uint_t;
typedef __attribute__((ext_vector_type(8))) short short8;
typedef __attribute__((ext_vector_type(4))) float f32x4;

__device__ __forceinline__ ushort_t f2bf(float x) {
  uint_t u = __float_as_uint(x);
  u = (u + 0x7FFF + ((u >> 16) & 1)) >> 16;
  return (ushort_t)u;
}
__device__ __forceinline__ float bf2f(ushort_t v) {
  return __uint_as_float(((uint_t)v) << 16);
}

// ---------------- fill ----------------
__global__ void zero4_kernel(float4* __restrict__ p, int n4) {
  int g = blockIdx.x * 256 + threadIdx.x;
  if (g < n4) p[g] = make_float4(0.f, 0.f, 0.f, 0.f);
}

__device__ __forceinline__ float wred(float v) {
#pragma unroll
  for (int off = 32; off > 0; off >>= 1) v += __shfl_xor(v, off);
  return v;
}

// ---------------- merged weight prep: 5 transposes fp32->bf16 ----------------
__global__ void wt_all_kernel(const float* __restrict__ W0, const float* __restrict__ W1,
                              const float* __restrict__ W2, const float* __restrict__ W3,
                              const float* __restrict__ W4, ushort_t* __restrict__ T0,
                              ushort_t* __restrict__ T1, ushort_t* __restrict__ T2,
                              ushort_t* __restrict__ T3, ushort_t* __restrict__ T4) {
  int id = blockIdx.x * 256 + threadIdx.x;
  const float* W;
  ushort_t* T;
  int K, N, base;
  if (id < 65536) { W = W0; T = T0; K = 256; N = 256; base = 0; }
  else if (id < 98304) { W = W1; T = T1; K = 128; N = 256; base = 65536; }
  else if (id < 114688) { W = W2; T = T2; K = 256; N = 64; base = 98304; }
  else if (id < 131072) { W = W3; T = T3; K = 256; N = 64; base = 114688; }
  else if (id < 147456) { W = W4; T = T4; K = 256; N = 64; base = 131072; }
  else return;
  int l = id - base;
  int k = l / N, n = l - k * N;
  T[(size_t)n * K + k] = f2bf(W[l]);
}

// ================= MFMA cores =================
// BM=128, BN=64, BK=32; 256 threads = 4 waves; wave w owns rows [w*32, w*32+32).
// LDS rows padded to 40 shorts (80 B).

// fp32 A input (converted to bf16 during staging)
__device__ __forceinline__ void mfma_core_f32(const float* __restrict__ A0,
                                              const ushort_t* __restrict__ BT, int K, int bm,
                                              short* __restrict__ As, short* __restrict__ Bs,
                                              f32x4 acc[2][4]) {
  int tid = threadIdx.x;
  int lane = tid & 63, w = tid >> 6;
  int q = lane >> 4, mr = lane & 15;
#pragma unroll 1
  for (int k0 = 0; k0 < K; k0 += 32) {
    {
      int r = tid >> 1, hf = tid & 1;
      int gr = bm + r;
      float4 f0 = make_float4(0.f, 0.f, 0.f, 0.f), f1 = f0, f2 = f0, f3 = f0;
      if (gr < NN) {
        const float4* pa = (const float4*)(A0 + (size_t)gr * K + k0 + hf * 16);
        f0 = pa[0]; f1 = pa[1]; f2 = pa[2]; f3 = pa[3];
      }
      short8 lo, hi;
      lo[0] = (short)f2bf(f0.x); lo[1] = (short)f2bf(f0.y);
      lo[2] = (short)f2bf(f0.z); lo[3] = (short)f2bf(f0.w);
      lo[4] = (short)f2bf(f1.x); lo[5] = (short)f2bf(f1.y);
      lo[6] = (short)f2bf(f1.z); lo[7] = (short)f2bf(f1.w);
      hi[0] = (short)f2bf(f2.x); hi[1] = (short)f2bf(f2.y);
      hi[2] = (short)f2bf(f2.z); hi[3] = (short)f2bf(f2.w);
      hi[4] = (short)f2bf(f3.x); hi[5] = (short)f2bf(f3.y);
      hi[6] = (short)f2bf(f3.z); hi[7] = (short)f2bf(f3.w);
      short* dst = As + r * 40 + hf * 16;
      *(short8*)(dst) = lo;
      *(short8*)(dst + 8) = hi;
    }
    {
      int n = tid >> 2, qk = tid & 3;
      short8 bv = *(const short8*)((const short*)BT + (size_t)n * K + k0 + qk * 8);
      *(short8*)(Bs + n * 40 + qk * 8) = bv;
    }
    __syncthreads();
    short8 a0 = *(short8*)(As + (w * 32 + mr) * 40 + q * 8);
    short8 a1 = *(short8*)(As + (w * 32 + 16 + mr) * 40 + q * 8);
#pragma unroll
    for (int j = 0; j < 4; ++j) {
      short8 b = *(short8*)(Bs + (j * 16 + mr) * 40 + q * 8);
      acc[0][j] = __builtin_amdgcn_mfma_f32_16x16x32_bf16(a0, b, acc[0][j], 0, 0, 0);
      acc[1][j] = __builtin_amdgcn_mfma_f32_16x16x32_bf16(a1, b, acc[1][j], 0, 0, 0);
    }
    __syncthreads();
  }
}

// bf16 A input (K fixed = 256); optional blend of two bf16 sources
template <bool BLEND>
__device__ __forceinline__ void mfma_core_bf(const ushort_t* __restrict__ A0,
                                             const ushort_t* __restrict__ A1, float w0, float w1,
                                             const ushort_t* __restrict__ BT, int bm,
                                             short* __restrict__ As, short* __restrict__ Bs,
                                             f32x4 acc[2][4]) {
  int tid = threadIdx.x;
  int lane = tid & 63, w = tid >> 6;
  int q = lane >> 4, mr = lane & 15;
#pragma unroll 1
  for (int k0 = 0; k0 < 256; k0 += 32) {
    {
      int r = tid >> 1, hf = tid & 1;
      int gr = bm + r;
      short8 v0 = {0, 0, 0, 0, 0, 0, 0, 0}, v1 = {0, 0, 0, 0, 0, 0, 0, 0};
      if (gr < NN) {
        const short* p0 = (const short*)A0 + (size_t)gr * 256 + k0 + hf * 16;
        v0 = *(const short8*)p0;
        v1 = *(const short8*)(p0 + 8);
        if (BLEND) {
          const short* p1 = (const short*)A1 + (size_t)gr * 256 + k0 + hf * 16;
          short8 y0 = *(const short8*)p1, y1 = *(const short8*)(p1 + 8);
#pragma unroll
          for (int t = 0; t < 8; ++t) {
            v0[t] = (short)f2bf(w0 * bf2f((ushort_t)v0[t]) + w1 * bf2f((ushort_t)y0[t]));
            v1[t] = (short)f2bf(w0 * bf2f((ushort_t)v1[t]) + w1 * bf2f((ushort_t)y1[t]));
          }
        }
      }
      short* dst = As + r * 40 + hf * 16;
      *(short8*)(dst) = v0;
      *(short8*)(dst + 8) = v1;
    }
    {
      int n = tid >> 2, qk = tid & 3;
      short8 bv = *(const short8*)((const short*)BT + (size_t)n * 256 + k0 + qk * 8);
      *(short8*)(Bs + n * 40 + qk * 8) = bv;
    }
    __syncthreads();
    short8 a0 = *(short8*)(As + (w * 32 + mr) * 40 + q * 8);
    short8 a1 = *(short8*)(As + (w * 32 + 16 + mr) * 40 + q * 8);
#pragma unroll
    for (int j = 0; j < 4; ++j) {
      short8 b = *(short8*)(Bs + (j * 16 + mr) * 40 + q * 8);
      acc[0][j] = __builtin_amdgcn_mfma_f32_16x16x32_bf16(a0, b, acc[0][j], 0, 0, 0);
      acc[1][j] = __builtin_amdgcn_mfma_f32_16x16x32_bf16(a1, b, acc[1][j], 0, 0, 0);
    }
    __syncthreads();
  }
}

// ---- h = feat @ Wgat -> bf16 [NN][256] + fused el/er; grid (NMT, 4), blockIdx.y = head ----
__global__ __launch_bounds__(256) void mfma_h_kernel(const float* __restrict__ A,
                                                     const ushort_t* __restrict__ WT, int K,
                                                     ushort_t* __restrict__ H,
                                                     const float* __restrict__ al,
                                                     const float* __restrict__ ar,
                                                     float* __restrict__ el,
                                                     float* __restrict__ er) {
  __shared__ short As[128 * 40];
  __shared__ short Bs[64 * 40];
  int head = blockIdx.y;
  int bm = blockIdx.x * 128, bn = head * 64;
  f32x4 acc[2][4];
#pragma unroll
  for (int i = 0; i < 2; ++i)
#pragma unroll
    for (int j = 0; j < 4; ++j) acc[i][j] = (f32x4){0.f, 0.f, 0.f, 0.f};
  mfma_core_f32(A, WT + (size_t)bn * K, K, bm, As, Bs, acc);
  int lane = threadIdx.x & 63, w = threadIdx.x >> 6;
  int q = lane >> 4, mr = lane & 15;
  float alv[4], arv[4];
#pragma unroll
  for (int j = 0; j < 4; ++j) {
    alv[j] = al[head * 64 + j * 16 + mr];
    arv[j] = ar[head * 64 + j * 16 + mr];
  }
#pragma unroll
  for (int i = 0; i < 2; ++i)
#pragma unroll
    for (int r = 0; r < 4; ++r) {
      int gr = bm + w * 32 + i * 16 + q * 4 + r;
      float pl = 0.f, pr = 0.f;
#pragma unroll
      for (int j = 0; j < 4; ++j) {
        pl = fmaf(acc[i][j][r], alv[j], pl);
        pr = fmaf(acc[i][j][r], arv[j], pr);
      }
#pragma unroll
      for (int m = 1; m < 16; m <<= 1) {
        pl += __shfl_xor(pl, m);
        pr += __shfl_xor(pr, m);
      }
      if (gr < NN) {
        if (mr == 0) {
          el[gr * 4 + head] = pl;
          er[gr * 4 + head] = pr;
        }
#pragma unroll
        for (int j = 0; j < 4; ++j) H[(size_t)gr * 256 + bn + j * 16 + mr] = f2bf(acc[i][j][r]);
      }
    }
}

// ---- attn partials from bf16 z: sum tanh(z@Wp1+bp1)*wp2, grid (NMT, 2) ----
__global__ __launch_bounds__(256) void mfma_attn_kernel(
    const ushort_t* __restrict__ z0, const ushort_t* __restrict__ z1,
    const ushort_t* __restrict__ WT, const float* __restrict__ bp1,
    const float* __restrict__ wp2, float* __restrict__ pbuf) {
  __shared__ short As[128 * 40];
  __shared__ short Bs[64 * 40];
  __shared__ float wsum[4];
  const ushort_t* A = blockIdx.y ? z1 : z0;
  int bm = blockIdx.x * 128;
  f32x4 acc[2][4];
#pragma unroll
  for (int i = 0; i < 2; ++i)
#pragma unroll
    for (int j = 0; j < 4; ++j) acc[i][j] = (f32x4){0.f, 0.f, 0.f, 0.f};
  mfma_core_bf<false>(A, nullptr, 0.f, 0.f, WT, bm, As, Bs, acc);
  int lane = threadIdx.x & 63, w = threadIdx.x >> 6;
  int q = lane >> 4, mr = lane & 15;
  float local = 0.f;
#pragma unroll
  for (int j = 0; j < 4; ++j) {
    int col = j * 16 + mr;
    float bp = bp1[col], wp = wp2[col];
#pragma unroll
    for (int i = 0; i < 2; ++i)
#pragma unroll
      for (int r = 0; r < 4; ++r) {
        int gr = bm + w * 32 + i * 16 + q * 4 + r;
        if (gr < NN) local += tanhf(acc[i][j][r] + bp) * wp;
      }
  }
  local = wred(local);
  if (lane == 0) wsum[w] = local;
  __syncthreads();
  if (threadIdx.x == 0)
    pbuf[blockIdx.y * NMT + blockIdx.x] = wsum[0] + wsum[1] + wsum[2] + wsum[3];
}

// ---- femb: Femb = (b0*z0 + b1*z1) @ Wf + bf (bf16 z), grid (NMT) ----
__global__ __launch_bounds__(256) void mfma_femb_kernel(
    const ushort_t* __restrict__ z0, const ushort_t* __restrict__ z1,
    const float* __restrict__ wb, const ushort_t* __restrict__ WT, const float* __restrict__ bf,
    float* __restrict__ Femb) {
  __shared__ short As[128 * 40];
  __shared__ short Bs[64 * 40];
  int bm = blockIdx.x * 128;
  float beta0 = wb[2], beta1 = wb[3];
  f32x4 acc[2][4];
#pragma unroll
  for (int i = 0; i < 2; ++i)
#pragma unroll
    for (int j = 0; j < 4; ++j) acc[i][j] = (f32x4){0.f, 0.f, 0.f, 0.f};
  mfma_core_bf<true>(z0, z1, beta0, beta1, WT, bm, As, Bs, acc);
  int lane = threadIdx.x & 63, w = threadIdx.x >> 6;
  int q = lane >> 4, mr = lane & 15;
#pragma unroll
  for (int j = 0; j < 4; ++j) {
    int col = j * 16 + mr;
    float bv = bf[col];
#pragma unroll
    for (int i = 0; i < 2; ++i)
#pragma unroll
      for (int r = 0; r < 4; ++r) {
        int gr = bm + w * 32 + i * 16 + q * 4 + r;
        if (gr < NN) Femb[(size_t)gr * 64 + col] = acc[i][j][r] + bv;
      }
  }
}

// ---- gcn1: out = bf16((sen @ Wg1) * rdo), grid (NMT) ----
__global__ __launch_bounds__(256) void mfma_gcn1_kernel(const float* __restrict__ X,
                                                        const ushort_t* __restrict__ WT,
                                                        const float* __restrict__ rdo,
                                                        ushort_t* __restrict__ out) {
  __shared__ short As[128 * 40];
  __shared__ short Bs[64 * 40];
  int bm = blockIdx.x * 128;
  f32x4 acc[2][4];
#pragma unroll
  for (int i = 0; i < 2; ++i)
#pragma unroll
    for (int j = 0; j < 4; ++j) acc[i][j] = (f32x4){0.f, 0.f, 0.f, 0.f};
  mfma_core_f32(X, WT, 256, bm, As, Bs, acc);
  int lane = threadIdx.x & 63, w = threadIdx.x >> 6;
  int q = lane >> 4, mr = lane & 15;
#pragma unroll
  for (int i = 0; i < 2; ++i)
#pragma unroll
    for (int r = 0; r < 4; ++r) {
      int gr = bm + w * 32 + i * 16 + q * 4 + r;
      if (gr < NN) {
        float sc = rdo[gr];
#pragma unroll
        for (int j = 0; j < 4; ++j) out[(size_t)gr * 64 + j * 16 + mr] = f2bf(acc[i][j][r] * sc);
      }
    }
}

// ---------------- CSR build: histogram over dst (g=0..2) + gsrc degree (g=3) ----------------
__global__ void hist_kernel(const int* __restrict__ d0, const int* __restrict__ d1,
                            const int* __restrict__ d2, const int* __restrict__ d3,
                            int* __restrict__ cnt) {
  int g = blockIdx.y;
  const int* d = g == 0 ? d0 : g == 1 ? d1 : g == 2 ? d2 : d3;
  int e = blockIdx.x * 256 + threadIdx.x;
  if (e < NE) atomicAdd(&cnt[g * NN + d[e]], 1);
}

__global__ __launch_bounds__(256) void scan_blocks_kernel(const int* __restrict__ cnt,
                                                          int* __restrict__ rows,
                                                          int* __restrict__ bsum) {
  __shared__ int sm[256];
  int g = blockIdx.y, t = threadIdx.x;
  int i = blockIdx.x * 256 + t;
  int v = (i < NN) ? cnt[g * NN + i] : 0;
  sm[t] = v;
  __syncthreads();
#pragma unroll
  for (int off = 1; off < 256; off <<= 1) {
    int tmp = (t >= off) ? sm[t - off] : 0;
    __syncthreads();
    sm[t] += tmp;
    __syncthreads();
  }
  if (i < NN) rows[g * (NN + 1) + i] = sm[t] - v;  // exclusive
  if (t == 255) bsum[g * NBLK + blockIdx.x] = sm[255];
}

__global__ __launch_bounds__(128) void scan_tops_kernel(int* __restrict__ bsum,
                                                        int* __restrict__ boff) {
  __shared__ int sm[128];
  int g = blockIdx.y, t = threadIdx.x;
  int v = (t < NBLK) ? bsum[g * NBLK + t] : 0;
  sm[t] = v;
  __syncthreads();
#pragma unroll
  for (int off = 1; off < 128; off <<= 1) {
    int tmp = (t >= off) ? sm[t - off] : 0;
    __syncthreads();
    sm[t] += tmp;
    __syncthreads();
  }
  if (t < NBLK) boff[g * NBLK + t] = sm[t] - v;  // exclusive
}

__global__ void add_off_kernel(int* __restrict__ rows, const int* __restrict__ boff) {
  int g = blockIdx.y, t = threadIdx.x;
  int i = blockIdx.x * 256 + t;
  if (i < NN) rows[g * (NN + 1) + i] += boff[g * NBLK + blockIdx.x];
  if (blockIdx.x == 0 && t == 0) rows[g * (NN + 1) + NN] = NE;
}

__global__ void scatter_kernel(const int* __restrict__ s0, const int* __restrict__ s1,
                               const int* __restrict__ s2, const int* __restrict__ d0,
                               const int* __restrict__ d1, const int* __restrict__ d2,
                               const int* __restrict__ rows, int* __restrict__ cnt2,
                               int* __restrict__ cols) {
  int g = blockIdx.y;
  const int* sp = g == 0 ? s0 : g == 1 ? s1 : s2;
  const int* dp = g == 0 ? d0 : g == 1 ? d1 : d2;
  int e = blockIdx.x * 256 + threadIdx.x;
  if (e >= NE) return;
  int d = dp[e];
  int pos = rows[g * (NN + 1) + d] + atomicAdd(&cnt2[g * NN + d], 1);
  cols[(size_t)g * NE + pos] = sp[e];
}

__global__ void rdeg2_kernel(const int* __restrict__ cnt_deg, float* __restrict__ rdo,
                             float* __restrict__ rdi, const int* __restrict__ rows_g) {
  int n = blockIdx.x * 256 + threadIdx.x;
  if (n >= NN) return;
  rdo[n] = rsqrtf(fmaxf((float)cnt_deg[n], 1.f));
  float di = (float)(rows_g[n + 1] - rows_g[n]);
  rdi[n] = rsqrtf(fmaxf(di, 1.f));
}

// ---------------- GAT per-node gather (both graphs), bf16 h, bf16 z out ----------------
// Phase A computes exps once per edge -> LDS cache; phase B = LDS read + gather + fma;
// softmax denominator folded into accumulator at the end.
__global__ __launch_bounds__(256) void gat_node_kernel(
    const int* __restrict__ rows0, const int* __restrict__ cols0, const float* __restrict__ el0,
    const float* __restrict__ er0, const ushort_t* __restrict__ h0,
    const float* __restrict__ bias0, ushort_t* __restrict__ zz0, const int* __restrict__ rows1,
    const int* __restrict__ cols1, const float* __restrict__ el1, const float* __restrict__ er1,
    const ushort_t* __restrict__ h1, const float* __restrict__ bias1,
    ushort_t* __restrict__ zz1) {
  __shared__ float aw[4][CAPD][4];  // 8 KB
  int g = blockIdx.y;
  const int* rows = g ? rows1 : rows0;
  const int* cols = g ? cols1 : cols0;
  const float* el = g ? el1 : el0;
  const float* er = g ? er1 : er0;
  const ushort_t* h = g ? h1 : h0;
  const float* bias = g ? bias1 : bias0;
  ushort_t* z = g ? zz1 : zz0;

  int lane = threadIdx.x & 63, w = threadIdx.x >> 6;
  int n = blockIdx.x * 4 + w;  // grid 7500*4 == NN exactly, no OOB
  int r0 = rows[n], r1 = rows[n + 1];
  int deg = r1 - r0;
  float4 er4 = *(const float4*)&er[n * 4];
  // ---- phase A: exps once per edge, cached in LDS ----
  float s0 = 0.f, s1 = 0.f, s2 = 0.f, s3 = 0.f;
  for (int j = lane; j < deg; j += 64) {
    int s = cols[r0 + j];
    float4 elv = *(const float4*)&el[s * 4];
    float v0 = elv.x + er4.x; v0 = v0 > 0.f ? v0 : 0.2f * v0;
    float v1 = elv.y + er4.y; v1 = v1 > 0.f ? v1 : 0.2f * v1;
    float v2 = elv.z + er4.z; v2 = v2 > 0.f ? v2 : 0.2f * v2;
    float v3 = elv.w + er4.w; v3 = v3 > 0.f ? v3 : 0.2f * v3;
    float e0 = __expf(v0), e1 = __expf(v1), e2 = __expf(v2), e3 = __expf(v3);
    s0 += e0; s1 += e1; s2 += e2; s3 += e3;
    if (j < CAPD) {
      aw[w][j][0] = e0; aw[w][j][1] = e1; aw[w][j][2] = e2; aw[w][j][3] = e3;
    }
  }
  s0 = wred(s0); s1 = wred(s1); s2 = wred(s2); s3 = wred(s3);
  __syncthreads();
  int hh = lane >> 4;
  float denom = hh == 0 ? s0 : hh == 1 ? s1 : hh == 2 ? s2 : s3;
  float myer = hh == 0 ? er4.x : hh == 1 ? er4.y : hh == 2 ? er4.z : er4.w;
  float invd = (deg > 0) ? 1.f / denom : 0.f;
  // ---- phase B: exp-weighted gather (normalize at the end) ----
  float4 acc = make_float4(0.f, 0.f, 0.f, 0.f);
  int jc = deg < CAPD ? deg : CAPD;
  int j = 0;
  for (; j + 4 <= jc; j += 4) {
    int sa = cols[r0 + j], sb = cols[r0 + j + 1], sc = cols[r0 + j + 2], sd = cols[r0 + j + 3];
    float aa = aw[w][j][hh], ab = aw[w][j + 1][hh], ac = aw[w][j + 2][hh], ad = aw[w][j + 3][hh];
    ushort4 ua = *(const ushort4*)&h[(size_t)sa * 256 + lane * 4];
    ushort4 ub = *(const ushort4*)&h[(size_t)sb * 256 + lane * 4];
    ushort4 uc = *(const ushort4*)&h[(size_t)sc * 256 + lane * 4];
    ushort4 ud = *(const ushort4*)&h[(size_t)sd * 256 + lane * 4];
    acc.x = fmaf(aa, bf2f(ua.x), acc.x); acc.y = fmaf(aa, bf2f(ua.y), acc.y);
    acc.z = fmaf(aa, bf2f(ua.z), acc.z); acc.w = fmaf(aa, bf2f(ua.w), acc.w);
    acc.x = fmaf(ab, bf2f(ub.x), acc.x); acc.y = fmaf(ab, bf2f(ub.y), acc.y);
    acc.z = fmaf(ab, bf2f(ub.z), acc.z); acc.w = fmaf(ab, bf2f(ub.w), acc.w);
    acc.x = fmaf(ac, bf2f(uc.x), acc.x); acc.y = fmaf(ac, bf2f(uc.y), acc.y);
    acc.z = fmaf(ac, bf2f(uc.z), acc.z); acc.w = fmaf(ac, bf2f(uc.w), acc.w);
    acc.x = fmaf(ad, bf2f(ud.x), acc.x); acc.y = fmaf(ad, bf2f(ud.y), acc.y);
    acc.z = fmaf(ad, bf2f(ud.z), acc.z); acc.w = fmaf(ad, bf2f(ud.w), acc.w);
  }
  for (; j < jc; ++j) {
    int s = cols[r0 + j];
    float a = aw[w][j][hh];
    ushort4 hu = *(const ushort4*)&h[(size_t)s * 256 + lane * 4];
    acc.x = fmaf(a, bf2f(hu.x), acc.x);
    acc.y = fmaf(a, bf2f(hu.y), acc.y);
    acc.z = fmaf(a, bf2f(hu.z), acc.z);
    acc.w = fmaf(a, bf2f(hu.w), acc.w);
  }
  for (; j < deg; ++j) {  // rare overflow fallback (deg > CAPD)
    int s = cols[r0 + j];
    float v = el[s * 4 + hh] + myer;
    v = v > 0.f ? v : 0.2f * v;
    float a = __expf(v);
    ushort4 hu = *(const ushort4*)&h[(size_t)s * 256 + lane * 4];
    acc.x = fmaf(a, bf2f(hu.x), acc.x);
    acc.y = fmaf(a, bf2f(hu.y), acc.y);
    acc.z = fmaf(a, bf2f(hu.z), acc.z);
    acc.w = fmaf(a, bf2f(hu.w), acc.w);
  }
  float4 bv = *(const float4*)&bias[lane * 4];
  ushort4 o;
  o.x = f2bf(fminf(fmaxf(acc.x * invd + bv.x, 0.f), 6.f));
  o.y = f2bf(fminf(fmaxf(acc.y * invd + bv.y, 0.f), 6.f));
  o.z = f2bf(fminf(fmaxf(acc.z * invd + bv.z, 0.f), 6.f));
  o.w = f2bf(fminf(fmaxf(acc.w * invd + bv.w, 0.f), 6.f));
  *(ushort4*)&z[(size_t)n * 256 + lane * 4] = o;
}

// ---- reduce partials -> beta ----
__global__ __launch_bounds__(256) void attn_reduce_kernel(const float* __restrict__ pbuf,
                                                          float* __restrict__ wb) {
  __shared__ float sm[8];
  int t = threadIdx.x;
  float a0 = 0.f, a1 = 0.f;
  for (int i = t; i < NMT; i += 256) {
    a0 += pbuf[i];
    a1 += pbuf[NMT + i];
  }
  a0 = wred(a0);
  a1 = wred(a1);
  int lane = t & 63, w = t >> 6;
  if (lane == 0) { sm[w] = a0; sm[4 + w] = a1; }
  __syncthreads();
  if (t == 0) {
    float w0 = (sm[0] + sm[1] + sm[2] + sm[3]) * (1.0f / NN);
    float w1 = (sm[4] + sm[5] + sm[6] + sm[7]) * (1.0f / NN);
    float mx = fmaxf(w0, w1);
    float e0 = expf(w0 - mx), e1 = expf(w1 - mx);
    float inv = 1.f / (e0 + e1);
    wb[2] = e0 * inv;
    wb[3] = e1 * inv;
  }
}

// ---------------- GCN gather1 + gemm64 fused ----------------
__global__ __launch_bounds__(256) void gcn_gather12_kernel(
    const int* __restrict__ rows, const int* __restrict__ cols, const ushort_t* __restrict__ X,
    const float* __restrict__ rdi, const float* __restrict__ bg1, const float* __restrict__ Wg2,
    const float* __restrict__ rdo, ushort_t* __restrict__ out2) {
  int lane = threadIdx.x & 63, w = threadIdx.x >> 6;
  int n = blockIdx.x * 4 + w;
  if (n >= NN) return;
  int r0 = rows[n], r1 = rows[n + 1];
  float acc = 0.f;
  int j = r0;
  for (; j + 4 <= r1; j += 4) {
    int sa = cols[j], sb = cols[j + 1], sc = cols[j + 2], sd = cols[j + 3];
    acc += bf2f(X[(size_t)sa * 64 + lane]) + bf2f(X[(size_t)sb * 64 + lane]) +
           bf2f(X[(size_t)sc * 64 + lane]) + bf2f(X[(size_t)sd * 64 + lane]);
  }
  for (; j < r1; ++j) acc += bf2f(X[(size_t)cols[j] * 64 + lane]);
  float p = tanhf(acc * rdi[n] + bg1[lane]);
  float o = 0.f;
#pragma unroll
  for (int k = 0; k < 64; ++k) o = fmaf(__shfl(p, k), Wg2[k * 64 + lane], o);
  out2[(size_t)n * 64 + lane] = f2bf(o * rdo[n]);
}

// ---------------- GCN gather layer2 fused with Z write + compact Zk ----------------
__global__ __launch_bounds__(256) void gcn_gather2_kernel(
    const int* __restrict__ rows, const int* __restrict__ cols, const ushort_t* __restrict__ X,
    const float* __restrict__ rdi, const float* __restrict__ Femb, const int* __restrict__ kptr,
    float* __restrict__ Zc, float* __restrict__ dout) {
  int lane = threadIdx.x & 63, w = threadIdx.x >> 6;
  int n = blockIdx.x * 4 + w;
  if (n >= NN) return;
  int r0 = rows[n], r1 = rows[n + 1];
  float acc = 0.f;
  int j = r0;
  for (; j + 4 <= r1; j += 4) {
    int sa = cols[j], sb = cols[j + 1], sc = cols[j + 2], sd = cols[j + 3];
    acc += bf2f(X[(size_t)sa * 64 + lane]) + bf2f(X[(size_t)sb * 64 + lane]) +
           bf2f(X[(size_t)sc * 64 + lane]) + bf2f(X[(size_t)sd * 64 + lane]);
  }
  for (; j < r1; ++j) acc += bf2f(X[(size_t)cols[j] * 64 + lane]);
  float zv = 0.5f * (Femb[(size_t)n * 64 + lane] + acc * rdi[n]);
  dout[1 + (size_t)n * 64 + lane] = zv;
  int k = *kptr;
  if (lane < k && lane < 16) Zc[(size_t)n * 16 + lane] = zv;  // compact L2-resident Zk
}

// ---------------- trace (reads compact Zc when k<=16, else full Z) ----------------
__global__ __launch_bounds__(256) void tr_kernel(const int* __restrict__ asrc,
                                                 const int* __restrict__ adst,
                                                 const int* __restrict__ kptr,
                                                 const float* __restrict__ Zc,
                                                 const float* __restrict__ dout,
                                                 float* __restrict__ trbuf) {
  __shared__ float wsum[4];
  int e = blockIdx.x * 256 + threadIdx.x;
  int k = *kptr;
  float local = 0.f;
  if (e < NE) {
    int a = asrc[e], b = adst[e];
    if (k <= 16) {
      const float* Za = Zc + (size_t)a * 16;
      const float* Zb = Zc + (size_t)b * 16;
      for (int c = 0; c < k; ++c) {
        float d2 = Za[c] - Zb[c];
        local += d2 * d2;
      }
    } else {
      const float* Za = dout + 1 + (size_t)a * 64;
      const float* Zb = dout + 1 + (size_t)b * 64;
      for (int c = 0; c < k; ++c) {
        float d2 = Za[c] - Zb[c];
        local += d2 * d2;
      }
    }
  }
#pragma unroll
  for (int off = 32; off > 0; off >>= 1) local += __shfl_down(local, off);
  int lane = threadIdx.x & 63, w = threadIdx.x >> 6;
  if (lane == 0) wsum[w] = local;
  __syncthreads();
  if (threadIdx.x == 0) trbuf[blockIdx.x] = wsum[0] + wsum[1] + wsum[2] + wsum[3];
}

__global__ __launch_bounds__(256) void tr_reduce_kernel(const float* __restrict__ trbuf,
                                                        float* __restrict__ dout) {
  __shared__ float sm[4];
  int t = threadIdx.x;
  float a = 0.f;
  for (int i = t; i < NTRB; i += 256) a += trbuf[i];
  a = wred(a);
  int lane = t & 63, w = t >> 6;
  if (lane == 0) sm[w] = a;
  __syncthreads();
  if (t == 0) dout[0] = 0.5f * (sm[0] + sm[1] + sm[2] + sm[3]);
}

extern "C" void kernel_launch(void* const* d_in, const int* in_sizes, int n_in, void* d_out,
                              int out_size, void* d_ws, size_t ws_size, hipStream_t stream) {
  const float* feat0 = (const float*)d_in[0];
  const float* feat1 = (const float*)d_in[1];
  const float* sen = (const float*)d_in[2];
  const float* Wgat0 = (const float*)d_in[3];
  const float* al0 = (const float*)d_in[4];
  const float* ar0 = (const float*)d_in[5];
  const float* b0 = (const float*)d_in[6];
  const float* Wgat1 = (const float*)d_in[7];
  const float* al1 = (const float*)d_in[8];
  const float* ar1 = (const float*)d_in[9];
  const float* b1 = (const float*)d_in[10];
  const float* Wp1 = (const float*)d_in[11];
  const float* bp1 = (const float*)d_in[12];
  const float* wp2 = (const float*)d_in[13];
  const float* Wf = (const float*)d_in[14];
  const float* bf = (const float*)d_in[15];
  const float* Wg1 = (const float*)d_in[16];
  const float* bg1 = (const float*)d_in[17];
  const float* Wg2 = (const float*)d_in[18];
  const int* src0 = (const int*)d_in[19];
  const int* dst0 = (const int*)d_in[20];
  const int* src1 = (const int*)d_in[21];
  const int* dst1 = (const int*)d_in[22];
  const int* gsrc = (const int*)d_in[23];
  const int* gdst = (const int*)d_in[24];
  const int* asrc = (const int*)d_in[25];
  const int* adst = (const int*)d_in[26];
  const int* kptr = (const int*)d_in[27];
  float* out = (float*)d_out;
  float* ws = (float*)d_ws;

  // ---- workspace layout (float-element offsets) ----
  // ZERO region [0 .. 210004): wb(4) cnt(120000 int) cnt2(90000 int)
  float* wb = ws;                               // 4
  int* cnt = (int*)(ws + 4);                    // 4*30000
  int* cnt2 = (int*)(ws + 120004);              // 3*30000
  float* rdo = ws + 210004;                     // 30000
  float* rdi = ws + 240004;                     // 30000
  int* rows = (int*)(ws + 270004);              // 3*(NN+1)=90003
  int* bsum = (int*)(ws + 360008);              // 354
  int* boff = (int*)(ws + 360364);              // 354
  int* cols = (int*)(ws + 360720);              // 3*NE = 1,440,000
  float* el0 = ws + 1800720;                    // 120000
  float* er0 = ws + 1920720;                    // 120000
  float* el1 = ws + 2040720;                    // 120000
  float* er1 = ws + 2160720;                    // 120000
  float* Femb = ws + 2280720;                   // 1,920,000
  float* pbuf = ws + 4200720;                   // 2*NMT = 470
  float* trbuf = ws + 4201192;                  // 1875
  ushort_t* h0 = (ushort_t*)(ws + 4203068);     // 7,680,000 bf16
  ushort_t* h1 = (ushort_t*)(ws + 8043068);     // 7,680,000 bf16
  ushort_t* z0 = (ushort_t*)(ws + 11883068);    // 7,680,000 bf16
  ushort_t* z1 = (ushort_t*)(ws + 15723068);    // 7,680,000 bf16
  ushort_t* gcnA = (ushort_t*)(ws + 19563068);  // 1,920,000 bf16
  ushort_t* gcnA2 = (ushort_t*)(ws + 20523068); // 1,920,000 bf16
  ushort_t* WT0 = (ushort_t*)(ws + 21483068);   // 65536 bf16
  ushort_t* WT1 = (ushort_t*)(ws + 21515836);   // 32768 bf16
  ushort_t* Wp1T = (ushort_t*)(ws + 21532220);  // 16384 bf16
  ushort_t* WfT = (ushort_t*)(ws + 21540412);   // 16384 bf16
  ushort_t* Wg1T = (ushort_t*)(ws + 21548604);  // 16384 bf16
  float* Zc = ws + 21556796;                    // 480,000 (NN x 16 compact Zk)

  int* rows_g = rows + 2 * (NN + 1);
  int* cols_g = cols + 2 * NE;
  int* cnt_deg = cnt + 3 * NN;

  zero4_kernel<<<206, 256, 0, stream>>>((float4*)ws, 52501);

  // ---- weight prep (single launch) ----
  wt_all_kernel<<<576, 256, 0, stream>>>(Wgat0, Wgat1, Wp1, Wf, Wg1, WT0, WT1, Wp1T, WfT, Wg1T);

  // ---- CSR build for 3 graphs (by dst) + gsrc out-degree ----
  hist_kernel<<<dim3(1875, 4), 256, 0, stream>>>(dst0, dst1, gdst, gsrc, cnt);
  scan_blocks_kernel<<<dim3(NBLK, 3), 256, 0, stream>>>(cnt, rows, bsum);
  scan_tops_kernel<<<dim3(1, 3), 128, 0, stream>>>(bsum, boff);
  add_off_kernel<<<dim3(NBLK, 3), 256, 0, stream>>>(rows, boff);
  scatter_kernel<<<dim3(1875, 3), 256, 0, stream>>>(src0, src1, gsrc, dst0, dst1, gdst, rows,
                                                    cnt2, cols);
  rdeg2_kernel<<<NBLK, 256, 0, stream>>>(cnt_deg, rdo, rdi, rows_g);

  // ---- GAT dense projections (MFMA, bf16 h out, fused el/er) ----
  mfma_h_kernel<<<dim3(NMT, 4), 256, 0, stream>>>(feat0, WT0, 256, h0, al0, ar0, el0, er0);
  mfma_h_kernel<<<dim3(NMT, 4), 256, 0, stream>>>(feat1, WT1, 128, h1, al1, ar1, el1, er1);

  // ---- GAT gather (both graphs) -> bf16 z ----
  gat_node_kernel<<<dim3(7500, 2), 256, 0, stream>>>(rows, cols, el0, er0, h0, b0, z0,
                                                     rows + (NN + 1), cols + NE, el1, er1, h1,
                                                     b1, z1);

  // ---- attention pooling -> beta -> Femb ----
  mfma_attn_kernel<<<dim3(NMT, 2), 256, 0, stream>>>(z0, z1, Wp1T, bp1, wp2, pbuf);
  attn_reduce_kernel<<<1, 256, 0, stream>>>(pbuf, wb);
  mfma_femb_kernel<<<NMT, 256, 0, stream>>>(z0, z1, wb, WfT, bf, Femb);

  // ---- GCN path ----
  mfma_gcn1_kernel<<<NMT, 256, 0, stream>>>(sen, Wg1T, rdo, gcnA);
  gcn_gather12_kernel<<<7500, 256, 0, stream>>>(rows_g, cols_g, gcnA, rdi, bg1, Wg2, rdo, gcnA2);
  gcn_gather2_kernel<<<7500, 256, 0, stream>>>(rows_g, cols_g, gcnA2, rdi, Femb, kptr, Zc, out);

  // ---- trace ----
  tr_kernel<<<NTRB, 256, 0, stream>>>(asrc, adst, kptr, Zc, out, trbuf);
  tr_reduce_kernel<<<1, 256, 0, stream>>>(trbuf, out);
}

// Round 9
// 553.194 us; speedup vs baseline: 8.9906x; 1.0412x over previous
//
#include <hip/hip_runtime.h>
#include <math.h>

#define NN 30000
#define NE 480000
#define NBLK 118   // ceil(30000/256)
#define NMT 235    // ceil(30000/128) MFMA row-tiles
#define NTRB 1875  // blocks in tr pass
#define CAPD 128   // LDS-cached attention weights per node

typedef unsigned short ushort_t;
typedef unsigned int uint_t;
typedef __attribute__((ext_vector_type(8))) short short8;
typedef __attribute__((ext_vector_type(4))) float f32x4;

__device__ __forceinline__ ushort_t f2bf(float x) {
  uint_t u = __float_as_uint(x);
  u = (u + 0x7FFF + ((u >> 16) & 1)) >> 16;
  return (ushort_t)u;
}
__device__ __forceinline__ float bf2f(ushort_t v) {
  return __uint_as_float(((uint_t)v) << 16);
}

// ---------------- fill ----------------
__global__ void zero4_kernel(float4* __restrict__ p, int n4) {
  int g = blockIdx.x * 256 + threadIdx.x;
  if (g < n4) p[g] = make_float4(0.f, 0.f, 0.f, 0.f);
}

__device__ __forceinline__ float wred(float v) {
#pragma unroll
  for (int off = 32; off > 0; off >>= 1) v += __shfl_xor(v, off);
  return v;
}

// ---------------- merged weight prep: transposes fp32->bf16 ----------------
// T2 = [Wp1^T ; Wf^T] packed contiguously (128 rows x 256)
__global__ void wt_all_kernel(const float* __restrict__ W0, const float* __restrict__ W1,
                              const float* __restrict__ W2, const float* __restrict__ W3,
                              const float* __restrict__ W4, ushort_t* __restrict__ T0,
                              ushort_t* __restrict__ T1, ushort_t* __restrict__ T2,
                              ushort_t* __restrict__ T3, ushort_t* __restrict__ T4) {
  int id = blockIdx.x * 256 + threadIdx.x;
  const float* W;
  ushort_t* T;
  int K, N, base;
  if (id < 65536) { W = W0; T = T0; K = 256; N = 256; base = 0; }
  else if (id < 98304) { W = W1; T = T1; K = 128; N = 256; base = 65536; }
  else if (id < 114688) { W = W2; T = T2; K = 256; N = 64; base = 98304; }
  else if (id < 131072) { W = W3; T = T3; K = 256; N = 64; base = 114688; }
  else if (id < 147456) { W = W4; T = T4; K = 256; N = 64; base = 131072; }
  else return;
  int l = id - base;
  int k = l / N, n = l - k * N;
  T[(size_t)n * K + k] = f2bf(W[l]);
}

// ================= MFMA cores =================
// 256 threads = 4 waves; wave w owns rows [w*32, w*32+32). LDS rows padded to 40 shorts.

// BN=64 core, fp32 A
__device__ __forceinline__ void mfma_core_f32(const float* __restrict__ A0,
                                              const ushort_t* __restrict__ BT, int K, int bm,
                                              short* __restrict__ As, short* __restrict__ Bs,
                                              f32x4 acc[2][4]) {
  int tid = threadIdx.x;
  int lane = tid & 63, w = tid >> 6;
  int q = lane >> 4, mr = lane & 15;
#pragma unroll 1
  for (int k0 = 0; k0 < K; k0 += 32) {
    {
      int r = tid >> 1, hf = tid & 1;
      int gr = bm + r;
      float4 f0 = make_float4(0.f, 0.f, 0.f, 0.f), f1 = f0, f2 = f0, f3 = f0;
      if (gr < NN) {
        const float4* pa = (const float4*)(A0 + (size_t)gr * K + k0 + hf * 16);
        f0 = pa[0]; f1 = pa[1]; f2 = pa[2]; f3 = pa[3];
      }
      short8 lo, hi;
      lo[0] = (short)f2bf(f0.x); lo[1] = (short)f2bf(f0.y);
      lo[2] = (short)f2bf(f0.z); lo[3] = (short)f2bf(f0.w);
      lo[4] = (short)f2bf(f1.x); lo[5] = (short)f2bf(f1.y);
      lo[6] = (short)f2bf(f1.z); lo[7] = (short)f2bf(f1.w);
      hi[0] = (short)f2bf(f2.x); hi[1] = (short)f2bf(f2.y);
      hi[2] = (short)f2bf(f2.z); hi[3] = (short)f2bf(f2.w);
      hi[4] = (short)f2bf(f3.x); hi[5] = (short)f2bf(f3.y);
      hi[6] = (short)f2bf(f3.z); hi[7] = (short)f2bf(f3.w);
      short* dst = As + r * 40 + hf * 16;
      *(short8*)(dst) = lo;
      *(short8*)(dst + 8) = hi;
    }
    {
      int n = tid >> 2, qk = tid & 3;
      short8 bv = *(const short8*)((const short*)BT + (size_t)n * K + k0 + qk * 8);
      *(short8*)(Bs + n * 40 + qk * 8) = bv;
    }
    __syncthreads();
    short8 a0 = *(short8*)(As + (w * 32 + mr) * 40 + q * 8);
    short8 a1 = *(short8*)(As + (w * 32 + 16 + mr) * 40 + q * 8);
#pragma unroll
    for (int j = 0; j < 4; ++j) {
      short8 b = *(short8*)(Bs + (j * 16 + mr) * 40 + q * 8);
      acc[0][j] = __builtin_amdgcn_mfma_f32_16x16x32_bf16(a0, b, acc[0][j], 0, 0, 0);
      acc[1][j] = __builtin_amdgcn_mfma_f32_16x16x32_bf16(a1, b, acc[1][j], 0, 0, 0);
    }
    __syncthreads();
  }
}

// BN=128 core, fp32 A
__device__ __forceinline__ void mfma_core2_f32(const float* __restrict__ A0,
                                               const ushort_t* __restrict__ BT, int K, int bm,
                                               short* __restrict__ As, short* __restrict__ Bs,
                                               f32x4 acc[2][8]) {
  int tid = threadIdx.x;
  int lane = tid & 63, w = tid >> 6;
  int q = lane >> 4, mr = lane & 15;
#pragma unroll 1
  for (int k0 = 0; k0 < K; k0 += 32) {
    {
      int r = tid >> 1, hf = tid & 1;
      int gr = bm + r;
      float4 f0 = make_float4(0.f, 0.f, 0.f, 0.f), f1 = f0, f2 = f0, f3 = f0;
      if (gr < NN) {
        const float4* pa = (const float4*)(A0 + (size_t)gr * K + k0 + hf * 16);
        f0 = pa[0]; f1 = pa[1]; f2 = pa[2]; f3 = pa[3];
      }
      short8 lo, hi;
      lo[0] = (short)f2bf(f0.x); lo[1] = (short)f2bf(f0.y);
      lo[2] = (short)f2bf(f0.z); lo[3] = (short)f2bf(f0.w);
      lo[4] = (short)f2bf(f1.x); lo[5] = (short)f2bf(f1.y);
      lo[6] = (short)f2bf(f1.z); lo[7] = (short)f2bf(f1.w);
      hi[0] = (short)f2bf(f2.x); hi[1] = (short)f2bf(f2.y);
      hi[2] = (short)f2bf(f2.z); hi[3] = (short)f2bf(f2.w);
      hi[4] = (short)f2bf(f3.x); hi[5] = (short)f2bf(f3.y);
      hi[6] = (short)f2bf(f3.z); hi[7] = (short)f2bf(f3.w);
      short* dst = As + r * 40 + hf * 16;
      *(short8*)(dst) = lo;
      *(short8*)(dst + 8) = hi;
    }
    {
      int n = tid >> 1, qk = tid & 1;
      const short* src = (const short*)BT + (size_t)n * K + k0 + qk * 16;
      short8 b0 = *(const short8*)src;
      short8 b1 = *(const short8*)(src + 8);
      short* d = Bs + n * 40 + qk * 16;
      *(short8*)d = b0;
      *(short8*)(d + 8) = b1;
    }
    __syncthreads();
    short8 a0 = *(short8*)(As + (w * 32 + mr) * 40 + q * 8);
    short8 a1 = *(short8*)(As + (w * 32 + 16 + mr) * 40 + q * 8);
#pragma unroll
    for (int j = 0; j < 8; ++j) {
      short8 b = *(short8*)(Bs + (j * 16 + mr) * 40 + q * 8);
      acc[0][j] = __builtin_amdgcn_mfma_f32_16x16x32_bf16(a0, b, acc[0][j], 0, 0, 0);
      acc[1][j] = __builtin_amdgcn_mfma_f32_16x16x32_bf16(a1, b, acc[1][j], 0, 0, 0);
    }
    __syncthreads();
  }
}

// BN=128 core, bf16 A (K fixed 256)
__device__ __forceinline__ void mfma_core2_bf(const ushort_t* __restrict__ A0,
                                              const ushort_t* __restrict__ BT, int bm,
                                              short* __restrict__ As, short* __restrict__ Bs,
                                              f32x4 acc[2][8]) {
  int tid = threadIdx.x;
  int lane = tid & 63, w = tid >> 6;
  int q = lane >> 4, mr = lane & 15;
#pragma unroll 1
  for (int k0 = 0; k0 < 256; k0 += 32) {
    {
      int r = tid >> 1, hf = tid & 1;
      int gr = bm + r;
      short8 v0 = {0, 0, 0, 0, 0, 0, 0, 0}, v1 = v0;
      if (gr < NN) {
        const short* p0 = (const short*)A0 + (size_t)gr * 256 + k0 + hf * 16;
        v0 = *(const short8*)p0;
        v1 = *(const short8*)(p0 + 8);
      }
      short* dst = As + r * 40 + hf * 16;
      *(short8*)(dst) = v0;
      *(short8*)(dst + 8) = v1;
    }
    {
      int n = tid >> 1, qk = tid & 1;
      const short* src = (const short*)BT + (size_t)n * 256 + k0 + qk * 16;
      short8 b0 = *(const short8*)src;
      short8 b1 = *(const short8*)(src + 8);
      short* d = Bs + n * 40 + qk * 16;
      *(short8*)d = b0;
      *(short8*)(d + 8) = b1;
    }
    __syncthreads();
    short8 a0 = *(short8*)(As + (w * 32 + mr) * 40 + q * 8);
    short8 a1 = *(short8*)(As + (w * 32 + 16 + mr) * 40 + q * 8);
#pragma unroll
    for (int j = 0; j < 8; ++j) {
      short8 b = *(short8*)(Bs + (j * 16 + mr) * 40 + q * 8);
      acc[0][j] = __builtin_amdgcn_mfma_f32_16x16x32_bf16(a0, b, acc[0][j], 0, 0, 0);
      acc[1][j] = __builtin_amdgcn_mfma_f32_16x16x32_bf16(a1, b, acc[1][j], 0, 0, 0);
    }
    __syncthreads();
  }
}

// ---- h = feat @ Wgat (2 heads/block) + fused el/er; grid (NMT, 2), blockIdx.y = head pair ----
__global__ __launch_bounds__(256) void mfma_h_kernel(const float* __restrict__ A,
                                                     const ushort_t* __restrict__ WT, int K,
                                                     ushort_t* __restrict__ H,
                                                     const float* __restrict__ al,
                                                     const float* __restrict__ ar,
                                                     float* __restrict__ el,
                                                     float* __restrict__ er) {
  __shared__ short As[128 * 40];
  __shared__ short Bs[128 * 40];
  int p = blockIdx.y;  // head pair: heads 2p, 2p+1
  int bm = blockIdx.x * 128;
  f32x4 acc[2][8];
#pragma unroll
  for (int i = 0; i < 2; ++i)
#pragma unroll
    for (int j = 0; j < 8; ++j) acc[i][j] = (f32x4){0.f, 0.f, 0.f, 0.f};
  mfma_core2_f32(A, WT + (size_t)p * 128 * K, K, bm, As, Bs, acc);
  int lane = threadIdx.x & 63, w = threadIdx.x >> 6;
  int q = lane >> 4, mr = lane & 15;
  float alv[8], arv[8];
#pragma unroll
  for (int j = 0; j < 8; ++j) {
    alv[j] = al[p * 128 + j * 16 + mr];
    arv[j] = ar[p * 128 + j * 16 + mr];
  }
#pragma unroll
  for (int i = 0; i < 2; ++i)
#pragma unroll
    for (int r = 0; r < 4; ++r) {
      int gr = bm + w * 32 + i * 16 + q * 4 + r;
      float pl0 = 0.f, pr0 = 0.f, pl1 = 0.f, pr1 = 0.f;
#pragma unroll
      for (int j = 0; j < 4; ++j) {
        pl0 = fmaf(acc[i][j][r], alv[j], pl0);
        pr0 = fmaf(acc[i][j][r], arv[j], pr0);
        pl1 = fmaf(acc[i][j + 4][r], alv[j + 4], pl1);
        pr1 = fmaf(acc[i][j + 4][r], arv[j + 4], pr1);
      }
#pragma unroll
      for (int m = 1; m < 16; m <<= 1) {
        pl0 += __shfl_xor(pl0, m);
        pr0 += __shfl_xor(pr0, m);
        pl1 += __shfl_xor(pl1, m);
        pr1 += __shfl_xor(pr1, m);
      }
      if (gr < NN) {
        if (mr == 0) {
          el[gr * 4 + 2 * p] = pl0;
          er[gr * 4 + 2 * p] = pr0;
          el[gr * 4 + 2 * p + 1] = pl1;
          er[gr * 4 + 2 * p + 1] = pr1;
        }
#pragma unroll
        for (int j = 0; j < 8; ++j)
          H[(size_t)gr * 256 + p * 128 + j * 16 + mr] = f2bf(acc[i][j][r]);
      }
    }
}

// ---- attn + Wf projection merged: B = [Wp1T ; WfT] (128 rows); grid (NMT, 2) ----
__global__ __launch_bounds__(256) void mfma_attnwf_kernel(
    const ushort_t* __restrict__ z0, const ushort_t* __restrict__ z1,
    const ushort_t* __restrict__ WpfT, const float* __restrict__ bp1,
    const float* __restrict__ wp2, float* __restrict__ pbuf, ushort_t* __restrict__ Y0,
    ushort_t* __restrict__ Y1) {
  __shared__ short As[128 * 40];
  __shared__ short Bs[128 * 40];
  __shared__ float wsum[4];
  const ushort_t* A = blockIdx.y ? z1 : z0;
  ushort_t* Y = blockIdx.y ? Y1 : Y0;
  int bm = blockIdx.x * 128;
  f32x4 acc[2][8];
#pragma unroll
  for (int i = 0; i < 2; ++i)
#pragma unroll
    for (int j = 0; j < 8; ++j) acc[i][j] = (f32x4){0.f, 0.f, 0.f, 0.f};
  mfma_core2_bf(A, WpfT, bm, As, Bs, acc);
  int lane = threadIdx.x & 63, w = threadIdx.x >> 6;
  int q = lane >> 4, mr = lane & 15;
  float local = 0.f;
#pragma unroll
  for (int j = 0; j < 4; ++j) {
    int col = j * 16 + mr;
    float bp = bp1[col], wp = wp2[col];
#pragma unroll
    for (int i = 0; i < 2; ++i)
#pragma unroll
      for (int r = 0; r < 4; ++r) {
        int gr = bm + w * 32 + i * 16 + q * 4 + r;
        if (gr < NN) local += tanhf(acc[i][j][r] + bp) * wp;
      }
  }
  local = wred(local);
  if (lane == 0) wsum[w] = local;
#pragma unroll
  for (int j = 4; j < 8; ++j) {
    int col = (j - 4) * 16 + mr;
#pragma unroll
    for (int i = 0; i < 2; ++i)
#pragma unroll
      for (int r = 0; r < 4; ++r) {
        int gr = bm + w * 32 + i * 16 + q * 4 + r;
        if (gr < NN) Y[(size_t)gr * 64 + col] = f2bf(acc[i][j][r]);
      }
  }
  __syncthreads();
  if (threadIdx.x == 0)
    pbuf[blockIdx.y * NMT + blockIdx.x] = wsum[0] + wsum[1] + wsum[2] + wsum[3];
}

// ---- gcn1: out = bf16((sen @ Wg1) * rdo), grid (NMT), BN=64 ----
__global__ __launch_bounds__(256) void mfma_gcn1_kernel(const float* __restrict__ X,
                                                        const ushort_t* __restrict__ WT,
                                                        const float* __restrict__ rdo,
                                                        ushort_t* __restrict__ out) {
  __shared__ short As[128 * 40];
  __shared__ short Bs[64 * 40];
  int bm = blockIdx.x * 128;
  f32x4 acc[2][4];
#pragma unroll
  for (int i = 0; i < 2; ++i)
#pragma unroll
    for (int j = 0; j < 4; ++j) acc[i][j] = (f32x4){0.f, 0.f, 0.f, 0.f};
  mfma_core_f32(X, WT, 256, bm, As, Bs, acc);
  int lane = threadIdx.x & 63, w = threadIdx.x >> 6;
  int q = lane >> 4, mr = lane & 15;
#pragma unroll
  for (int i = 0; i < 2; ++i)
#pragma unroll
    for (int r = 0; r < 4; ++r) {
      int gr = bm + w * 32 + i * 16 + q * 4 + r;
      if (gr < NN) {
        float sc = rdo[gr];
#pragma unroll
        for (int j = 0; j < 4; ++j) out[(size_t)gr * 64 + j * 16 + mr] = f2bf(acc[i][j][r] * sc);
      }
    }
}

// ---------------- CSR build ----------------
__global__ void hist_kernel(const int* __restrict__ d0, const int* __restrict__ d1,
                            const int* __restrict__ d2, const int* __restrict__ d3,
                            int* __restrict__ cnt) {
  int g = blockIdx.y;
  const int* d = g == 0 ? d0 : g == 1 ? d1 : g == 2 ? d2 : d3;
  int e = blockIdx.x * 256 + threadIdx.x;
  if (e < NE) atomicAdd(&cnt[g * NN + d[e]], 1);
}

__global__ __launch_bounds__(256) void scan_blocks_kernel(const int* __restrict__ cnt,
                                                          int* __restrict__ rows,
                                                          int* __restrict__ bsum) {
  __shared__ int sm[256];
  int g = blockIdx.y, t = threadIdx.x;
  int i = blockIdx.x * 256 + t;
  int v = (i < NN) ? cnt[g * NN + i] : 0;
  sm[t] = v;
  __syncthreads();
#pragma unroll
  for (int off = 1; off < 256; off <<= 1) {
    int tmp = (t >= off) ? sm[t - off] : 0;
    __syncthreads();
    sm[t] += tmp;
    __syncthreads();
  }
  if (i < NN) rows[g * (NN + 1) + i] = sm[t] - v;  // exclusive
  if (t == 255) bsum[g * NBLK + blockIdx.x] = sm[255];
}

__global__ __launch_bounds__(128) void scan_tops_kernel(int* __restrict__ bsum,
                                                        int* __restrict__ boff) {
  __shared__ int sm[128];
  int g = blockIdx.y, t = threadIdx.x;
  int v = (t < NBLK) ? bsum[g * NBLK + t] : 0;
  sm[t] = v;
  __syncthreads();
#pragma unroll
  for (int off = 1; off < 128; off <<= 1) {
    int tmp = (t >= off) ? sm[t - off] : 0;
    __syncthreads();
    sm[t] += tmp;
    __syncthreads();
  }
  if (t < NBLK) boff[g * NBLK + t] = sm[t] - v;  // exclusive
}

__global__ void add_off_kernel(int* __restrict__ rows, const int* __restrict__ boff) {
  int g = blockIdx.y, t = threadIdx.x;
  int i = blockIdx.x * 256 + t;
  if (i < NN) rows[g * (NN + 1) + i] += boff[g * NBLK + blockIdx.x];
  if (blockIdx.x == 0 && t == 0) rows[g * (NN + 1) + NN] = NE;
}

__global__ void scatter_kernel(const int* __restrict__ s0, const int* __restrict__ s1,
                               const int* __restrict__ s2, const int* __restrict__ d0,
                               const int* __restrict__ d1, const int* __restrict__ d2,
                               const int* __restrict__ rows, int* __restrict__ cnt2,
                               int* __restrict__ cols) {
  int g = blockIdx.y;
  const int* sp = g == 0 ? s0 : g == 1 ? s1 : s2;
  const int* dp = g == 0 ? d0 : g == 1 ? d1 : d2;
  int e = blockIdx.x * 256 + threadIdx.x;
  if (e >= NE) return;
  int d = dp[e];
  int pos = rows[g * (NN + 1) + d] + atomicAdd(&cnt2[g * NN + d], 1);
  cols[(size_t)g * NE + pos] = sp[e];
}

__global__ void rdeg2_kernel(const int* __restrict__ cnt_deg, float* __restrict__ rdo,
                             float* __restrict__ rdi, const int* __restrict__ rows_g) {
  int n = blockIdx.x * 256 + threadIdx.x;
  if (n >= NN) return;
  rdo[n] = rsqrtf(fmaxf((float)cnt_deg[n], 1.f));
  float di = (float)(rows_g[n + 1] - rows_g[n]);
  rdi[n] = rsqrtf(fmaxf(di, 1.f));
}

// ---------------- GAT per-node gather (both graphs), bf16 h, bf16 z out ----------------
__global__ __launch_bounds__(256) void gat_node_kernel(
    const int* __restrict__ rows0, const int* __restrict__ cols0, const float* __restrict__ el0,
    const float* __restrict__ er0, const ushort_t* __restrict__ h0,
    const float* __restrict__ bias0, ushort_t* __restrict__ zz0, const int* __restrict__ rows1,
    const int* __restrict__ cols1, const float* __restrict__ el1, const float* __restrict__ er1,
    const ushort_t* __restrict__ h1, const float* __restrict__ bias1,
    ushort_t* __restrict__ zz1) {
  __shared__ float aw[4][CAPD][4];  // 8 KB
  int g = blockIdx.y;
  const int* rows = g ? rows1 : rows0;
  const int* cols = g ? cols1 : cols0;
  const float* el = g ? el1 : el0;
  const float* er = g ? er1 : er0;
  const ushort_t* h = g ? h1 : h0;
  const float* bias = g ? bias1 : bias0;
  ushort_t* z = g ? zz1 : zz0;

  int lane = threadIdx.x & 63, w = threadIdx.x >> 6;
  int n = blockIdx.x * 4 + w;
  int r0 = rows[n], r1 = rows[n + 1];
  int deg = r1 - r0;
  float4 er4 = *(const float4*)&er[n * 4];
  float s0 = 0.f, s1 = 0.f, s2 = 0.f, s3 = 0.f;
  for (int j = lane; j < deg; j += 64) {
    int s = cols[r0 + j];
    float4 elv = *(const float4*)&el[s * 4];
    float v0 = elv.x + er4.x; v0 = v0 > 0.f ? v0 : 0.2f * v0;
    float v1 = elv.y + er4.y; v1 = v1 > 0.f ? v1 : 0.2f * v1;
    float v2 = elv.z + er4.z; v2 = v2 > 0.f ? v2 : 0.2f * v2;
    float v3 = elv.w + er4.w; v3 = v3 > 0.f ? v3 : 0.2f * v3;
    float e0 = __expf(v0), e1 = __expf(v1), e2 = __expf(v2), e3 = __expf(v3);
    s0 += e0; s1 += e1; s2 += e2; s3 += e3;
    if (j < CAPD) {
      aw[w][j][0] = e0; aw[w][j][1] = e1; aw[w][j][2] = e2; aw[w][j][3] = e3;
    }
  }
  s0 = wred(s0); s1 = wred(s1); s2 = wred(s2); s3 = wred(s3);
  __syncthreads();
  int hh = lane >> 4;
  float denom = hh == 0 ? s0 : hh == 1 ? s1 : hh == 2 ? s2 : s3;
  float myer = hh == 0 ? er4.x : hh == 1 ? er4.y : hh == 2 ? er4.z : er4.w;
  float invd = (deg > 0) ? 1.f / denom : 0.f;
  float4 acc = make_float4(0.f, 0.f, 0.f, 0.f);
  int jc = deg < CAPD ? deg : CAPD;
  int j = 0;
  for (; j + 4 <= jc; j += 4) {
    int sa = cols[r0 + j], sb = cols[r0 + j + 1], sc = cols[r0 + j + 2], sd = cols[r0 + j + 3];
    float aa = aw[w][j][hh], ab = aw[w][j + 1][hh], ac = aw[w][j + 2][hh], ad = aw[w][j + 3][hh];
    ushort4 ua = *(const ushort4*)&h[(size_t)sa * 256 + lane * 4];
    ushort4 ub = *(const ushort4*)&h[(size_t)sb * 256 + lane * 4];
    ushort4 uc = *(const ushort4*)&h[(size_t)sc * 256 + lane * 4];
    ushort4 ud = *(const ushort4*)&h[(size_t)sd * 256 + lane * 4];
    acc.x = fmaf(aa, bf2f(ua.x), acc.x); acc.y = fmaf(aa, bf2f(ua.y), acc.y);
    acc.z = fmaf(aa, bf2f(ua.z), acc.z); acc.w = fmaf(aa, bf2f(ua.w), acc.w);
    acc.x = fmaf(ab, bf2f(ub.x), acc.x); acc.y = fmaf(ab, bf2f(ub.y), acc.y);
    acc.z = fmaf(ab, bf2f(ub.z), acc.z); acc.w = fmaf(ab, bf2f(ub.w), acc.w);
    acc.x = fmaf(ac, bf2f(uc.x), acc.x); acc.y = fmaf(ac, bf2f(uc.y), acc.y);
    acc.z = fmaf(ac, bf2f(uc.z), acc.z); acc.w = fmaf(ac, bf2f(uc.w), acc.w);
    acc.x = fmaf(ad, bf2f(ud.x), acc.x); acc.y = fmaf(ad, bf2f(ud.y), acc.y);
    acc.z = fmaf(ad, bf2f(ud.z), acc.z); acc.w = fmaf(ad, bf2f(ud.w), acc.w);
  }
  for (; j < jc; ++j) {
    int s = cols[r0 + j];
    float a = aw[w][j][hh];
    ushort4 hu = *(const ushort4*)&h[(size_t)s * 256 + lane * 4];
    acc.x = fmaf(a, bf2f(hu.x), acc.x);
    acc.y = fmaf(a, bf2f(hu.y), acc.y);
    acc.z = fmaf(a, bf2f(hu.z), acc.z);
    acc.w = fmaf(a, bf2f(hu.w), acc.w);
  }
  for (; j < deg; ++j) {  // rare overflow fallback
    int s = cols[r0 + j];
    float v = el[s * 4 + hh] + myer;
    v = v > 0.f ? v : 0.2f * v;
    float a = __expf(v);
    ushort4 hu = *(const ushort4*)&h[(size_t)s * 256 + lane * 4];
    acc.x = fmaf(a, bf2f(hu.x), acc.x);
    acc.y = fmaf(a, bf2f(hu.y), acc.y);
    acc.z = fmaf(a, bf2f(hu.z), acc.z);
    acc.w = fmaf(a, bf2f(hu.w), acc.w);
  }
  float4 bv = *(const float4*)&bias[lane * 4];
  ushort4 o;
  o.x = f2bf(fminf(fmaxf(acc.x * invd + bv.x, 0.f), 6.f));
  o.y = f2bf(fminf(fmaxf(acc.y * invd + bv.y, 0.f), 6.f));
  o.z = f2bf(fminf(fmaxf(acc.z * invd + bv.z, 0.f), 6.f));
  o.w = f2bf(fminf(fmaxf(acc.w * invd + bv.w, 0.f), 6.f));
  *(ushort4*)&z[(size_t)n * 256 + lane * 4] = o;
}

// ---- reduce partials -> beta ----
__global__ __launch_bounds__(256) void attn_reduce_kernel(const float* __restrict__ pbuf,
                                                          float* __restrict__ wb) {
  __shared__ float sm[8];
  int t = threadIdx.x;
  float a0 = 0.f, a1 = 0.f;
  for (int i = t; i < NMT; i += 256) {
    a0 += pbuf[i];
    a1 += pbuf[NMT + i];
  }
  a0 = wred(a0);
  a1 = wred(a1);
  int lane = t & 63, w = t >> 6;
  if (lane == 0) { sm[w] = a0; sm[4 + w] = a1; }
  __syncthreads();
  if (t == 0) {
    float w0 = (sm[0] + sm[1] + sm[2] + sm[3]) * (1.0f / NN);
    float w1 = (sm[4] + sm[5] + sm[6] + sm[7]) * (1.0f / NN);
    float mx = fmaxf(w0, w1);
    float e0 = expf(w0 - mx), e1 = expf(w1 - mx);
    float inv = 1.f / (e0 + e1);
    wb[2] = e0 * inv;
    wb[3] = e1 * inv;
  }
}

// ---------------- GCN gather1 + gemm64 fused ----------------
__global__ __launch_bounds__(256) void gcn_gather12_kernel(
    const int* __restrict__ rows, const int* __restrict__ cols, const ushort_t* __restrict__ X,
    const float* __restrict__ rdi, const float* __restrict__ bg1, const float* __restrict__ Wg2,
    const float* __restrict__ rdo, ushort_t* __restrict__ out2) {
  int lane = threadIdx.x & 63, w = threadIdx.x >> 6;
  int n = blockIdx.x * 4 + w;
  if (n >= NN) return;
  int r0 = rows[n], r1 = rows[n + 1];
  float acc = 0.f;
  int j = r0;
  for (; j + 4 <= r1; j += 4) {
    int sa = cols[j], sb = cols[j + 1], sc = cols[j + 2], sd = cols[j + 3];
    acc += bf2f(X[(size_t)sa * 64 + lane]) + bf2f(X[(size_t)sb * 64 + lane]) +
           bf2f(X[(size_t)sc * 64 + lane]) + bf2f(X[(size_t)sd * 64 + lane]);
  }
  for (; j < r1; ++j) acc += bf2f(X[(size_t)cols[j] * 64 + lane]);
  float p = tanhf(acc * rdi[n] + bg1[lane]);
  float o = 0.f;
#pragma unroll
  for (int k = 0; k < 64; ++k) o = fmaf(__shfl(p, k), Wg2[k * 64 + lane], o);
  out2[(size_t)n * 64 + lane] = f2bf(o * rdo[n]);
}

// ---------------- GCN gather layer2: inline Femb from Y0/Y1/beta, Z write + compact Zk ----
__global__ __launch_bounds__(256) void gcn_gather2_kernel(
    const int* __restrict__ rows, const int* __restrict__ cols, const ushort_t* __restrict__ X,
    const float* __restrict__ rdi, const ushort_t* __restrict__ Y0,
    const ushort_t* __restrict__ Y1, const float* __restrict__ wb, const float* __restrict__ bf,
    const int* __restrict__ kptr, float* __restrict__ Zc, float* __restrict__ dout) {
  int lane = threadIdx.x & 63, w = threadIdx.x >> 6;
  int n = blockIdx.x * 4 + w;
  if (n >= NN) return;
  int r0 = rows[n], r1 = rows[n + 1];
  float acc = 0.f;
  int j = r0;
  for (; j + 4 <= r1; j += 4) {
    int sa = cols[j], sb = cols[j + 1], sc = cols[j + 2], sd = cols[j + 3];
    acc += bf2f(X[(size_t)sa * 64 + lane]) + bf2f(X[(size_t)sb * 64 + lane]) +
           bf2f(X[(size_t)sc * 64 + lane]) + bf2f(X[(size_t)sd * 64 + lane]);
  }
  for (; j < r1; ++j) acc += bf2f(X[(size_t)cols[j] * 64 + lane]);
  float femb = wb[2] * bf2f(Y0[(size_t)n * 64 + lane]) +
               wb[3] * bf2f(Y1[(size_t)n * 64 + lane]) + bf[lane];
  float zv = 0.5f * (femb + acc * rdi[n]);
  dout[1 + (size_t)n * 64 + lane] = zv;
  int k = *kptr;
  if (lane < k && lane < 16) Zc[(size_t)n * 16 + lane] = zv;
}

// ---------------- trace ----------------
__global__ __launch_bounds__(256) void tr_kernel(const int* __restrict__ asrc,
                                                 const int* __restrict__ adst,
                                                 const int* __restrict__ kptr,
                                                 const float* __restrict__ Zc,
                                                 const float* __restrict__ dout,
                                                 float* __restrict__ trbuf) {
  __shared__ float wsum[4];
  int e = blockIdx.x * 256 + threadIdx.x;
  int k = *kptr;
  float local = 0.f;
  if (e < NE) {
    int a = asrc[e], b = adst[e];
    if (k <= 16) {
      const float* Za = Zc + (size_t)a * 16;
      const float* Zb = Zc + (size_t)b * 16;
      for (int c = 0; c < k; ++c) {
        float d2 = Za[c] - Zb[c];
        local += d2 * d2;
      }
    } else {
      const float* Za = dout + 1 + (size_t)a * 64;
      const float* Zb = dout + 1 + (size_t)b * 64;
      for (int c = 0; c < k; ++c) {
        float d2 = Za[c] - Zb[c];
        local += d2 * d2;
      }
    }
  }
#pragma unroll
  for (int off = 32; off > 0; off >>= 1) local += __shfl_down(local, off);
  int lane = threadIdx.x & 63, w = threadIdx.x >> 6;
  if (lane == 0) wsum[w] = local;
  __syncthreads();
  if (threadIdx.x == 0) trbuf[blockIdx.x] = wsum[0] + wsum[1] + wsum[2] + wsum[3];
}

__global__ __launch_bounds__(256) void tr_reduce_kernel(const float* __restrict__ trbuf,
                                                        float* __restrict__ dout) {
  __shared__ float sm[4];
  int t = threadIdx.x;
  float a = 0.f;
  for (int i = t; i < NTRB; i += 256) a += trbuf[i];
  a = wred(a);
  int lane = t & 63, w = t >> 6;
  if (lane == 0) sm[w] = a;
  __syncthreads();
  if (t == 0) dout[0] = 0.5f * (sm[0] + sm[1] + sm[2] + sm[3]);
}

extern "C" void kernel_launch(void* const* d_in, const int* in_sizes, int n_in, void* d_out,
                              int out_size, void* d_ws, size_t ws_size, hipStream_t stream) {
  const float* feat0 = (const float*)d_in[0];
  const float* feat1 = (const float*)d_in[1];
  const float* sen = (const float*)d_in[2];
  const float* Wgat0 = (const float*)d_in[3];
  const float* al0 = (const float*)d_in[4];
  const float* ar0 = (const float*)d_in[5];
  const float* b0 = (const float*)d_in[6];
  const float* Wgat1 = (const float*)d_in[7];
  const float* al1 = (const float*)d_in[8];
  const float* ar1 = (const float*)d_in[9];
  const float* b1 = (const float*)d_in[10];
  const float* Wp1 = (const float*)d_in[11];
  const float* bp1 = (const float*)d_in[12];
  const float* wp2 = (const float*)d_in[13];
  const float* Wf = (const float*)d_in[14];
  const float* bf = (const float*)d_in[15];
  const float* Wg1 = (const float*)d_in[16];
  const float* bg1 = (const float*)d_in[17];
  const float* Wg2 = (const float*)d_in[18];
  const int* src0 = (const int*)d_in[19];
  const int* dst0 = (const int*)d_in[20];
  const int* src1 = (const int*)d_in[21];
  const int* dst1 = (const int*)d_in[22];
  const int* gsrc = (const int*)d_in[23];
  const int* gdst = (const int*)d_in[24];
  const int* asrc = (const int*)d_in[25];
  const int* adst = (const int*)d_in[26];
  const int* kptr = (const int*)d_in[27];
  float* out = (float*)d_out;
  float* ws = (float*)d_ws;

  // ---- workspace layout (float-element offsets) ----
  // ZERO region [0 .. 210004): wb(4) cnt(120000 int) cnt2(90000 int)
  float* wb = ws;                               // 4
  int* cnt = (int*)(ws + 4);                    // 4*30000
  int* cnt2 = (int*)(ws + 120004);              // 3*30000
  float* rdo = ws + 210004;                     // 30000
  float* rdi = ws + 240004;                     // 30000
  int* rows = (int*)(ws + 270004);              // 3*(NN+1)=90003
  int* bsum = (int*)(ws + 360008);              // 354
  int* boff = (int*)(ws + 360364);              // 354
  int* cols = (int*)(ws + 360720);              // 3*NE = 1,440,000
  float* el0 = ws + 1800720;                    // 120000
  float* er0 = ws + 1920720;                    // 120000
  float* el1 = ws + 2040720;                    // 120000
  float* er1 = ws + 2160720;                    // 120000
  float* pbuf = ws + 2280720;                   // 2*NMT = 470
  float* trbuf = ws + 2281192;                  // 1875
  ushort_t* h0 = (ushort_t*)(ws + 2283068);     // 7,680,000 bf16
  ushort_t* h1 = (ushort_t*)(ws + 6123068);     // 7,680,000 bf16
  ushort_t* z0 = (ushort_t*)(ws + 9963068);     // 7,680,000 bf16
  ushort_t* z1 = (ushort_t*)(ws + 13803068);    // 7,680,000 bf16
  ushort_t* gcnA = (ushort_t*)(ws + 17643068);  // 1,920,000 bf16
  ushort_t* gcnA2 = (ushort_t*)(ws + 18603068); // 1,920,000 bf16
  ushort_t* Y0 = (ushort_t*)(ws + 19563068);    // 1,920,000 bf16
  ushort_t* Y1 = (ushort_t*)(ws + 20523068);    // 1,920,000 bf16
  ushort_t* WT0 = (ushort_t*)(ws + 21483068);   // 65536 bf16
  ushort_t* WT1 = (ushort_t*)(ws + 21515836);   // 32768 bf16
  ushort_t* WpfT = (ushort_t*)(ws + 21532220);  // 32768 bf16 = [Wp1T;WfT]
  ushort_t* Wg1T = (ushort_t*)(ws + 21548604);  // 16384 bf16
  float* Zc = ws + 21556796;                    // 480,000 (NN x 16 compact Zk)

  int* rows_g = rows + 2 * (NN + 1);
  int* cols_g = cols + 2 * NE;
  int* cnt_deg = cnt + 3 * NN;

  zero4_kernel<<<206, 256, 0, stream>>>((float4*)ws, 52501);

  // ---- weight prep ----
  wt_all_kernel<<<576, 256, 0, stream>>>(Wgat0, Wgat1, Wp1, Wf, Wg1, WT0, WT1, WpfT,
                                         WpfT + 16384, Wg1T);

  // ---- CSR build for 3 graphs (by dst) + gsrc out-degree ----
  hist_kernel<<<dim3(1875, 4), 256, 0, stream>>>(dst0, dst1, gdst, gsrc, cnt);
  scan_blocks_kernel<<<dim3(NBLK, 3), 256, 0, stream>>>(cnt, rows, bsum);
  scan_tops_kernel<<<dim3(1, 3), 128, 0, stream>>>(bsum, boff);
  add_off_kernel<<<dim3(NBLK, 3), 256, 0, stream>>>(rows, boff);
  scatter_kernel<<<dim3(1875, 3), 256, 0, stream>>>(src0, src1, gsrc, dst0, dst1, gdst, rows,
                                                    cnt2, cols);
  rdeg2_kernel<<<NBLK, 256, 0, stream>>>(cnt_deg, rdo, rdi, rows_g);

  // ---- GAT dense projections (MFMA BN=128: 2 heads/block, fused el/er) ----
  mfma_h_kernel<<<dim3(NMT, 2), 256, 0, stream>>>(feat0, WT0, 256, h0, al0, ar0, el0, er0);
  mfma_h_kernel<<<dim3(NMT, 2), 256, 0, stream>>>(feat1, WT1, 128, h1, al1, ar1, el1, er1);

  // ---- GAT gather (both graphs) -> bf16 z ----
  gat_node_kernel<<<dim3(7500, 2), 256, 0, stream>>>(rows, cols, el0, er0, h0, b0, z0,
                                                     rows + (NN + 1), cols + NE, el1, er1, h1,
                                                     b1, z1);

  // ---- merged attn pooling + Wf projection; then beta ----
  mfma_attnwf_kernel<<<dim3(NMT, 2), 256, 0, stream>>>(z0, z1, WpfT, bp1, wp2, pbuf, Y0, Y1);
  attn_reduce_kernel<<<1, 256, 0, stream>>>(pbuf, wb);

  // ---- GCN path (gather2 forms Femb inline from Y0/Y1/beta) ----
  mfma_gcn1_kernel<<<NMT, 256, 0, stream>>>(sen, Wg1T, rdo, gcnA);
  gcn_gather12_kernel<<<7500, 256, 0, stream>>>(rows_g, cols_g, gcnA, rdi, bg1, Wg2, rdo, gcnA2);
  gcn_gather2_kernel<<<7500, 256, 0, stream>>>(rows_g, cols_g, gcnA2, rdi, Y0, Y1, wb, bf, kptr,
                                               Zc, out);

  // ---- trace ----
  tr_kernel<<<NTRB, 256, 0, stream>>>(asrc, adst, kptr, Zc, out, trbuf);
  tr_reduce_kernel<<<1, 256, 0, stream>>>(trbuf, out);
}

// Round 10
// 549.399 us; speedup vs baseline: 9.0527x; 1.0069x over previous
//
#include <hip/hip_runtime.h>
#include <math.h>

#define NN 30000
#define NE 480000
#define NBLK 118   // ceil(30000/256)
#define NMT 235    // ceil(30000/128) MFMA row-tiles
#define NTRB 1875  // blocks in tr pass
#define CAPD 128   // LDS-cached attention weights per node

typedef unsigned short ushort_t;
typedef unsigned int uint_t;
typedef __attribute__((ext_vector_type(8))) short short8;
typedef __attribute__((ext_vector_type(4))) float f32x4;

__device__ __forceinline__ ushort_t f2bf(float x) {
  uint_t u = __float_as_uint(x);
  u = (u + 0x7FFF + ((u >> 16) & 1)) >> 16;
  return (ushort_t)u;
}
__device__ __forceinline__ float bf2f(ushort_t v) {
  return __uint_as_float(((uint_t)v) << 16);
}

__device__ __forceinline__ float wred(float v) {
#pragma unroll
  for (int off = 32; off > 0; off >>= 1) v += __shfl_xor(v, off);
  return v;
}

// ---------------- prep: zero workspace head + 5 weight transposes (fp32->bf16) ----------------
// zero items: 52501 float4; wt items: 147456
__global__ void prep_kernel(float4* __restrict__ zp, const float* __restrict__ W0,
                            const float* __restrict__ W1, const float* __restrict__ W2,
                            const float* __restrict__ W3, const float* __restrict__ W4,
                            ushort_t* __restrict__ T0, ushort_t* __restrict__ T1,
                            ushort_t* __restrict__ T2, ushort_t* __restrict__ T3,
                            ushort_t* __restrict__ T4) {
  int id = blockIdx.x * 256 + threadIdx.x;
  if (id < 52501) {
    zp[id] = make_float4(0.f, 0.f, 0.f, 0.f);
    return;
  }
  int wid = id - 52501;
  const float* W;
  ushort_t* T;
  int K, N, base;
  if (wid < 65536) { W = W0; T = T0; K = 256; N = 256; base = 0; }
  else if (wid < 98304) { W = W1; T = T1; K = 128; N = 256; base = 65536; }
  else if (wid < 114688) { W = W2; T = T2; K = 256; N = 64; base = 98304; }
  else if (wid < 131072) { W = W3; T = T3; K = 256; N = 64; base = 114688; }
  else if (wid < 147456) { W = W4; T = T4; K = 256; N = 64; base = 131072; }
  else return;
  int l = wid - base;
  int k = l / N, n = l - k * N;
  T[(size_t)n * K + k] = f2bf(W[l]);
}

// ================= MFMA cores =================
// 256 threads = 4 waves; wave w owns rows [w*32, w*32+32). LDS rows padded to 40 shorts.

// BN=64 core, fp32 A
__device__ __forceinline__ void mfma_core_f32(const float* __restrict__ A0,
                                              const ushort_t* __restrict__ BT, int K, int bm,
                                              short* __restrict__ As, short* __restrict__ Bs,
                                              f32x4 acc[2][4]) {
  int tid = threadIdx.x;
  int lane = tid & 63, w = tid >> 6;
  int q = lane >> 4, mr = lane & 15;
#pragma unroll 1
  for (int k0 = 0; k0 < K; k0 += 32) {
    {
      int r = tid >> 1, hf = tid & 1;
      int gr = bm + r;
      float4 f0 = make_float4(0.f, 0.f, 0.f, 0.f), f1 = f0, f2 = f0, f3 = f0;
      if (gr < NN) {
        const float4* pa = (const float4*)(A0 + (size_t)gr * K + k0 + hf * 16);
        f0 = pa[0]; f1 = pa[1]; f2 = pa[2]; f3 = pa[3];
      }
      short8 lo, hi;
      lo[0] = (short)f2bf(f0.x); lo[1] = (short)f2bf(f0.y);
      lo[2] = (short)f2bf(f0.z); lo[3] = (short)f2bf(f0.w);
      lo[4] = (short)f2bf(f1.x); lo[5] = (short)f2bf(f1.y);
      lo[6] = (short)f2bf(f1.z); lo[7] = (short)f2bf(f1.w);
      hi[0] = (short)f2bf(f2.x); hi[1] = (short)f2bf(f2.y);
      hi[2] = (short)f2bf(f2.z); hi[3] = (short)f2bf(f2.w);
      hi[4] = (short)f2bf(f3.x); hi[5] = (short)f2bf(f3.y);
      hi[6] = (short)f2bf(f3.z); hi[7] = (short)f2bf(f3.w);
      short* dst = As + r * 40 + hf * 16;
      *(short8*)(dst) = lo;
      *(short8*)(dst + 8) = hi;
    }
    {
      int n = tid >> 2, qk = tid & 3;
      short8 bv = *(const short8*)((const short*)BT + (size_t)n * K + k0 + qk * 8);
      *(short8*)(Bs + n * 40 + qk * 8) = bv;
    }
    __syncthreads();
    short8 a0 = *(short8*)(As + (w * 32 + mr) * 40 + q * 8);
    short8 a1 = *(short8*)(As + (w * 32 + 16 + mr) * 40 + q * 8);
#pragma unroll
    for (int j = 0; j < 4; ++j) {
      short8 b = *(short8*)(Bs + (j * 16 + mr) * 40 + q * 8);
      acc[0][j] = __builtin_amdgcn_mfma_f32_16x16x32_bf16(a0, b, acc[0][j], 0, 0, 0);
      acc[1][j] = __builtin_amdgcn_mfma_f32_16x16x32_bf16(a1, b, acc[1][j], 0, 0, 0);
    }
    __syncthreads();
  }
}

// BN=128 core, fp32 A
__device__ __forceinline__ void mfma_core2_f32(const float* __restrict__ A0,
                                               const ushort_t* __restrict__ BT, int K, int bm,
                                               short* __restrict__ As, short* __restrict__ Bs,
                                               f32x4 acc[2][8]) {
  int tid = threadIdx.x;
  int lane = tid & 63, w = tid >> 6;
  int q = lane >> 4, mr = lane & 15;
#pragma unroll 1
  for (int k0 = 0; k0 < K; k0 += 32) {
    {
      int r = tid >> 1, hf = tid & 1;
      int gr = bm + r;
      float4 f0 = make_float4(0.f, 0.f, 0.f, 0.f), f1 = f0, f2 = f0, f3 = f0;
      if (gr < NN) {
        const float4* pa = (const float4*)(A0 + (size_t)gr * K + k0 + hf * 16);
        f0 = pa[0]; f1 = pa[1]; f2 = pa[2]; f3 = pa[3];
      }
      short8 lo, hi;
      lo[0] = (short)f2bf(f0.x); lo[1] = (short)f2bf(f0.y);
      lo[2] = (short)f2bf(f0.z); lo[3] = (short)f2bf(f0.w);
      lo[4] = (short)f2bf(f1.x); lo[5] = (short)f2bf(f1.y);
      lo[6] = (short)f2bf(f1.z); lo[7] = (short)f2bf(f1.w);
      hi[0] = (short)f2bf(f2.x); hi[1] = (short)f2bf(f2.y);
      hi[2] = (short)f2bf(f2.z); hi[3] = (short)f2bf(f2.w);
      hi[4] = (short)f2bf(f3.x); hi[5] = (short)f2bf(f3.y);
      hi[6] = (short)f2bf(f3.z); hi[7] = (short)f2bf(f3.w);
      short* dst = As + r * 40 + hf * 16;
      *(short8*)(dst) = lo;
      *(short8*)(dst + 8) = hi;
    }
    {
      int n = tid >> 1, qk = tid & 1;
      const short* src = (const short*)BT + (size_t)n * K + k0 + qk * 16;
      short8 b0 = *(const short8*)src;
      short8 b1 = *(const short8*)(src + 8);
      short* d = Bs + n * 40 + qk * 16;
      *(short8*)d = b0;
      *(short8*)(d + 8) = b1;
    }
    __syncthreads();
    short8 a0 = *(short8*)(As + (w * 32 + mr) * 40 + q * 8);
    short8 a1 = *(short8*)(As + (w * 32 + 16 + mr) * 40 + q * 8);
#pragma unroll
    for (int j = 0; j < 8; ++j) {
      short8 b = *(short8*)(Bs + (j * 16 + mr) * 40 + q * 8);
      acc[0][j] = __builtin_amdgcn_mfma_f32_16x16x32_bf16(a0, b, acc[0][j], 0, 0, 0);
      acc[1][j] = __builtin_amdgcn_mfma_f32_16x16x32_bf16(a1, b, acc[1][j], 0, 0, 0);
    }
    __syncthreads();
  }
}

// BN=128 core, bf16 A (K fixed 256)
__device__ __forceinline__ void mfma_core2_bf(const ushort_t* __restrict__ A0,
                                              const ushort_t* __restrict__ BT, int bm,
                                              short* __restrict__ As, short* __restrict__ Bs,
                                              f32x4 acc[2][8]) {
  int tid = threadIdx.x;
  int lane = tid & 63, w = tid >> 6;
  int q = lane >> 4, mr = lane & 15;
#pragma unroll 1
  for (int k0 = 0; k0 < 256; k0 += 32) {
    {
      int r = tid >> 1, hf = tid & 1;
      int gr = bm + r;
      short8 v0 = {0, 0, 0, 0, 0, 0, 0, 0}, v1 = v0;
      if (gr < NN) {
        const short* p0 = (const short*)A0 + (size_t)gr * 256 + k0 + hf * 16;
        v0 = *(const short8*)p0;
        v1 = *(const short8*)(p0 + 8);
      }
      short* dst = As + r * 40 + hf * 16;
      *(short8*)(dst) = v0;
      *(short8*)(dst + 8) = v1;
    }
    {
      int n = tid >> 1, qk = tid & 1;
      const short* src = (const short*)BT + (size_t)n * 256 + k0 + qk * 16;
      short8 b0 = *(const short8*)src;
      short8 b1 = *(const short8*)(src + 8);
      short* d = Bs + n * 40 + qk * 16;
      *(short8*)d = b0;
      *(short8*)(d + 8) = b1;
    }
    __syncthreads();
    short8 a0 = *(short8*)(As + (w * 32 + mr) * 40 + q * 8);
    short8 a1 = *(short8*)(As + (w * 32 + 16 + mr) * 40 + q * 8);
#pragma unroll
    for (int j = 0; j < 8; ++j) {
      short8 b = *(short8*)(Bs + (j * 16 + mr) * 40 + q * 8);
      acc[0][j] = __builtin_amdgcn_mfma_f32_16x16x32_bf16(a0, b, acc[0][j], 0, 0, 0);
      acc[1][j] = __builtin_amdgcn_mfma_f32_16x16x32_bf16(a1, b, acc[1][j], 0, 0, 0);
    }
    __syncthreads();
  }
}

// ---- merged GEMM phase: grid (NMT, 5)
// y=0,1: h0 head-pairs; y=2,3: h1 head-pairs; y=4: gcn1
__global__ __launch_bounds__(256) void mfma_all_kernel(
    const float* __restrict__ feat0, const float* __restrict__ feat1,
    const float* __restrict__ sen, const ushort_t* __restrict__ WT0,
    const ushort_t* __restrict__ WT1, const ushort_t* __restrict__ Wg1T,
    ushort_t* __restrict__ h0, ushort_t* __restrict__ h1, ushort_t* __restrict__ gcnA,
    const float* __restrict__ al0, const float* __restrict__ ar0, float* __restrict__ el0,
    float* __restrict__ er0, const float* __restrict__ al1, const float* __restrict__ ar1,
    float* __restrict__ el1, float* __restrict__ er1, const float* __restrict__ rdo) {
  __shared__ short As[128 * 40];
  __shared__ short Bs[128 * 40];
  int y = blockIdx.y;
  int bm = blockIdx.x * 128;
  int lane = threadIdx.x & 63, w = threadIdx.x >> 6;
  int q = lane >> 4, mr = lane & 15;
  if (y < 4) {
    int gsel = y >> 1, p = y & 1;
    const float* A = gsel ? feat1 : feat0;
    int K = gsel ? 128 : 256;
    const ushort_t* WT = gsel ? WT1 : WT0;
    ushort_t* H = gsel ? h1 : h0;
    const float* al = gsel ? al1 : al0;
    const float* ar = gsel ? ar1 : ar0;
    float* el = gsel ? el1 : el0;
    float* er = gsel ? er1 : er0;
    f32x4 acc[2][8];
#pragma unroll
    for (int i = 0; i < 2; ++i)
#pragma unroll
      for (int j = 0; j < 8; ++j) acc[i][j] = (f32x4){0.f, 0.f, 0.f, 0.f};
    mfma_core2_f32(A, WT + (size_t)p * 128 * K, K, bm, As, Bs, acc);
    float alv[8], arv[8];
#pragma unroll
    for (int j = 0; j < 8; ++j) {
      alv[j] = al[p * 128 + j * 16 + mr];
      arv[j] = ar[p * 128 + j * 16 + mr];
    }
#pragma unroll
    for (int i = 0; i < 2; ++i)
#pragma unroll
      for (int r = 0; r < 4; ++r) {
        int gr = bm + w * 32 + i * 16 + q * 4 + r;
        float pl0 = 0.f, pr0 = 0.f, pl1 = 0.f, pr1 = 0.f;
#pragma unroll
        for (int j = 0; j < 4; ++j) {
          pl0 = fmaf(acc[i][j][r], alv[j], pl0);
          pr0 = fmaf(acc[i][j][r], arv[j], pr0);
          pl1 = fmaf(acc[i][j + 4][r], alv[j + 4], pl1);
          pr1 = fmaf(acc[i][j + 4][r], arv[j + 4], pr1);
        }
#pragma unroll
        for (int m = 1; m < 16; m <<= 1) {
          pl0 += __shfl_xor(pl0, m);
          pr0 += __shfl_xor(pr0, m);
          pl1 += __shfl_xor(pl1, m);
          pr1 += __shfl_xor(pr1, m);
        }
        if (gr < NN) {
          if (mr == 0) {
            el[gr * 4 + 2 * p] = pl0;
            er[gr * 4 + 2 * p] = pr0;
            el[gr * 4 + 2 * p + 1] = pl1;
            er[gr * 4 + 2 * p + 1] = pr1;
          }
#pragma unroll
          for (int j = 0; j < 8; ++j)
            H[(size_t)gr * 256 + p * 128 + j * 16 + mr] = f2bf(acc[i][j][r]);
        }
      }
  } else {
    f32x4 acc[2][4];
#pragma unroll
    for (int i = 0; i < 2; ++i)
#pragma unroll
      for (int j = 0; j < 4; ++j) acc[i][j] = (f32x4){0.f, 0.f, 0.f, 0.f};
    mfma_core_f32(sen, Wg1T, 256, bm, As, Bs, acc);
#pragma unroll
    for (int i = 0; i < 2; ++i)
#pragma unroll
      for (int r = 0; r < 4; ++r) {
        int gr = bm + w * 32 + i * 16 + q * 4 + r;
        if (gr < NN) {
          float sc = rdo[gr];
#pragma unroll
          for (int j = 0; j < 4; ++j)
            gcnA[(size_t)gr * 64 + j * 16 + mr] = f2bf(acc[i][j][r] * sc);
        }
      }
  }
}

// ---- attn + Wf projection merged: B = [Wp1T ; WfT] (128 rows); grid (NMT, 2) ----
__global__ __launch_bounds__(256) void mfma_attnwf_kernel(
    const ushort_t* __restrict__ z0, const ushort_t* __restrict__ z1,
    const ushort_t* __restrict__ WpfT, const float* __restrict__ bp1,
    const float* __restrict__ wp2, float* __restrict__ pbuf, ushort_t* __restrict__ Y0,
    ushort_t* __restrict__ Y1) {
  __shared__ short As[128 * 40];
  __shared__ short Bs[128 * 40];
  __shared__ float wsum[4];
  const ushort_t* A = blockIdx.y ? z1 : z0;
  ushort_t* Y = blockIdx.y ? Y1 : Y0;
  int bm = blockIdx.x * 128;
  f32x4 acc[2][8];
#pragma unroll
  for (int i = 0; i < 2; ++i)
#pragma unroll
    for (int j = 0; j < 8; ++j) acc[i][j] = (f32x4){0.f, 0.f, 0.f, 0.f};
  mfma_core2_bf(A, WpfT, bm, As, Bs, acc);
  int lane = threadIdx.x & 63, w = threadIdx.x >> 6;
  int q = lane >> 4, mr = lane & 15;
  float local = 0.f;
#pragma unroll
  for (int j = 0; j < 4; ++j) {
    int col = j * 16 + mr;
    float bp = bp1[col], wp = wp2[col];
#pragma unroll
    for (int i = 0; i < 2; ++i)
#pragma unroll
      for (int r = 0; r < 4; ++r) {
        int gr = bm + w * 32 + i * 16 + q * 4 + r;
        if (gr < NN) local += tanhf(acc[i][j][r] + bp) * wp;
      }
  }
  local = wred(local);
  if (lane == 0) wsum[w] = local;
#pragma unroll
  for (int j = 4; j < 8; ++j) {
    int col = (j - 4) * 16 + mr;
#pragma unroll
    for (int i = 0; i < 2; ++i)
#pragma unroll
      for (int r = 0; r < 4; ++r) {
        int gr = bm + w * 32 + i * 16 + q * 4 + r;
        if (gr < NN) Y[(size_t)gr * 64 + col] = f2bf(acc[i][j][r]);
      }
  }
  __syncthreads();
  if (threadIdx.x == 0)
    pbuf[blockIdx.y * NMT + blockIdx.x] = wsum[0] + wsum[1] + wsum[2] + wsum[3];
}

// ---------------- CSR build ----------------
__global__ void hist_kernel(const int* __restrict__ d0, const int* __restrict__ d1,
                            const int* __restrict__ d2, const int* __restrict__ d3,
                            int* __restrict__ cnt) {
  int g = blockIdx.y;
  const int* d = g == 0 ? d0 : g == 1 ? d1 : g == 2 ? d2 : d3;
  int e = blockIdx.x * 256 + threadIdx.x;
  if (e < NE) atomicAdd(&cnt[g * NN + d[e]], 1);
}

__global__ __launch_bounds__(256) void scan_blocks_kernel(const int* __restrict__ cnt,
                                                          int* __restrict__ rows,
                                                          int* __restrict__ bsum) {
  __shared__ int sm[256];
  int g = blockIdx.y, t = threadIdx.x;
  int i = blockIdx.x * 256 + t;
  int v = (i < NN) ? cnt[g * NN + i] : 0;
  sm[t] = v;
  __syncthreads();
#pragma unroll
  for (int off = 1; off < 256; off <<= 1) {
    int tmp = (t >= off) ? sm[t - off] : 0;
    __syncthreads();
    sm[t] += tmp;
    __syncthreads();
  }
  if (i < NN) rows[g * (NN + 1) + i] = sm[t] - v;  // exclusive
  if (t == 255) bsum[g * NBLK + blockIdx.x] = sm[255];
}

__global__ __launch_bounds__(128) void scan_tops_kernel(int* __restrict__ bsum,
                                                        int* __restrict__ boff) {
  __shared__ int sm[128];
  int g = blockIdx.y, t = threadIdx.x;
  int v = (t < NBLK) ? bsum[g * NBLK + t] : 0;
  sm[t] = v;
  __syncthreads();
#pragma unroll
  for (int off = 1; off < 128; off <<= 1) {
    int tmp = (t >= off) ? sm[t - off] : 0;
    __syncthreads();
    sm[t] += tmp;
    __syncthreads();
  }
  if (t < NBLK) boff[g * NBLK + t] = sm[t] - v;  // exclusive
}

__global__ void add_off_kernel(int* __restrict__ rows, const int* __restrict__ boff) {
  int g = blockIdx.y, t = threadIdx.x;
  int i = blockIdx.x * 256 + t;
  if (i < NN) rows[g * (NN + 1) + i] += boff[g * NBLK + blockIdx.x];
  if (blockIdx.x == 0 && t == 0) rows[g * (NN + 1) + NN] = NE;
}

// scatter (y=0..2) + rdeg (y=3)
__global__ void scatter_kernel(const int* __restrict__ s0, const int* __restrict__ s1,
                               const int* __restrict__ s2, const int* __restrict__ d0,
                               const int* __restrict__ d1, const int* __restrict__ d2,
                               const int* __restrict__ rows, int* __restrict__ cnt2,
                               int* __restrict__ cols, const int* __restrict__ cnt_deg,
                               float* __restrict__ rdo, float* __restrict__ rdi,
                               const int* __restrict__ rows_g) {
  int g = blockIdx.y;
  if (g == 3) {
    int n = blockIdx.x * 256 + threadIdx.x;
    if (n < NN) {
      rdo[n] = rsqrtf(fmaxf((float)cnt_deg[n], 1.f));
      float di = (float)(rows_g[n + 1] - rows_g[n]);
      rdi[n] = rsqrtf(fmaxf(di, 1.f));
    }
    return;
  }
  const int* sp = g == 0 ? s0 : g == 1 ? s1 : s2;
  const int* dp = g == 0 ? d0 : g == 1 ? d1 : d2;
  int e = blockIdx.x * 256 + threadIdx.x;
  if (e >= NE) return;
  int d = dp[e];
  int pos = rows[g * (NN + 1) + d] + atomicAdd(&cnt2[g * NN + d], 1);
  cols[(size_t)g * NE + pos] = sp[e];
}

// ---------------- GAT per-node gather (both graphs), bf16 h, bf16 z out ----------------
__global__ __launch_bounds__(256) void gat_node_kernel(
    const int* __restrict__ rows0, const int* __restrict__ cols0, const float* __restrict__ el0,
    const float* __restrict__ er0, const ushort_t* __restrict__ h0,
    const float* __restrict__ bias0, ushort_t* __restrict__ zz0, const int* __restrict__ rows1,
    const int* __restrict__ cols1, const float* __restrict__ el1, const float* __restrict__ er1,
    const ushort_t* __restrict__ h1, const float* __restrict__ bias1,
    ushort_t* __restrict__ zz1) {
  __shared__ float aw[4][CAPD][4];  // 8 KB
  int g = blockIdx.y;
  const int* rows = g ? rows1 : rows0;
  const int* cols = g ? cols1 : cols0;
  const float* el = g ? el1 : el0;
  const float* er = g ? er1 : er0;
  const ushort_t* h = g ? h1 : h0;
  const float* bias = g ? bias1 : bias0;
  ushort_t* z = g ? zz1 : zz0;

  int lane = threadIdx.x & 63, w = threadIdx.x >> 6;
  int n = blockIdx.x * 4 + w;
  int r0 = rows[n], r1 = rows[n + 1];
  int deg = r1 - r0;
  float4 er4 = *(const float4*)&er[n * 4];
  float s0 = 0.f, s1 = 0.f, s2 = 0.f, s3 = 0.f;
  for (int j = lane; j < deg; j += 64) {
    int s = cols[r0 + j];
    float4 elv = *(const float4*)&el[s * 4];
    float v0 = elv.x + er4.x; v0 = v0 > 0.f ? v0 : 0.2f * v0;
    float v1 = elv.y + er4.y; v1 = v1 > 0.f ? v1 : 0.2f * v1;
    float v2 = elv.z + er4.z; v2 = v2 > 0.f ? v2 : 0.2f * v2;
    float v3 = elv.w + er4.w; v3 = v3 > 0.f ? v3 : 0.2f * v3;
    float e0 = __expf(v0), e1 = __expf(v1), e2 = __expf(v2), e3 = __expf(v3);
    s0 += e0; s1 += e1; s2 += e2; s3 += e3;
    if (j < CAPD) {
      aw[w][j][0] = e0; aw[w][j][1] = e1; aw[w][j][2] = e2; aw[w][j][3] = e3;
    }
  }
  s0 = wred(s0); s1 = wred(s1); s2 = wred(s2); s3 = wred(s3);
  __syncthreads();
  int hh = lane >> 4;
  float denom = hh == 0 ? s0 : hh == 1 ? s1 : hh == 2 ? s2 : s3;
  float myer = hh == 0 ? er4.x : hh == 1 ? er4.y : hh == 2 ? er4.z : er4.w;
  float invd = (deg > 0) ? 1.f / denom : 0.f;
  float4 acc = make_float4(0.f, 0.f, 0.f, 0.f);
  int jc = deg < CAPD ? deg : CAPD;
  int j = 0;
  // 8-deep unrolled gather: 8 outstanding 512B requests per wave
  for (; j + 8 <= jc; j += 8) {
    int si[8];
    float ai[8];
    ushort4 ui[8];
#pragma unroll
    for (int t = 0; t < 8; ++t) {
      si[t] = cols[r0 + j + t];
      ai[t] = aw[w][j + t][hh];
    }
#pragma unroll
    for (int t = 0; t < 8; ++t) ui[t] = *(const ushort4*)&h[(size_t)si[t] * 256 + lane * 4];
#pragma unroll
    for (int t = 0; t < 8; ++t) {
      acc.x = fmaf(ai[t], bf2f(ui[t].x), acc.x);
      acc.y = fmaf(ai[t], bf2f(ui[t].y), acc.y);
      acc.z = fmaf(ai[t], bf2f(ui[t].z), acc.z);
      acc.w = fmaf(ai[t], bf2f(ui[t].w), acc.w);
    }
  }
  for (; j + 4 <= jc; j += 4) {
    int sa = cols[r0 + j], sb = cols[r0 + j + 1], sc = cols[r0 + j + 2], sd = cols[r0 + j + 3];
    float aa = aw[w][j][hh], ab = aw[w][j + 1][hh], ac = aw[w][j + 2][hh], ad = aw[w][j + 3][hh];
    ushort4 ua = *(const ushort4*)&h[(size_t)sa * 256 + lane * 4];
    ushort4 ub = *(const ushort4*)&h[(size_t)sb * 256 + lane * 4];
    ushort4 uc = *(const ushort4*)&h[(size_t)sc * 256 + lane * 4];
    ushort4 ud = *(const ushort4*)&h[(size_t)sd * 256 + lane * 4];
    acc.x = fmaf(aa, bf2f(ua.x), acc.x); acc.y = fmaf(aa, bf2f(ua.y), acc.y);
    acc.z = fmaf(aa, bf2f(ua.z), acc.z); acc.w = fmaf(aa, bf2f(ua.w), acc.w);
    acc.x = fmaf(ab, bf2f(ub.x), acc.x); acc.y = fmaf(ab, bf2f(ub.y), acc.y);
    acc.z = fmaf(ab, bf2f(ub.z), acc.z); acc.w = fmaf(ab, bf2f(ub.w), acc.w);
    acc.x = fmaf(ac, bf2f(uc.x), acc.x); acc.y = fmaf(ac, bf2f(uc.y), acc.y);
    acc.z = fmaf(ac, bf2f(uc.z), acc.z); acc.w = fmaf(ac, bf2f(uc.w), acc.w);
    acc.x = fmaf(ad, bf2f(ud.x), acc.x); acc.y = fmaf(ad, bf2f(ud.y), acc.y);
    acc.z = fmaf(ad, bf2f(ud.z), acc.z); acc.w = fmaf(ad, bf2f(ud.w), acc.w);
  }
  for (; j < jc; ++j) {
    int s = cols[r0 + j];
    float a = aw[w][j][hh];
    ushort4 hu = *(const ushort4*)&h[(size_t)s * 256 + lane * 4];
    acc.x = fmaf(a, bf2f(hu.x), acc.x);
    acc.y = fmaf(a, bf2f(hu.y), acc.y);
    acc.z = fmaf(a, bf2f(hu.z), acc.z);
    acc.w = fmaf(a, bf2f(hu.w), acc.w);
  }
  for (; j < deg; ++j) {  // rare overflow fallback
    int s = cols[r0 + j];
    float v = el[s * 4 + hh] + myer;
    v = v > 0.f ? v : 0.2f * v;
    float a = __expf(v);
    ushort4 hu = *(const ushort4*)&h[(size_t)s * 256 + lane * 4];
    acc.x = fmaf(a, bf2f(hu.x), acc.x);
    acc.y = fmaf(a, bf2f(hu.y), acc.y);
    acc.z = fmaf(a, bf2f(hu.z), acc.z);
    acc.w = fmaf(a, bf2f(hu.w), acc.w);
  }
  float4 bv = *(const float4*)&bias[lane * 4];
  ushort4 o;
  o.x = f2bf(fminf(fmaxf(acc.x * invd + bv.x, 0.f), 6.f));
  o.y = f2bf(fminf(fmaxf(acc.y * invd + bv.y, 0.f), 6.f));
  o.z = f2bf(fminf(fmaxf(acc.z * invd + bv.z, 0.f), 6.f));
  o.w = f2bf(fminf(fmaxf(acc.w * invd + bv.w, 0.f), 6.f));
  *(ushort4*)&z[(size_t)n * 256 + lane * 4] = o;
}

// ---------------- GCN gather1 + gemm64 fused; block 0 also computes beta ----------------
__global__ __launch_bounds__(256) void gcn_gather12_kernel(
    const int* __restrict__ rows, const int* __restrict__ cols, const ushort_t* __restrict__ X,
    const float* __restrict__ rdi, const float* __restrict__ bg1, const float* __restrict__ Wg2,
    const float* __restrict__ rdo, ushort_t* __restrict__ out2, const float* __restrict__ pbuf,
    float* __restrict__ wb) {
  int lane = threadIdx.x & 63, w = threadIdx.x >> 6;
  // ---- folded attn_reduce (block 0 only; ~470 reads) ----
  if (blockIdx.x == 0) {
    __shared__ float sm[8];
    int t = threadIdx.x;
    float a0 = 0.f, a1 = 0.f;
    for (int i = t; i < NMT; i += 256) {
      a0 += pbuf[i];
      a1 += pbuf[NMT + i];
    }
    a0 = wred(a0);
    a1 = wred(a1);
    if (lane == 0) { sm[w] = a0; sm[4 + w] = a1; }
    __syncthreads();
    if (t == 0) {
      float w0 = (sm[0] + sm[1] + sm[2] + sm[3]) * (1.0f / NN);
      float w1 = (sm[4] + sm[5] + sm[6] + sm[7]) * (1.0f / NN);
      float mx = fmaxf(w0, w1);
      float e0 = expf(w0 - mx), e1 = expf(w1 - mx);
      float inv = 1.f / (e0 + e1);
      wb[2] = e0 * inv;
      wb[3] = e1 * inv;
    }
  }
  int n = blockIdx.x * 4 + w;
  if (n >= NN) return;
  int r0 = rows[n], r1 = rows[n + 1];
  float acc = 0.f;
  int j = r0;
  for (; j + 4 <= r1; j += 4) {
    int sa = cols[j], sb = cols[j + 1], sc = cols[j + 2], sd = cols[j + 3];
    acc += bf2f(X[(size_t)sa * 64 + lane]) + bf2f(X[(size_t)sb * 64 + lane]) +
           bf2f(X[(size_t)sc * 64 + lane]) + bf2f(X[(size_t)sd * 64 + lane]);
  }
  for (; j < r1; ++j) acc += bf2f(X[(size_t)cols[j] * 64 + lane]);
  float p = tanhf(acc * rdi[n] + bg1[lane]);
  float o = 0.f;
#pragma unroll
  for (int k = 0; k < 64; ++k) o = fmaf(__shfl(p, k), Wg2[k * 64 + lane], o);
  out2[(size_t)n * 64 + lane] = f2bf(o * rdo[n]);
}

// ---------------- GCN gather layer2: inline Femb from Y0/Y1/beta, Z write + compact Zk ----
__global__ __launch_bounds__(256) void gcn_gather2_kernel(
    const int* __restrict__ rows, const int* __restrict__ cols, const ushort_t* __restrict__ X,
    const float* __restrict__ rdi, const ushort_t* __restrict__ Y0,
    const ushort_t* __restrict__ Y1, const float* __restrict__ wb, const float* __restrict__ bf,
    const int* __restrict__ kptr, float* __restrict__ Zc, float* __restrict__ dout) {
  int lane = threadIdx.x & 63, w = threadIdx.x >> 6;
  int n = blockIdx.x * 4 + w;
  if (n >= NN) return;
  int r0 = rows[n], r1 = rows[n + 1];
  float acc = 0.f;
  int j = r0;
  for (; j + 4 <= r1; j += 4) {
    int sa = cols[j], sb = cols[j + 1], sc = cols[j + 2], sd = cols[j + 3];
    acc += bf2f(X[(size_t)sa * 64 + lane]) + bf2f(X[(size_t)sb * 64 + lane]) +
           bf2f(X[(size_t)sc * 64 + lane]) + bf2f(X[(size_t)sd * 64 + lane]);
  }
  for (; j < r1; ++j) acc += bf2f(X[(size_t)cols[j] * 64 + lane]);
  float femb = wb[2] * bf2f(Y0[(size_t)n * 64 + lane]) +
               wb[3] * bf2f(Y1[(size_t)n * 64 + lane]) + bf[lane];
  float zv = 0.5f * (femb + acc * rdi[n]);
  dout[1 + (size_t)n * 64 + lane] = zv;
  int k = *kptr;
  if (lane < k && lane < 16) Zc[(size_t)n * 16 + lane] = zv;
}

// ---------------- trace ----------------
__global__ __launch_bounds__(256) void tr_kernel(const int* __restrict__ asrc,
                                                 const int* __restrict__ adst,
                                                 const int* __restrict__ kptr,
                                                 const float* __restrict__ Zc,
                                                 const float* __restrict__ dout,
                                                 float* __restrict__ trbuf) {
  __shared__ float wsum[4];
  int e = blockIdx.x * 256 + threadIdx.x;
  int k = *kptr;
  float local = 0.f;
  if (e < NE) {
    int a = asrc[e], b = adst[e];
    if (k <= 16) {
      const float* Za = Zc + (size_t)a * 16;
      const float* Zb = Zc + (size_t)b * 16;
      for (int c = 0; c < k; ++c) {
        float d2 = Za[c] - Zb[c];
        local += d2 * d2;
      }
    } else {
      const float* Za = dout + 1 + (size_t)a * 64;
      const float* Zb = dout + 1 + (size_t)b * 64;
      for (int c = 0; c < k; ++c) {
        float d2 = Za[c] - Zb[c];
        local += d2 * d2;
      }
    }
  }
#pragma unroll
  for (int off = 32; off > 0; off >>= 1) local += __shfl_down(local, off);
  int lane = threadIdx.x & 63, w = threadIdx.x >> 6;
  if (lane == 0) wsum[w] = local;
  __syncthreads();
  if (threadIdx.x == 0) trbuf[blockIdx.x] = wsum[0] + wsum[1] + wsum[2] + wsum[3];
}

__global__ __launch_bounds__(256) void tr_reduce_kernel(const float* __restrict__ trbuf,
                                                        float* __restrict__ dout) {
  __shared__ float sm[4];
  int t = threadIdx.x;
  float a = 0.f;
  for (int i = t; i < NTRB; i += 256) a += trbuf[i];
  a = wred(a);
  int lane = t & 63, w = t >> 6;
  if (lane == 0) sm[w] = a;
  __syncthreads();
  if (t == 0) dout[0] = 0.5f * (sm[0] + sm[1] + sm[2] + sm[3]);
}

extern "C" void kernel_launch(void* const* d_in, const int* in_sizes, int n_in, void* d_out,
                              int out_size, void* d_ws, size_t ws_size, hipStream_t stream) {
  const float* feat0 = (const float*)d_in[0];
  const float* feat1 = (const float*)d_in[1];
  const float* sen = (const float*)d_in[2];
  const float* Wgat0 = (const float*)d_in[3];
  const float* al0 = (const float*)d_in[4];
  const float* ar0 = (const float*)d_in[5];
  const float* b0 = (const float*)d_in[6];
  const float* Wgat1 = (const float*)d_in[7];
  const float* al1 = (const float*)d_in[8];
  const float* ar1 = (const float*)d_in[9];
  const float* b1 = (const float*)d_in[10];
  const float* Wp1 = (const float*)d_in[11];
  const float* bp1 = (const float*)d_in[12];
  const float* wp2 = (const float*)d_in[13];
  const float* Wf = (const float*)d_in[14];
  const float* bf = (const float*)d_in[15];
  const float* Wg1 = (const float*)d_in[16];
  const float* bg1 = (const float*)d_in[17];
  const float* Wg2 = (const float*)d_in[18];
  const int* src0 = (const int*)d_in[19];
  const int* dst0 = (const int*)d_in[20];
  const int* src1 = (const int*)d_in[21];
  const int* dst1 = (const int*)d_in[22];
  const int* gsrc = (const int*)d_in[23];
  const int* gdst = (const int*)d_in[24];
  const int* asrc = (const int*)d_in[25];
  const int* adst = (const int*)d_in[26];
  const int* kptr = (const int*)d_in[27];
  float* out = (float*)d_out;
  float* ws = (float*)d_ws;

  // ---- workspace layout (float-element offsets) ----
  // ZERO region [0 .. 210004): wb(4) cnt(120000 int) cnt2(90000 int)
  float* wb = ws;                               // 4
  int* cnt = (int*)(ws + 4);                    // 4*30000
  int* cnt2 = (int*)(ws + 120004);              // 3*30000
  float* rdo = ws + 210004;                     // 30000
  float* rdi = ws + 240004;                     // 30000
  int* rows = (int*)(ws + 270004);              // 3*(NN+1)=90003
  int* bsum = (int*)(ws + 360008);              // 354
  int* boff = (int*)(ws + 360364);              // 354
  int* cols = (int*)(ws + 360720);              // 3*NE = 1,440,000
  float* el0 = ws + 1800720;                    // 120000
  float* er0 = ws + 1920720;                    // 120000
  float* el1 = ws + 2040720;                    // 120000
  float* er1 = ws + 2160720;                    // 120000
  float* pbuf = ws + 2280720;                   // 2*NMT = 470
  float* trbuf = ws + 2281192;                  // 1875
  ushort_t* h0 = (ushort_t*)(ws + 2283068);     // 7,680,000 bf16
  ushort_t* h1 = (ushort_t*)(ws + 6123068);     // 7,680,000 bf16
  ushort_t* z0 = (ushort_t*)(ws + 9963068);     // 7,680,000 bf16
  ushort_t* z1 = (ushort_t*)(ws + 13803068);    // 7,680,000 bf16
  ushort_t* gcnA = (ushort_t*)(ws + 17643068);  // 1,920,000 bf16
  ushort_t* gcnA2 = (ushort_t*)(ws + 18603068); // 1,920,000 bf16
  ushort_t* Y0 = (ushort_t*)(ws + 19563068);    // 1,920,000 bf16
  ushort_t* Y1 = (ushort_t*)(ws + 20523068);    // 1,920,000 bf16
  ushort_t* WT0 = (ushort_t*)(ws + 21483068);   // 65536 bf16
  ushort_t* WT1 = (ushort_t*)(ws + 21515836);   // 32768 bf16
  ushort_t* WpfT = (ushort_t*)(ws + 21532220);  // 32768 bf16 = [Wp1T;WfT]
  ushort_t* Wg1T = (ushort_t*)(ws + 21548604);  // 16384 bf16
  float* Zc = ws + 21556796;                    // 480,000 (NN x 16 compact Zk)

  int* rows_g = rows + 2 * (NN + 1);
  int* cols_g = cols + 2 * NE;
  int* cnt_deg = cnt + 3 * NN;

  // ---- prep: zero + weight transposes (one launch) ----
  prep_kernel<<<782, 256, 0, stream>>>((float4*)ws, Wgat0, Wgat1, Wp1, Wf, Wg1, WT0, WT1, WpfT,
                                       WpfT + 16384, Wg1T);

  // ---- CSR build for 3 graphs (by dst) + gsrc out-degree ----
  hist_kernel<<<dim3(1875, 4), 256, 0, stream>>>(dst0, dst1, gdst, gsrc, cnt);
  scan_blocks_kernel<<<dim3(NBLK, 3), 256, 0, stream>>>(cnt, rows, bsum);
  scan_tops_kernel<<<dim3(1, 3), 128, 0, stream>>>(bsum, boff);
  add_off_kernel<<<dim3(NBLK, 3), 256, 0, stream>>>(rows, boff);
  scatter_kernel<<<dim3(1875, 4), 256, 0, stream>>>(src0, src1, gsrc, dst0, dst1, gdst, rows,
                                                    cnt2, cols, cnt_deg, rdo, rdi, rows_g);

  // ---- merged GEMM phase: h0 (2 pairs) + h1 (2 pairs) + gcn1 ----
  mfma_all_kernel<<<dim3(NMT, 5), 256, 0, stream>>>(feat0, feat1, sen, WT0, WT1, Wg1T, h0, h1,
                                                    gcnA, al0, ar0, el0, er0, al1, ar1, el1,
                                                    er1, rdo);

  // ---- GAT gather (both graphs) -> bf16 z ----
  gat_node_kernel<<<dim3(7500, 2), 256, 0, stream>>>(rows, cols, el0, er0, h0, b0, z0,
                                                     rows + (NN + 1), cols + NE, el1, er1, h1,
                                                     b1, z1);

  // ---- merged attn pooling + Wf projection ----
  mfma_attnwf_kernel<<<dim3(NMT, 2), 256, 0, stream>>>(z0, z1, WpfT, bp1, wp2, pbuf, Y0, Y1);

  // ---- GCN path (gather12 block0 folds beta; gather2 forms Femb inline) ----
  gcn_gather12_kernel<<<7500, 256, 0, stream>>>(rows_g, cols_g, gcnA, rdi, bg1, Wg2, rdo, gcnA2,
                                                pbuf, wb);
  gcn_gather2_kernel<<<7500, 256, 0, stream>>>(rows_g, cols_g, gcnA2, rdi, Y0, Y1, wb, bf, kptr,
                                               Zc, out);

  // ---- trace ----
  tr_kernel<<<NTRB, 256, 0, stream>>>(asrc, adst, kptr, Zc, out, trbuf);
  tr_reduce_kernel<<<1, 256, 0, stream>>>(trbuf, out);
}